// Round 10
// baseline (1195.563 us; speedup 1.0000x reference)
//
#include <hip/hip_runtime.h>
#include <hip/hip_bf16.h>

typedef unsigned short u16;
typedef unsigned int u32;
typedef __attribute__((ext_vector_type(2))) unsigned int u32x2;
typedef __attribute__((ext_vector_type(4))) float f32x4;
typedef __attribute__((ext_vector_type(8))) __bf16 bf16x8;

#define DEVI static __device__ __forceinline__

// ---------- scalar helpers ----------
DEVI u16 f2bf(float x) {
  union { float f; u32 u; } v; v.f = x;
  u32 r = v.u + 0x7fffu + ((v.u >> 16) & 1u);
  return (u16)(r >> 16);
}
DEVI float bf2f(u16 h) { union { u32 u; float f; } v; v.u = ((u32)h) << 16; return v.f; }
DEVI u32 pk2bf(float a, float b) { return (u32)f2bf(a) | ((u32)f2bf(b) << 16); }
DEVI float sigm(float x) { return 1.f / (1.f + __expf(-x)); }
DEVI float tanh_(float x) {
  float a = fabsf(x);
  float e = __expf(-2.f * a);
  float t = (1.f - e) / (1.f + e);
  return copysignf(t, x);
}

DEVI void gl_lds16(const u16* g, void* l) {
  __builtin_amdgcn_global_load_lds(
      (const __attribute__((address_space(1))) u32*)(const void*)g,
      (__attribute__((address_space(3))) u32*)l, 16, 0, 0);
}
DEVI f32x4 mfma16(bf16x8 a, bf16x8 b, f32x4 c) {
  return __builtin_amdgcn_mfma_f32_16x16x32_bf16(a, b, c, 0, 0, 0);
}

// 64B-row LDS swizzle key (R8-proven: zero conflicts).
#define SWZ(row) (((row) >> 1) & 3)

// ---------- prep kernels ----------
__global__ void sums_k(const float* __restrict__ adj, float* __restrict__ rs, float* __restrict__ cs) {
  __shared__ float red[256];
  int bid = blockIdx.x, tid = threadIdx.x;
  if (bid < 1024) {
    float a = 0.f;
    for (int j = tid; j < 1024; j += 256) a += adj[bid * 1024 + j];
    red[tid] = a; __syncthreads();
    for (int s = 128; s; s >>= 1) { if (tid < s) red[tid] += red[tid + s]; __syncthreads(); }
    if (!tid) rs[bid] = red[0];
  } else {
    int c0 = (bid - 1024) * 64;
    int c = tid & 63, r0 = tid >> 6;
    float a = 0.f;
    for (int r = r0; r < 1024; r += 4) a += adj[r * 1024 + c0 + c];
    red[tid] = a; __syncthreads();
    if (tid < 64) cs[c0 + c] = red[c] + red[64 + c] + red[128 + c] + red[192 + c];
  }
}

__global__ void s0_build(const float* __restrict__ adj, const float* __restrict__ rs, u16* __restrict__ S0) {
  __shared__ float tile[32][33];
  int i0 = blockIdx.x * 32, j0 = blockIdx.y * 32;
  int tx = threadIdx.x & 31, ty = threadIdx.x >> 5;
  for (int yy = ty; yy < 32; yy += 8)
    tile[yy][tx] = adj[(j0 + yy) * 1024 + i0 + tx];
  __syncthreads();
  for (int yy = ty; yy < 32; yy += 8)
    S0[(i0 + yy) * 1024 + j0 + tx] = f2bf(tile[tx][yy] / rs[j0 + tx]);
}

__global__ void s1_build(const float* __restrict__ adj, const float* __restrict__ cs, u16* __restrict__ S1) {
  int idx = blockIdx.x * 256 + threadIdx.x;
  int j = idx & 1023;
  S1[idx] = f2bf(adj[idx] / cs[j]);
}

__global__ void pack_w(const float* __restrict__ src, u16* __restrict__ dst,
                       int NO, int Ktot, int off0, int off1) {
  int idx = blockIdx.x * 256 + threadIdx.x;
  if (idx >= NO * Ktot) return;
  int o = idx / Ktot, k = idx % Ktot;
  int seg = k >> 7, i = k & 127;
  int mo = seg % 6;
  int pos = ((seg / 6) ? off1 : off0) + i;
  const float* wr = src + (long)pos * 5 * NO + o;
  float v;
  switch (mo) {
    case 0: case 1: v = wr[0] - wr[(long)2 * NO] - wr[(long)4 * NO]; break;
    case 2: v = wr[(long)1 * NO]; break;
    case 3: v = 2.f * wr[(long)2 * NO]; break;
    case 4: v = wr[(long)3 * NO]; break;
    default: v = 2.f * wr[(long)4 * NO]; break;
  }
  dst[idx] = f2bf(v);
}

__global__ void build_hx(const float* __restrict__ src, u16* __restrict__ hiN,
                         u16* __restrict__ loN, u16* __restrict__ hiT) {
  __shared__ u16 t[32][33];
  int n0 = blockIdx.x * 32, u0 = blockIdx.y * 32, b = blockIdx.z;
  int tx = threadIdx.x & 31, ty = threadIdx.x >> 5;
  for (int yy = ty; yy < 32; yy += 8) {
    long d = (long)b * 131072 + (n0 + yy) * 128 + u0 + tx;
    float v = src[d];
    u16 h = f2bf(v);
    hiN[d] = h;
    loN[d] = f2bf(v - bf2f(h));
    t[yy][tx] = h;
  }
  __syncthreads();
  for (int yy = ty; yy < 32; yy += 8)
    hiT[(long)(b * 128 + u0 + yy) * 1024 + n0 + tx] = t[tx][yy];
}

// ---------- x-part (layer 0): exact fp32 path ----------
__global__ void xch0_build(const float* __restrict__ inp, float* __restrict__ x0) {
  int idx = blockIdx.x * 256 + threadIdx.x;
  int n = idx >> 7, c = idx & 127, b = c >> 1, d = c & 1;
  x0[idx] = inp[b * 2048 + n * 2 + d];
}

__global__ void xch_diffuse(const u16* __restrict__ S, const float* __restrict__ xin,
                            float* __restrict__ xout) {
  int n = blockIdx.x, c = threadIdx.x;
  float acc = 0.f;
  for (int k = 0; k < 1024; k++) acc += bf2f(S[n * 1024 + k]) * xin[k * 128 + c];
  xout[n * 128 + c] = acc;
}

__global__ void xch_cheb(const u16* __restrict__ S, const float* __restrict__ xin,
                         const float* __restrict__ x0, float* __restrict__ xout) {
  int n = blockIdx.x, c = threadIdx.x;
  float acc = 0.f;
  for (int k = 0; k < 1024; k++) acc += bf2f(S[n * 1024 + k]) * xin[k * 128 + c];
  xout[n * 128 + c] = 2.f * acc - x0[n * 128 + c];
}

__global__ void xg_build(const float* __restrict__ gw0, const float* __restrict__ cw0,
                         const float* __restrict__ xch,
                         u16* __restrict__ xgg, u16* __restrict__ xgc) {
  int r = blockIdx.x;
  int n = r & 1023, b = r >> 10;
  int t = threadIdx.x;
  __shared__ float xv[10];
  if (t < 10) { int m = t % 5, p = t / 5; xv[t] = xch[(long)m * 131072 + n * 128 + b * 2 + p]; }
  __syncthreads();
  float a = 0.f;
#pragma unroll
  for (int q = 0; q < 10; q++) { int m = q % 5, p = q / 5;
    a += gw0[(long)(p * 5 + m) * 256 + t] * xv[q]; }
  xgg[(long)r * 256 + t] = f2bf(a);
  if (t < 128) {
    float a2 = 0.f;
#pragma unroll
    for (int q = 0; q < 10; q++) { int m = q % 5, p = q / 5;
      a2 += cw0[(long)(p * 5 + m) * 128 + t] * xv[q]; }
    xgc[(long)r * 128 + t] = f2bf(a2);
  }
}

// ---------- fused diffusion GEMM (256x256 tile, 8 waves, BK=64, double-buffered) ----------
struct DiffJob { const u16* X; const u16* S; u16* YN; u16* YT; };
struct DiffJobs { DiffJob j[4]; };

__global__ __launch_bounds__(512, 2) void gemm_diffz(DiffJobs jobs) {
  DiffJob J = jobs.j[blockIdx.z];
  constexpr int HALF = 512 * 64;                // 256 S-rows + 256 X-rows, 64B each (one 32-k half)
  constexpr int BUF = 2 * HALF;                 // BK=64 tile
  __shared__ char smem[2 * BUF];
  const int tid = threadIdx.x, wid = tid >> 6, lane = tid & 63;
  const int wrM = wid >> 2, wcN = wid & 3, l15 = lane & 15, l4 = lane >> 4;
  const int s_row = lane >> 2, s_kcp = lane & 3;
  const int ntile = blockIdx.y * 256;
  const int fbase = blockIdx.x * 256;

  f32x4 acc[8][4];
#pragma unroll
  for (int i = 0; i < 8; i++)
#pragma unroll
    for (int j = 0; j < 4; j++) acc[i][j] = (f32x4){0.f, 0.f, 0.f, 0.f};

  auto stage = [&](char* buf, int ks) {
#pragma unroll
    for (int h = 0; h < 2; h++) {
      const int kk = ks * 64 + h * 32;
#pragma unroll
      for (int c = 0; c < 4; c++) {
        const int row0 = c * 128 + wid * 16;    // wave-uniform
        const int row = row0 + s_row;           // per-lane (source only)
        const u16* src;
        if (row0 < 256) src = J.S + (long)(ntile + row) * 1024 + kk + ((s_kcp ^ SWZ(row)) * 8);
        else { const int fr = row - 256; src = J.X + (long)(fbase + fr) * 1024 + kk + ((s_kcp ^ SWZ(fr)) * 8); }
        gl_lds16(src, buf + h * HALF + row0 * 64);
      }
    }
  };
  auto compute = [&](char* buf) {
#pragma unroll
    for (int h = 0; h < 2; h++) {
      char* Ab = buf + h * HALF; char* Bb = Ab + 256 * 64;
      bf16x8 af[8], bfr[4];
#pragma unroll
      for (int mb = 0; mb < 8; mb++) {
        const int row = wrM * 128 + mb * 16 + l15;
        af[mb] = *(const bf16x8*)(Ab + row * 64 + ((l4 ^ SWZ(row)) * 16));
      }
#pragma unroll
      for (int nb = 0; nb < 4; nb++) {
        const int row = wcN * 64 + nb * 16 + l15;
        bfr[nb] = *(const bf16x8*)(Bb + row * 64 + ((l4 ^ SWZ(row)) * 16));
      }
      __builtin_amdgcn_s_setprio(1);
#pragma unroll
      for (int mb = 0; mb < 8; mb++)
#pragma unroll
        for (int nb = 0; nb < 4; nb++)
          acc[mb][nb] = mfma16(af[mb], bfr[nb], acc[mb][nb]);
      __builtin_amdgcn_s_setprio(0);
    }
  };

  const int NKS = 16;
  stage(smem, 0);
  for (int ks = 0; ks < NKS; ks++) {
    char* cur = smem + (ks & 1) * BUF;
    char* nxt = smem + ((ks + 1) & 1) * BUF;
    if (ks + 1 < NKS) {
      stage(nxt, ks + 1);
      asm volatile("s_waitcnt vmcnt(8)" ::: "memory");
    } else {
      asm volatile("s_waitcnt vmcnt(0)" ::: "memory");
    }
    __builtin_amdgcn_s_barrier();
    __builtin_amdgcn_sched_barrier(0);
    compute(cur);
    asm volatile("" ::: "memory");
    __builtin_amdgcn_s_barrier();
    __builtin_amdgcn_sched_barrier(0);
  }

#pragma unroll
  for (int mb = 0; mb < 8; mb++) {
#pragma unroll
    for (int nb = 0; nb < 4; nb++) {
      const int n0 = ntile + wrM * 128 + mb * 16 + l4 * 4;
      const int f  = fbase + wcN * 64 + nb * 16 + l15;
      const int b = f >> 7, u = f & 127;
      f32x4 v = acc[mb][nb];
      u16 h0 = f2bf(v[0]), h1 = f2bf(v[1]), h2 = f2bf(v[2]), h3 = f2bf(v[3]);
      u16* yn = J.YN + (long)b * 131072 + (long)n0 * 128 + u;
      yn[0] = h0; yn[128] = h1; yn[256] = h2; yn[384] = h3;
      if (J.YT != nullptr) {
        u32x2 wv; wv[0] = (u32)h0 | ((u32)h1 << 16); wv[1] = (u32)h2 | ((u32)h3 << 16);
        *(u32x2*)(J.YT + (long)f * 1024 + n0) = wv;
      }
    }
  }
}

// ---------- W GEMM with fused epilogue (256-wide N tile, 8 waves, BK=64) ----------
struct Segs { const u16* p[12]; };
DEVI const u16* seg_sel(const Segs& s, int i) {
  switch (i) {
    case 0: return s.p[0]; case 1: return s.p[1]; case 2: return s.p[2];
    case 3: return s.p[3]; case 4: return s.p[4]; case 5: return s.p[5];
    case 6: return s.p[6]; case 7: return s.p[7]; case 8: return s.p[8];
    case 9: return s.p[9]; case 10: return s.p[10]; default: return s.p[11];
  }
}

template<int EPI>   // 0 = GATE (M=256), 1 = CAND (M=128)
__global__ __launch_bounds__(512, 2) void gemm_wseg(
    Segs segs, const u16* __restrict__ WT, int Ktot,
    const float* __restrict__ bias, const float* __restrict__ Hprev,
    const u16* __restrict__ xadd,
    u16* __restrict__ rh_hi, u16* __restrict__ rh_lo, u16* __restrict__ rh_t,
    u16* __restrict__ usig,
    float* __restrict__ hnew_out, u16* __restrict__ xa_hi, u16* __restrict__ xa_lo,
    u16* __restrict__ xa_t)
{
  constexpr int TM = (EPI == 0) ? 256 : 128;
  constexpr int MB = (EPI == 0) ? 8 : 4;
  constexpr int MW = (EPI == 0) ? 128 : 64;
  constexpr int R1 = (TM + 256) / 128;          // stage rounds per 32-k half
  constexpr int HALF = (TM + 256) * 64;
  constexpr int BUF = 2 * HALF;
  __shared__ char smem[2 * BUF];
  const int tid = threadIdx.x, wid = tid >> 6, lane = tid & 63;
  const int wrM = wid >> 2, wcN = wid & 3, l15 = lane & 15, l4 = lane >> 4;
  const int s_row = lane >> 2, s_kcp = lane & 3;
  const int rtile = blockIdx.x * 256;

  f32x4 acc[MB][4];
#pragma unroll
  for (int i = 0; i < MB; i++)
#pragma unroll
    for (int j = 0; j < 4; j++) acc[i][j] = (f32x4){0.f, 0.f, 0.f, 0.f};

  const int NKS = Ktot >> 6;
  auto stage = [&](char* buf, int ks) {
#pragma unroll
    for (int h = 0; h < 2; h++) {
      const int kk = ks * 64 + h * 32;
      const int sidx = kk >> 7, si0 = kk & 127;
      const u16* sp = seg_sel(segs, sidx);
#pragma unroll
      for (int c = 0; c < R1; c++) {
        const int row0 = c * 128 + wid * 16;    // wave-uniform
        const int row = row0 + s_row;           // per-lane (source only)
        const u16* src;
        if (row0 < TM) src = WT + (long)row * Ktot + kk + ((s_kcp ^ SWZ(row)) * 8);
        else { const int br = row - TM; src = sp + (long)(rtile + br) * 128 + si0 + ((s_kcp ^ SWZ(br)) * 8); }
        gl_lds16(src, buf + h * HALF + row0 * 64);
      }
    }
  };
  auto compute = [&](char* buf) {
#pragma unroll
    for (int h = 0; h < 2; h++) {
      char* Ab = buf + h * HALF; char* Bb = Ab + TM * 64;
      bf16x8 af[MB], bfr[4];
#pragma unroll
      for (int mb = 0; mb < MB; mb++) {
        const int row = wrM * MW + mb * 16 + l15;
        af[mb] = *(const bf16x8*)(Ab + row * 64 + ((l4 ^ SWZ(row)) * 16));
      }
#pragma unroll
      for (int nb = 0; nb < 4; nb++) {
        const int row = wcN * 64 + nb * 16 + l15;
        bfr[nb] = *(const bf16x8*)(Bb + row * 64 + ((l4 ^ SWZ(row)) * 16));
      }
      __builtin_amdgcn_s_setprio(1);
#pragma unroll
      for (int mb = 0; mb < MB; mb++)
#pragma unroll
        for (int nb = 0; nb < 4; nb++)
          acc[mb][nb] = mfma16(af[mb], bfr[nb], acc[mb][nb]);
      __builtin_amdgcn_s_setprio(0);
    }
  };

  stage(smem, 0);
  for (int ks = 0; ks < NKS; ks++) {
    char* cur = smem + (ks & 1) * BUF;
    char* nxt = smem + ((ks + 1) & 1) * BUF;
    if (ks + 1 < NKS) {
      stage(nxt, ks + 1);
      if constexpr (R1 == 4) asm volatile("s_waitcnt vmcnt(8)" ::: "memory");
      else                   asm volatile("s_waitcnt vmcnt(6)" ::: "memory");
    } else {
      asm volatile("s_waitcnt vmcnt(0)" ::: "memory");
    }
    __builtin_amdgcn_s_barrier();
    __builtin_amdgcn_sched_barrier(0);
    compute(cur);
    asm volatile("" ::: "memory");
    __builtin_amdgcn_s_barrier();
    __builtin_amdgcn_sched_barrier(0);
  }

#pragma unroll
  for (int mb = 0; mb < MB; mb++) {
#pragma unroll
    for (int nb = 0; nb < 4; nb++) {
      const int o = wrM * MW + mb * 16 + l4 * 4;
      const int rr = rtile + wcN * 64 + nb * 16 + l15;
      const int n = rr & 1023, b = rr >> 10;
      f32x4 v = acc[mb][nb];
      float4 bv = *(const float4*)(bias + o);
      float a0 = 0.f, a1 = 0.f, a2 = 0.f, a3 = 0.f;
      if (xadd != nullptr) {
        const int xs = (EPI == 0) ? 256 : 128;
        u32x2 xv = *(const u32x2*)(xadd + (long)rr * xs + o);
        a0 = bf2f((u16)(xv[0] & 0xffffu)); a1 = bf2f((u16)(xv[0] >> 16));
        a2 = bf2f((u16)(xv[1] & 0xffffu)); a3 = bf2f((u16)(xv[1] >> 16));
      }
      if (EPI == 0) {
        float s0 = sigm(v[0] + bv.x + a0), s1 = sigm(v[1] + bv.y + a1);
        float s2 = sigm(v[2] + bv.z + a2), s3 = sigm(v[3] + bv.w + a3);
        if (o < 128) {
          float4 hv = *(const float4*)(Hprev + (long)rr * 128 + o);
          float r0 = s0 * hv.x, r1 = s1 * hv.y, r2 = s2 * hv.z, r3 = s3 * hv.w;
          u16 h0 = f2bf(r0), h1 = f2bf(r1), h2 = f2bf(r2), h3 = f2bf(r3);
          long d = (long)rr * 128 + o;
          u32x2 wh; wh[0] = (u32)h0 | ((u32)h1 << 16); wh[1] = (u32)h2 | ((u32)h3 << 16);
          *(u32x2*)(rh_hi + d) = wh;
          u32x2 wl; wl[0] = pk2bf(r0 - bf2f(h0), r1 - bf2f(h1));
          wl[1] = pk2bf(r2 - bf2f(h2), r3 - bf2f(h3));
          *(u32x2*)(rh_lo + d) = wl;
          u16* rt = rh_t + (long)(b * 128 + o) * 1024 + n;
          rt[0] = h0; rt[1024] = h1; rt[2048] = h2; rt[3072] = h3;
        } else {
          u32x2 wu; wu[0] = pk2bf(s0, s1); wu[1] = pk2bf(s2, s3);
          *(u32x2*)(usig + (long)rr * 128 + (o - 128)) = wu;
        }
      } else {
        float c0 = tanh_(v[0] + bv.x + a0), c1 = tanh_(v[1] + bv.y + a1);
        float c2 = tanh_(v[2] + bv.z + a2), c3 = tanh_(v[3] + bv.w + a3);
        u32x2 uv = *(const u32x2*)(usig + (long)rr * 128 + o);
        float u0 = bf2f((u16)(uv[0] & 0xffffu)), u1 = bf2f((u16)(uv[0] >> 16));
        float u2 = bf2f((u16)(uv[1] & 0xffffu)), u3 = bf2f((u16)(uv[1] >> 16));
        float4 hv = *(const float4*)(Hprev + (long)rr * 128 + o);
        float h0n = u0 * hv.x + (1.f - u0) * c0;
        float h1n = u1 * hv.y + (1.f - u1) * c1;
        float h2n = u2 * hv.z + (1.f - u2) * c2;
        float h3n = u3 * hv.w + (1.f - u3) * c3;
        *(float4*)(hnew_out + (long)rr * 128 + o) = make_float4(h0n, h1n, h2n, h3n);
        if (xa_hi != nullptr) {
          u16 x0 = f2bf(h0n), x1 = f2bf(h1n), x2 = f2bf(h2n), x3 = f2bf(h3n);
          long d = (long)rr * 128 + o;
          u32x2 wh; wh[0] = (u32)x0 | ((u32)x1 << 16); wh[1] = (u32)x2 | ((u32)x3 << 16);
          *(u32x2*)(xa_hi + d) = wh;
          u32x2 wl; wl[0] = pk2bf(h0n - bf2f(x0), h1n - bf2f(x1));
          wl[1] = pk2bf(h2n - bf2f(x2), h3n - bf2f(x3));
          *(u32x2*)(xa_lo + d) = wl;
          u16* xt = xa_t + (long)(b * 128 + o) * 1024 + n;
          xt[0] = x0; xt[1024] = x1; xt[2048] = x2; xt[3072] = x3;
        }
      }
    }
  }
}

// ---------- projection ----------
__global__ __launch_bounds__(256) void proj_k(const float* __restrict__ h1n, const float* __restrict__ pw,
                                              const float* __restrict__ pb, float* __restrict__ out) {
  int wid = threadIdx.x >> 6, lane = threadIdx.x & 63;
  int r = blockIdx.x * 4 + wid;
  int b = r >> 10, n = r & 1023;
  const float* hp = h1n + (long)b * 131072 + n * 128;
  float ha = hp[lane], hb = hp[lane + 64];
  float p0 = ha * pw[lane * 2]     + hb * pw[(lane + 64) * 2];
  float p1 = ha * pw[lane * 2 + 1] + hb * pw[(lane + 64) * 2 + 1];
  for (int off = 32; off; off >>= 1) { p0 += __shfl_down(p0, off); p1 += __shfl_down(p1, off); }
  if (!lane) {
    out[(long)b * 2048 + n * 2]     = p0 + pb[0];
    out[(long)b * 2048 + n * 2 + 1] = p1 + pb[1];
  }
}

// ---------- host ----------
extern "C" void kernel_launch(void* const* d_in, const int* in_sizes, int n_in,
                              void* d_out, int out_size, void* d_ws, size_t ws_size,
                              hipStream_t stream) {
  (void)in_sizes; (void)n_in; (void)out_size; (void)ws_size;
  const float* inputs = (const float*)d_in[0];
  const float* hidden = (const float*)d_in[1];
  const float* adj    = (const float*)d_in[2];
  const float* gw0 = (const float*)d_in[3];
  const float* gb0 = (const float*)d_in[4];
  const float* cw0 = (const float*)d_in[5];
  const float* cb0 = (const float*)d_in[6];
  const float* gw1 = (const float*)d_in[7];
  const float* gb1 = (const float*)d_in[8];
  const float* cw1 = (const float*)d_in[9];
  const float* cb1 = (const float*)d_in[10];
  const float* pw  = (const float*)d_in[11];
  const float* pb  = (const float*)d_in[12];

  float* out    = (float*)d_out;
  float* out_h0 = out + 131072;
  float* out_h1 = out_h0 + 8388608;
  const float* h0 = hidden;
  const float* h1 = hidden + 8388608;

  u16* OH1a = (u16*)out_h1;            // h1 hiN
  u16* OH1b = OH1a + 8388608;          // h1 loN

  char* wp = (char*)d_ws;
  auto alloc = [&](size_t bytes) { char* r = wp; wp += (bytes + 255) & ~(size_t)255; return r; };
  u16*   S0b  = (u16*)  alloc(1048576 * 2);
  u16*   S1b  = (u16*)  alloc(1048576 * 2);
  float* rs   = (float*)alloc(1024 * 4);
  float* cs   = (float*)alloc(1024 * 4);
  u16*   WG0  = (u16*)  alloc((size_t)256 * 768 * 2);
  u16*   WC0  = (u16*)  alloc((size_t)128 * 768 * 2);
  u16*   WG1  = (u16*)  alloc((size_t)256 * 1536 * 2);
  u16*   WC1  = (u16*)  alloc((size_t)128 * 1536 * 2);
  u16*   Bb   = (u16*)  alloc((size_t)13 * 8388608 * 2);   // 13 chain slots
  u16*   USIG = (u16*)  alloc((size_t)8388608 * 2);
  float* XCH  = (float*)alloc((size_t)5 * 131072 * 4);
  auto BB = [&](int i) { return Bb + (size_t)i * 8388608; };
  auto XC = [&](int i) { return XCH + (size_t)i * 131072; };
  u16* XGg = BB(4);   // spans slots 4,5
  u16* XGc = BB(6);

  // prep
  sums_k<<<1040, 256, 0, stream>>>(adj, rs, cs);
  s0_build<<<dim3(32, 32), 256, 0, stream>>>(adj, rs, S0b);
  s1_build<<<4096, 256, 0, stream>>>(adj, cs, S1b);
  pack_w<<<768,  256, 0, stream>>>(gw0, WG0, 256, 768, 2, 0);
  pack_w<<<384,  256, 0, stream>>>(cw0, WC0, 128, 768, 2, 0);
  pack_w<<<1536, 256, 0, stream>>>(gw1, WG1, 256, 1536, 0, 128);
  pack_w<<<768,  256, 0, stream>>>(cw1, WC1, 128, 1536, 0, 128);
  build_hx<<<dim3(32, 4, 64), 256, 0, stream>>>(h0, BB(0), BB(1), BB(2));      // A,B + x0T->C
  build_hx<<<dim3(32, 4, 64), 256, 0, stream>>>(h1, OH1a, OH1b, BB(3));        // h1T->D

  // x-part exact chains + additive preacts
  xch0_build<<<512, 256, 0, stream>>>(inputs, XC(0));
  xch_diffuse<<<1024, 128, 0, stream>>>(S0b, XC(0), XC(1));
  xch_cheb   <<<1024, 128, 0, stream>>>(S0b, XC(1), XC(0), XC(2));
  xch_diffuse<<<1024, 128, 0, stream>>>(S1b, XC(0), XC(3));
  xch_cheb   <<<1024, 128, 0, stream>>>(S1b, XC(3), XC(0), XC(4));
  xg_build<<<65536, 256, 0, stream>>>(gw0, cw0, XCH, XGg, XGc);

  DiffJobs dj{};
  // L0 s-chain: {s1: S0*x0T -> H(+T I) ; s3: S1*x0T -> J(+T K)}
  dj.j[0] = {BB(2), S0b, BB(7), BB(8)};
  dj.j[1] = {BB(2), S1b, BB(9), BB(10)};
  gemm_diffz<<<dim3(32, 4, 2), 512, 0, stream>>>(dj);
  // {s2: S0*s1T -> L ; s4: S1*s3T -> M}
  dj.j[0] = {BB(8),  S0b, BB(11), nullptr};
  dj.j[1] = {BB(10), S1b, BB(12), nullptr};
  gemm_diffz<<<dim3(32, 4, 2), 512, 0, stream>>>(dj);

  // GATE0: segs {A,B,H,L,J,M}; rhN->C, rhlo->K, rhT->I
  Segs sg0{};
  sg0.p[0] = BB(0); sg0.p[1] = BB(1); sg0.p[2] = BB(7); sg0.p[3] = BB(11); sg0.p[4] = BB(9); sg0.p[5] = BB(12);
  gemm_wseg<0><<<256, 512, 0, stream>>>(sg0, WG0, 768, gb0, h0, XGg,
      BB(2), BB(10), BB(8), USIG, nullptr, nullptr, nullptr, nullptr);

  // L0 c-chain: {c1: S0*rhT -> E(+T F) ; c3: S1*rhT -> A(+T B)}
  dj.j[0] = {BB(8), S0b, BB(4), BB(5)};
  dj.j[1] = {BB(8), S1b, BB(0), BB(1)};
  gemm_diffz<<<dim3(32, 4, 2), 512, 0, stream>>>(dj);
  // {c2: S0*c1T -> H ; c4: S1*c3T -> J}
  dj.j[0] = {BB(5), S0b, BB(7), nullptr};
  dj.j[1] = {BB(1), S1b, BB(9), nullptr};
  gemm_diffz<<<dim3(32, 4, 2), 512, 0, stream>>>(dj);

  // CAND0: segs {C,K,E,H,A,J}; xadd=XGc; out_h0; xaN->L, xalo->M, xaT->B
  Segs sc0{};
  sc0.p[0] = BB(2); sc0.p[1] = BB(10); sc0.p[2] = BB(4); sc0.p[3] = BB(7); sc0.p[4] = BB(0); sc0.p[5] = BB(9);
  gemm_wseg<1><<<256, 512, 0, stream>>>(sc0, WC0, 768, cb0, h0, XGc,
      nullptr, nullptr, nullptr, USIG, out_h0, BB(11), BB(12), BB(1));

  // L1 wave-1 (z=4)
  dj.j[0] = {BB(1), S0b, BB(0), BB(2)};
  dj.j[1] = {BB(1), S1b, BB(4), BB(5)};
  dj.j[2] = {BB(3), S0b, BB(8), BB(6)};
  dj.j[3] = {BB(3), S1b, BB(9), BB(7)};
  gemm_diffz<<<dim3(32, 4, 4), 512, 0, stream>>>(dj);
  dj.j[0] = {BB(2), S0b, BB(10), nullptr};
  dj.j[1] = {BB(5), S1b, BB(3),  nullptr};
  gemm_diffz<<<dim3(32, 4, 2), 512, 0, stream>>>(dj);
  dj.j[0] = {BB(6), S0b, BB(1), nullptr};
  dj.j[1] = {BB(7), S1b, BB(2), nullptr};
  gemm_diffz<<<dim3(32, 4, 2), 512, 0, stream>>>(dj);

  // GATE1: segs x{L,M,A,K,E,D} h{OH1a,OH1b,I,B,J,C}; rh1N->F, rh1lo->H, rh1T->G
  Segs sg1{};
  sg1.p[0] = BB(11); sg1.p[1] = BB(12); sg1.p[2] = BB(0); sg1.p[3] = BB(10); sg1.p[4] = BB(4); sg1.p[5] = BB(3);
  sg1.p[6] = OH1a;   sg1.p[7] = OH1b;   sg1.p[8] = BB(8); sg1.p[9] = BB(1);  sg1.p[10] = BB(9); sg1.p[11] = BB(2);
  gemm_wseg<0><<<256, 512, 0, stream>>>(sg1, WG1, 1536, gb1, h1, nullptr,
      BB(5), BB(7), BB(6), USIG, nullptr, nullptr, nullptr, nullptr);

  // L1 d-chain
  dj.j[0] = {BB(6), S0b, BB(8), BB(1)};
  dj.j[1] = {BB(6), S1b, BB(9), BB(2)};
  gemm_diffz<<<dim3(32, 4, 2), 512, 0, stream>>>(dj);
  dj.j[0] = {BB(1), S0b, BB(6), nullptr};
  gemm_diffz<<<dim3(32, 4, 1), 512, 0, stream>>>(dj);
  dj.j[0] = {BB(2), S1b, BB(1), nullptr};
  gemm_diffz<<<dim3(32, 4, 1), 512, 0, stream>>>(dj);

  // CAND1
  Segs sc1{};
  sc1.p[0] = BB(11); sc1.p[1] = BB(12); sc1.p[2] = BB(0); sc1.p[3] = BB(10); sc1.p[4] = BB(4); sc1.p[5] = BB(3);
  sc1.p[6] = BB(5);  sc1.p[7] = BB(7);  sc1.p[8] = BB(8); sc1.p[9] = BB(6);  sc1.p[10] = BB(9); sc1.p[11] = BB(1);
  gemm_wseg<1><<<256, 512, 0, stream>>>(sc1, WC1, 1536, cb1, h1, nullptr,
      nullptr, nullptr, nullptr, USIG, out_h1, nullptr, nullptr, nullptr);

  // projection
  proj_k<<<16384, 256, 0, stream>>>(out_h1, pw, pb, out);
}

// Round 11
// 1115.023 us; speedup vs baseline: 1.0722x; 1.0722x over previous
//
#include <hip/hip_runtime.h>
#include <hip/hip_bf16.h>

typedef unsigned short u16;
typedef unsigned int u32;
typedef __attribute__((ext_vector_type(2))) unsigned int u32x2;
typedef __attribute__((ext_vector_type(4))) float f32x4;
typedef __attribute__((ext_vector_type(8))) __bf16 bf16x8;

#define DEVI static __device__ __forceinline__

// ---------- scalar helpers ----------
DEVI u16 f2bf(float x) {
  union { float f; u32 u; } v; v.f = x;
  u32 r = v.u + 0x7fffu + ((v.u >> 16) & 1u);
  return (u16)(r >> 16);
}
DEVI float bf2f(u16 h) { union { u32 u; float f; } v; v.u = ((u32)h) << 16; return v.f; }
DEVI u32 pk2bf(float a, float b) { return (u32)f2bf(a) | ((u32)f2bf(b) << 16); }
DEVI float sigm(float x) { return 1.f / (1.f + __expf(-x)); }
DEVI float tanh_(float x) {
  float a = fabsf(x);
  float e = __expf(-2.f * a);
  float t = (1.f - e) / (1.f + e);
  return copysignf(t, x);
}

DEVI void gl_lds16(const u16* g, void* l) {
  __builtin_amdgcn_global_load_lds(
      (const __attribute__((address_space(1))) u32*)(const void*)g,
      (__attribute__((address_space(3))) u32*)l, 16, 0, 0);
}
DEVI f32x4 mfma16(bf16x8 a, bf16x8 b, f32x4 c) {
  return __builtin_amdgcn_mfma_f32_16x16x32_bf16(a, b, c, 0, 0, 0);
}

// 64B-row LDS swizzle key (R8-proven: zero conflicts).
#define SWZ(row) (((row) >> 1) & 3)

// ---------- prep kernels ----------
__global__ void sums_k(const float* __restrict__ adj, float* __restrict__ rs, float* __restrict__ cs) {
  __shared__ float red[256];
  int bid = blockIdx.x, tid = threadIdx.x;
  if (bid < 1024) {
    float a = 0.f;
    for (int j = tid; j < 1024; j += 256) a += adj[bid * 1024 + j];
    red[tid] = a; __syncthreads();
    for (int s = 128; s; s >>= 1) { if (tid < s) red[tid] += red[tid + s]; __syncthreads(); }
    if (!tid) rs[bid] = red[0];
  } else {
    int c0 = (bid - 1024) * 64;
    int c = tid & 63, r0 = tid >> 6;
    float a = 0.f;
    for (int r = r0; r < 1024; r += 4) a += adj[r * 1024 + c0 + c];
    red[tid] = a; __syncthreads();
    if (tid < 64) cs[c0 + c] = red[c] + red[64 + c] + red[128 + c] + red[192 + c];
  }
}

__global__ void s0_build(const float* __restrict__ adj, const float* __restrict__ rs, u16* __restrict__ S0) {
  __shared__ float tile[32][33];
  int i0 = blockIdx.x * 32, j0 = blockIdx.y * 32;
  int tx = threadIdx.x & 31, ty = threadIdx.x >> 5;
  for (int yy = ty; yy < 32; yy += 8)
    tile[yy][tx] = adj[(j0 + yy) * 1024 + i0 + tx];
  __syncthreads();
  for (int yy = ty; yy < 32; yy += 8)
    S0[(i0 + yy) * 1024 + j0 + tx] = f2bf(tile[tx][yy] / rs[j0 + tx]);
}

__global__ void s1_build(const float* __restrict__ adj, const float* __restrict__ cs, u16* __restrict__ S1) {
  int idx = blockIdx.x * 256 + threadIdx.x;
  int j = idx & 1023;
  S1[idx] = f2bf(adj[idx] / cs[j]);
}

__global__ void pack_w(const float* __restrict__ src, u16* __restrict__ dst,
                       int NO, int Ktot, int off0, int off1) {
  int idx = blockIdx.x * 256 + threadIdx.x;
  if (idx >= NO * Ktot) return;
  int o = idx / Ktot, k = idx % Ktot;
  int seg = k >> 7, i = k & 127;
  int mo = seg % 6;
  int pos = ((seg / 6) ? off1 : off0) + i;
  const float* wr = src + (long)pos * 5 * NO + o;
  float v;
  switch (mo) {
    case 0: case 1: v = wr[0] - wr[(long)2 * NO] - wr[(long)4 * NO]; break;
    case 2: v = wr[(long)1 * NO]; break;
    case 3: v = 2.f * wr[(long)2 * NO]; break;
    case 4: v = wr[(long)3 * NO]; break;
    default: v = 2.f * wr[(long)4 * NO]; break;
  }
  dst[idx] = f2bf(v);
}

__global__ void build_hx(const float* __restrict__ src, u16* __restrict__ hiN,
                         u16* __restrict__ loN, u16* __restrict__ hiT) {
  __shared__ u16 t[32][33];
  int n0 = blockIdx.x * 32, u0 = blockIdx.y * 32, b = blockIdx.z;
  int tx = threadIdx.x & 31, ty = threadIdx.x >> 5;
  for (int yy = ty; yy < 32; yy += 8) {
    long d = (long)b * 131072 + (n0 + yy) * 128 + u0 + tx;
    float v = src[d];
    u16 h = f2bf(v);
    hiN[d] = h;
    loN[d] = f2bf(v - bf2f(h));
    t[yy][tx] = h;
  }
  __syncthreads();
  for (int yy = ty; yy < 32; yy += 8)
    hiT[(long)(b * 128 + u0 + yy) * 1024 + n0 + tx] = t[tx][yy];
}

// ---------- x-part (layer 0): exact fp32 path ----------
__global__ void xch0_build(const float* __restrict__ inp, float* __restrict__ x0) {
  int idx = blockIdx.x * 256 + threadIdx.x;
  int n = idx >> 7, c = idx & 127, b = c >> 1, d = c & 1;
  x0[idx] = inp[b * 2048 + n * 2 + d];
}

__global__ void xch_diffuse(const u16* __restrict__ S, const float* __restrict__ xin,
                            float* __restrict__ xout) {
  int n = blockIdx.x, c = threadIdx.x;
  float acc = 0.f;
  for (int k = 0; k < 1024; k++) acc += bf2f(S[n * 1024 + k]) * xin[k * 128 + c];
  xout[n * 128 + c] = acc;
}

__global__ void xch_cheb(const u16* __restrict__ S, const float* __restrict__ xin,
                         const float* __restrict__ x0, float* __restrict__ xout) {
  int n = blockIdx.x, c = threadIdx.x;
  float acc = 0.f;
  for (int k = 0; k < 1024; k++) acc += bf2f(S[n * 1024 + k]) * xin[k * 128 + c];
  xout[n * 128 + c] = 2.f * acc - x0[n * 128 + c];
}

__global__ void xg_build(const float* __restrict__ gw0, const float* __restrict__ cw0,
                         const float* __restrict__ xch,
                         u16* __restrict__ xgg, u16* __restrict__ xgc) {
  int r = blockIdx.x;
  int n = r & 1023, b = r >> 10;
  int t = threadIdx.x;
  __shared__ float xv[10];
  if (t < 10) { int m = t % 5, p = t / 5; xv[t] = xch[(long)m * 131072 + n * 128 + b * 2 + p]; }
  __syncthreads();
  float a = 0.f;
#pragma unroll
  for (int q = 0; q < 10; q++) { int m = q % 5, p = q / 5;
    a += gw0[(long)(p * 5 + m) * 256 + t] * xv[q]; }
  xgg[(long)r * 256 + t] = f2bf(a);
  if (t < 128) {
    float a2 = 0.f;
#pragma unroll
    for (int q = 0; q < 10; q++) { int m = q % 5, p = q / 5;
      a2 += cw0[(long)(p * 5 + m) * 128 + t] * xv[q]; }
    xgc[(long)r * 128 + t] = f2bf(a2);
  }
}

// ---------- fused diffusion GEMM (256n x 128f tile, 4 waves, BK=32, triple-buffered) ----------
struct DiffJob { const u16* X; const u16* S; u16* YN; u16* YT; };
struct DiffJobs { DiffJob j[4]; };

__global__ __launch_bounds__(256, 2) void gemm_diffz(DiffJobs jobs) {
  DiffJob J = jobs.j[blockIdx.z];
  constexpr int ROWS = 384;                 // 256 S-rows + 128 X-rows
  constexpr int BUF = ROWS * 64;            // 24 KB
  __shared__ char smem[3 * BUF];            // 72 KB -> 2 blocks/CU
  const int tid = threadIdx.x, wid = tid >> 6, lane = tid & 63;
  const int wrM = wid >> 1, wcN = wid & 1, l15 = lane & 15, l4 = lane >> 4;
  const int s_row = lane >> 2, s_kcp = lane & 3;
  const int ntile = blockIdx.y * 256;
  const int fbase = blockIdx.x * 128;

  f32x4 acc[8][4];
#pragma unroll
  for (int i = 0; i < 8; i++)
#pragma unroll
    for (int j = 0; j < 4; j++) acc[i][j] = (f32x4){0.f, 0.f, 0.f, 0.f};

  auto stage = [&](char* buf, int ks) {
    const int k0 = ks * 32;
#pragma unroll
    for (int c = 0; c < 6; c++) {
      const int row0 = c * 64 + wid * 16;   // wave-uniform
      const int row = row0 + s_row;         // per-lane (source only)
      const u16* src;
      if (row0 < 256) src = J.S + (long)(ntile + row) * 1024 + k0 + ((s_kcp ^ SWZ(row)) * 8);
      else { const int fr = row - 256; src = J.X + (long)(fbase + fr) * 1024 + k0 + ((s_kcp ^ SWZ(fr)) * 8); }
      gl_lds16(src, buf + row0 * 64);
    }
  };
  auto compute = [&](char* buf) {
    char* Ab = buf; char* Bb = buf + 256 * 64;
    bf16x8 af[8], bfr[4];
#pragma unroll
    for (int mb = 0; mb < 8; mb++) {
      const int row = wrM * 128 + mb * 16 + l15;
      af[mb] = *(const bf16x8*)(Ab + row * 64 + ((l4 ^ SWZ(row)) * 16));
    }
#pragma unroll
    for (int nb = 0; nb < 4; nb++) {
      const int row = wcN * 64 + nb * 16 + l15;
      bfr[nb] = *(const bf16x8*)(Bb + row * 64 + ((l4 ^ SWZ(row)) * 16));
    }
    __builtin_amdgcn_s_setprio(1);
#pragma unroll
    for (int mb = 0; mb < 8; mb++)
#pragma unroll
      for (int nb = 0; nb < 4; nb++)
        acc[mb][nb] = mfma16(af[mb], bfr[nb], acc[mb][nb]);
    __builtin_amdgcn_s_setprio(0);
  };

  const int NKS = 32;
  stage(smem, 0);
  stage(smem + BUF, 1);
  char* cur = smem; char* mid = smem + BUF; char* fut = smem + 2 * BUF;
  for (int ks = 0; ks + 2 < NKS; ks++) {
    stage(fut, ks + 2);
    asm volatile("s_waitcnt vmcnt(12)" ::: "memory");
    __builtin_amdgcn_s_barrier();
    __builtin_amdgcn_sched_barrier(0);
    compute(cur);
    asm volatile("" ::: "memory");
    __builtin_amdgcn_s_barrier();
    __builtin_amdgcn_sched_barrier(0);
    char* t = cur; cur = mid; mid = fut; fut = t;
  }
  asm volatile("s_waitcnt vmcnt(6)" ::: "memory");
  __builtin_amdgcn_s_barrier();
  __builtin_amdgcn_sched_barrier(0);
  compute(cur);
  asm volatile("s_waitcnt vmcnt(0)" ::: "memory");
  __builtin_amdgcn_s_barrier();
  __builtin_amdgcn_sched_barrier(0);
  compute(mid);

#pragma unroll
  for (int mb = 0; mb < 8; mb++) {
#pragma unroll
    for (int nb = 0; nb < 4; nb++) {
      const int n0 = ntile + wrM * 128 + mb * 16 + l4 * 4;
      const int f  = fbase + wcN * 64 + nb * 16 + l15;
      const int b = f >> 7, u = f & 127;
      f32x4 v = acc[mb][nb];
      u16 h0 = f2bf(v[0]), h1 = f2bf(v[1]), h2 = f2bf(v[2]), h3 = f2bf(v[3]);
      u16* yn = J.YN + (long)b * 131072 + (long)n0 * 128 + u;
      yn[0] = h0; yn[128] = h1; yn[256] = h2; yn[384] = h3;
      if (J.YT != nullptr) {
        u32x2 wv; wv[0] = (u32)h0 | ((u32)h1 << 16); wv[1] = (u32)h2 | ((u32)h3 << 16);
        *(u32x2*)(J.YT + (long)f * 1024 + n0) = wv;
      }
    }
  }
}

// ---------- W GEMM with fused epilogue (M x 128 tile, 4 waves, BK=32, triple-buffered) ----------
struct Segs { const u16* p[12]; };
DEVI const u16* seg_sel(const Segs& s, int i) {
  switch (i) {
    case 0: return s.p[0]; case 1: return s.p[1]; case 2: return s.p[2];
    case 3: return s.p[3]; case 4: return s.p[4]; case 5: return s.p[5];
    case 6: return s.p[6]; case 7: return s.p[7]; case 8: return s.p[8];
    case 9: return s.p[9]; case 10: return s.p[10]; default: return s.p[11];
  }
}

template<int EPI>   // 0 = GATE (M=256), 1 = CAND (M=128)
__global__ __launch_bounds__(256, 2) void gemm_wseg(
    Segs segs, const u16* __restrict__ WT, int Ktot,
    const float* __restrict__ bias, const float* __restrict__ Hprev,
    const u16* __restrict__ xadd,
    u16* __restrict__ rh_hi, u16* __restrict__ rh_lo, u16* __restrict__ rh_t,
    u16* __restrict__ usig,
    float* __restrict__ hnew_out, u16* __restrict__ xa_hi, u16* __restrict__ xa_lo,
    u16* __restrict__ xa_t)
{
  constexpr int TM = (EPI == 0) ? 256 : 128;
  constexpr int MB = (EPI == 0) ? 8 : 4;
  constexpr int MW = (EPI == 0) ? 128 : 64;
  constexpr int R1 = (TM + 128) / 64;       // stage rounds (64 rows each): 6 or 4
  constexpr int BUF = (TM + 128) * 64;      // 24 KB or 16 KB
  __shared__ char smem[3 * BUF];
  const int tid = threadIdx.x, wid = tid >> 6, lane = tid & 63;
  const int wrM = wid >> 1, wcN = wid & 1, l15 = lane & 15, l4 = lane >> 4;
  const int s_row = lane >> 2, s_kcp = lane & 3;
  const int rtile = blockIdx.x * 128;

  f32x4 acc[MB][4];
#pragma unroll
  for (int i = 0; i < MB; i++)
#pragma unroll
    for (int j = 0; j < 4; j++) acc[i][j] = (f32x4){0.f, 0.f, 0.f, 0.f};

  const int NKS = Ktot >> 5;
  auto stage = [&](char* buf, int ks) {
    const int k0 = ks * 32;
    const int sidx = ks >> 2, si0 = (ks & 3) * 32;
    const u16* sp = seg_sel(segs, sidx);
#pragma unroll
    for (int c = 0; c < R1; c++) {
      const int row0 = c * 64 + wid * 16;   // wave-uniform
      const int row = row0 + s_row;         // per-lane (source only)
      const u16* src;
      if (row0 < TM) src = WT + (long)row * Ktot + k0 + ((s_kcp ^ SWZ(row)) * 8);
      else { const int br = row - TM; src = sp + (long)(rtile + br) * 128 + si0 + ((s_kcp ^ SWZ(br)) * 8); }
      gl_lds16(src, buf + row0 * 64);
    }
  };
  auto compute = [&](char* buf) {
    char* Ab = buf; char* Bb = buf + TM * 64;
    bf16x8 af[MB], bfr[4];
#pragma unroll
    for (int mb = 0; mb < MB; mb++) {
      const int row = wrM * MW + mb * 16 + l15;
      af[mb] = *(const bf16x8*)(Ab + row * 64 + ((l4 ^ SWZ(row)) * 16));
    }
#pragma unroll
    for (int nb = 0; nb < 4; nb++) {
      const int row = wcN * 64 + nb * 16 + l15;
      bfr[nb] = *(const bf16x8*)(Bb + row * 64 + ((l4 ^ SWZ(row)) * 16));
    }
    __builtin_amdgcn_s_setprio(1);
#pragma unroll
    for (int mb = 0; mb < MB; mb++)
#pragma unroll
      for (int nb = 0; nb < 4; nb++)
        acc[mb][nb] = mfma16(af[mb], bfr[nb], acc[mb][nb]);
    __builtin_amdgcn_s_setprio(0);
  };

  stage(smem, 0);
  stage(smem + BUF, 1);
  char* cur = smem; char* mid = smem + BUF; char* fut = smem + 2 * BUF;
  for (int ks = 0; ks + 2 < NKS; ks++) {
    stage(fut, ks + 2);
    if constexpr (R1 == 6) asm volatile("s_waitcnt vmcnt(12)" ::: "memory");
    else                   asm volatile("s_waitcnt vmcnt(8)" ::: "memory");
    __builtin_amdgcn_s_barrier();
    __builtin_amdgcn_sched_barrier(0);
    compute(cur);
    asm volatile("" ::: "memory");
    __builtin_amdgcn_s_barrier();
    __builtin_amdgcn_sched_barrier(0);
    char* t = cur; cur = mid; mid = fut; fut = t;
  }
  if constexpr (R1 == 6) asm volatile("s_waitcnt vmcnt(6)" ::: "memory");
  else                   asm volatile("s_waitcnt vmcnt(4)" ::: "memory");
  __builtin_amdgcn_s_barrier();
  __builtin_amdgcn_sched_barrier(0);
  compute(cur);
  asm volatile("s_waitcnt vmcnt(0)" ::: "memory");
  __builtin_amdgcn_s_barrier();
  __builtin_amdgcn_sched_barrier(0);
  compute(mid);

#pragma unroll
  for (int mb = 0; mb < MB; mb++) {
#pragma unroll
    for (int nb = 0; nb < 4; nb++) {
      const int o = wrM * MW + mb * 16 + l4 * 4;
      const int rr = rtile + wcN * 64 + nb * 16 + l15;
      const int n = rr & 1023, b = rr >> 10;
      f32x4 v = acc[mb][nb];
      float4 bv = *(const float4*)(bias + o);
      float a0 = 0.f, a1 = 0.f, a2 = 0.f, a3 = 0.f;
      if (xadd != nullptr) {
        const int xs = (EPI == 0) ? 256 : 128;
        u32x2 xv = *(const u32x2*)(xadd + (long)rr * xs + o);
        a0 = bf2f((u16)(xv[0] & 0xffffu)); a1 = bf2f((u16)(xv[0] >> 16));
        a2 = bf2f((u16)(xv[1] & 0xffffu)); a3 = bf2f((u16)(xv[1] >> 16));
      }
      if (EPI == 0) {
        float s0 = sigm(v[0] + bv.x + a0), s1 = sigm(v[1] + bv.y + a1);
        float s2 = sigm(v[2] + bv.z + a2), s3 = sigm(v[3] + bv.w + a3);
        if (o < 128) {
          float4 hv = *(const float4*)(Hprev + (long)rr * 128 + o);
          float r0 = s0 * hv.x, r1 = s1 * hv.y, r2 = s2 * hv.z, r3 = s3 * hv.w;
          u16 h0 = f2bf(r0), h1 = f2bf(r1), h2 = f2bf(r2), h3 = f2bf(r3);
          long d = (long)rr * 128 + o;
          u32x2 wh; wh[0] = (u32)h0 | ((u32)h1 << 16); wh[1] = (u32)h2 | ((u32)h3 << 16);
          *(u32x2*)(rh_hi + d) = wh;
          u32x2 wl; wl[0] = pk2bf(r0 - bf2f(h0), r1 - bf2f(h1));
          wl[1] = pk2bf(r2 - bf2f(h2), r3 - bf2f(h3));
          *(u32x2*)(rh_lo + d) = wl;
          u16* rt = rh_t + (long)(b * 128 + o) * 1024 + n;
          rt[0] = h0; rt[1024] = h1; rt[2048] = h2; rt[3072] = h3;
        } else {
          u32x2 wu; wu[0] = pk2bf(s0, s1); wu[1] = pk2bf(s2, s3);
          *(u32x2*)(usig + (long)rr * 128 + (o - 128)) = wu;
        }
      } else {
        float c0 = tanh_(v[0] + bv.x + a0), c1 = tanh_(v[1] + bv.y + a1);
        float c2 = tanh_(v[2] + bv.z + a2), c3 = tanh_(v[3] + bv.w + a3);
        u32x2 uv = *(const u32x2*)(usig + (long)rr * 128 + o);
        float u0 = bf2f((u16)(uv[0] & 0xffffu)), u1 = bf2f((u16)(uv[0] >> 16));
        float u2 = bf2f((u16)(uv[1] & 0xffffu)), u3 = bf2f((u16)(uv[1] >> 16));
        float4 hv = *(const float4*)(Hprev + (long)rr * 128 + o);
        float h0n = u0 * hv.x + (1.f - u0) * c0;
        float h1n = u1 * hv.y + (1.f - u1) * c1;
        float h2n = u2 * hv.z + (1.f - u2) * c2;
        float h3n = u3 * hv.w + (1.f - u3) * c3;
        *(float4*)(hnew_out + (long)rr * 128 + o) = make_float4(h0n, h1n, h2n, h3n);
        if (xa_hi != nullptr) {
          u16 x0 = f2bf(h0n), x1 = f2bf(h1n), x2 = f2bf(h2n), x3 = f2bf(h3n);
          long d = (long)rr * 128 + o;
          u32x2 wh; wh[0] = (u32)x0 | ((u32)x1 << 16); wh[1] = (u32)x2 | ((u32)x3 << 16);
          *(u32x2*)(xa_hi + d) = wh;
          u32x2 wl; wl[0] = pk2bf(h0n - bf2f(x0), h1n - bf2f(x1));
          wl[1] = pk2bf(h2n - bf2f(x2), h3n - bf2f(x3));
          *(u32x2*)(xa_lo + d) = wl;
          u16* xt = xa_t + (long)(b * 128 + o) * 1024 + n;
          xt[0] = x0; xt[1024] = x1; xt[2048] = x2; xt[3072] = x3;
        }
      }
    }
  }
}

// ---------- projection ----------
__global__ __launch_bounds__(256) void proj_k(const float* __restrict__ h1n, const float* __restrict__ pw,
                                              const float* __restrict__ pb, float* __restrict__ out) {
  int wid = threadIdx.x >> 6, lane = threadIdx.x & 63;
  int r = blockIdx.x * 4 + wid;
  int b = r >> 10, n = r & 1023;
  const float* hp = h1n + (long)b * 131072 + n * 128;
  float ha = hp[lane], hb = hp[lane + 64];
  float p0 = ha * pw[lane * 2]     + hb * pw[(lane + 64) * 2];
  float p1 = ha * pw[lane * 2 + 1] + hb * pw[(lane + 64) * 2 + 1];
  for (int off = 32; off; off >>= 1) { p0 += __shfl_down(p0, off); p1 += __shfl_down(p1, off); }
  if (!lane) {
    out[(long)b * 2048 + n * 2]     = p0 + pb[0];
    out[(long)b * 2048 + n * 2 + 1] = p1 + pb[1];
  }
}

// ---------- host ----------
extern "C" void kernel_launch(void* const* d_in, const int* in_sizes, int n_in,
                              void* d_out, int out_size, void* d_ws, size_t ws_size,
                              hipStream_t stream) {
  (void)in_sizes; (void)n_in; (void)out_size; (void)ws_size;
  const float* inputs = (const float*)d_in[0];
  const float* hidden = (const float*)d_in[1];
  const float* adj    = (const float*)d_in[2];
  const float* gw0 = (const float*)d_in[3];
  const float* gb0 = (const float*)d_in[4];
  const float* cw0 = (const float*)d_in[5];
  const float* cb0 = (const float*)d_in[6];
  const float* gw1 = (const float*)d_in[7];
  const float* gb1 = (const float*)d_in[8];
  const float* cw1 = (const float*)d_in[9];
  const float* cb1 = (const float*)d_in[10];
  const float* pw  = (const float*)d_in[11];
  const float* pb  = (const float*)d_in[12];

  float* out    = (float*)d_out;
  float* out_h0 = out + 131072;
  float* out_h1 = out_h0 + 8388608;
  const float* h0 = hidden;
  const float* h1 = hidden + 8388608;

  u16* OH1a = (u16*)out_h1;            // h1 hiN
  u16* OH1b = OH1a + 8388608;          // h1 loN

  char* wp = (char*)d_ws;
  auto alloc = [&](size_t bytes) { char* r = wp; wp += (bytes + 255) & ~(size_t)255; return r; };
  u16*   S0b  = (u16*)  alloc(1048576 * 2);
  u16*   S1b  = (u16*)  alloc(1048576 * 2);
  float* rs   = (float*)alloc(1024 * 4);
  float* cs   = (float*)alloc(1024 * 4);
  u16*   WG0  = (u16*)  alloc((size_t)256 * 768 * 2);
  u16*   WC0  = (u16*)  alloc((size_t)128 * 768 * 2);
  u16*   WG1  = (u16*)  alloc((size_t)256 * 1536 * 2);
  u16*   WC1  = (u16*)  alloc((size_t)128 * 1536 * 2);
  u16*   Bb   = (u16*)  alloc((size_t)13 * 8388608 * 2);   // 13 chain slots
  u16*   USIG = (u16*)  alloc((size_t)8388608 * 2);
  float* XCH  = (float*)alloc((size_t)5 * 131072 * 4);
  auto BB = [&](int i) { return Bb + (size_t)i * 8388608; };
  auto XC = [&](int i) { return XCH + (size_t)i * 131072; };
  u16* XGg = BB(4);   // spans slots 4,5
  u16* XGc = BB(6);

  // prep
  sums_k<<<1040, 256, 0, stream>>>(adj, rs, cs);
  s0_build<<<dim3(32, 32), 256, 0, stream>>>(adj, rs, S0b);
  s1_build<<<4096, 256, 0, stream>>>(adj, cs, S1b);
  pack_w<<<768,  256, 0, stream>>>(gw0, WG0, 256, 768, 2, 0);
  pack_w<<<384,  256, 0, stream>>>(cw0, WC0, 128, 768, 2, 0);
  pack_w<<<1536, 256, 0, stream>>>(gw1, WG1, 256, 1536, 0, 128);
  pack_w<<<768,  256, 0, stream>>>(cw1, WC1, 128, 1536, 0, 128);
  build_hx<<<dim3(32, 4, 64), 256, 0, stream>>>(h0, BB(0), BB(1), BB(2));      // A,B + x0T->C
  build_hx<<<dim3(32, 4, 64), 256, 0, stream>>>(h1, OH1a, OH1b, BB(3));        // h1T->D

  // x-part exact chains + additive preacts
  xch0_build<<<512, 256, 0, stream>>>(inputs, XC(0));
  xch_diffuse<<<1024, 128, 0, stream>>>(S0b, XC(0), XC(1));
  xch_cheb   <<<1024, 128, 0, stream>>>(S0b, XC(1), XC(0), XC(2));
  xch_diffuse<<<1024, 128, 0, stream>>>(S1b, XC(0), XC(3));
  xch_cheb   <<<1024, 128, 0, stream>>>(S1b, XC(3), XC(0), XC(4));
  xg_build<<<65536, 256, 0, stream>>>(gw0, cw0, XCH, XGg, XGc);

  DiffJobs dj{};
  // L0 s-chain: {s1: S0*x0T -> H(+T I) ; s3: S1*x0T -> J(+T K)}
  dj.j[0] = {BB(2), S0b, BB(7), BB(8)};
  dj.j[1] = {BB(2), S1b, BB(9), BB(10)};
  gemm_diffz<<<dim3(64, 4, 2), 256, 0, stream>>>(dj);
  // {s2: S0*s1T -> L ; s4: S1*s3T -> M}
  dj.j[0] = {BB(8),  S0b, BB(11), nullptr};
  dj.j[1] = {BB(10), S1b, BB(12), nullptr};
  gemm_diffz<<<dim3(64, 4, 2), 256, 0, stream>>>(dj);

  // GATE0: segs {A,B,H,L,J,M}; rhN->C, rhlo->K, rhT->I
  Segs sg0{};
  sg0.p[0] = BB(0); sg0.p[1] = BB(1); sg0.p[2] = BB(7); sg0.p[3] = BB(11); sg0.p[4] = BB(9); sg0.p[5] = BB(12);
  gemm_wseg<0><<<512, 256, 0, stream>>>(sg0, WG0, 768, gb0, h0, XGg,
      BB(2), BB(10), BB(8), USIG, nullptr, nullptr, nullptr, nullptr);

  // L0 c-chain: {c1: S0*rhT -> E(+T F) ; c3: S1*rhT -> A(+T B)}
  dj.j[0] = {BB(8), S0b, BB(4), BB(5)};
  dj.j[1] = {BB(8), S1b, BB(0), BB(1)};
  gemm_diffz<<<dim3(64, 4, 2), 256, 0, stream>>>(dj);
  // {c2: S0*c1T -> H ; c4: S1*c3T -> J}
  dj.j[0] = {BB(5), S0b, BB(7), nullptr};
  dj.j[1] = {BB(1), S1b, BB(9), nullptr};
  gemm_diffz<<<dim3(64, 4, 2), 256, 0, stream>>>(dj);

  // CAND0: segs {C,K,E,H,A,J}; xadd=XGc; out_h0; xaN->L, xalo->M, xaT->B
  Segs sc0{};
  sc0.p[0] = BB(2); sc0.p[1] = BB(10); sc0.p[2] = BB(4); sc0.p[3] = BB(7); sc0.p[4] = BB(0); sc0.p[5] = BB(9);
  gemm_wseg<1><<<512, 256, 0, stream>>>(sc0, WC0, 768, cb0, h0, XGc,
      nullptr, nullptr, nullptr, USIG, out_h0, BB(11), BB(12), BB(1));

  // L1 wave-1 (z=4)
  dj.j[0] = {BB(1), S0b, BB(0), BB(2)};
  dj.j[1] = {BB(1), S1b, BB(4), BB(5)};
  dj.j[2] = {BB(3), S0b, BB(8), BB(6)};
  dj.j[3] = {BB(3), S1b, BB(9), BB(7)};
  gemm_diffz<<<dim3(64, 4, 4), 256, 0, stream>>>(dj);
  dj.j[0] = {BB(2), S0b, BB(10), nullptr};
  dj.j[1] = {BB(5), S1b, BB(3),  nullptr};
  gemm_diffz<<<dim3(64, 4, 2), 256, 0, stream>>>(dj);
  dj.j[0] = {BB(6), S0b, BB(1), nullptr};
  dj.j[1] = {BB(7), S1b, BB(2), nullptr};
  gemm_diffz<<<dim3(64, 4, 2), 256, 0, stream>>>(dj);

  // GATE1: segs x{L,M,A,K,E,D} h{OH1a,OH1b,I,B,J,C}; rh1N->F, rh1lo->H, rh1T->G
  Segs sg1{};
  sg1.p[0] = BB(11); sg1.p[1] = BB(12); sg1.p[2] = BB(0); sg1.p[3] = BB(10); sg1.p[4] = BB(4); sg1.p[5] = BB(3);
  sg1.p[6] = OH1a;   sg1.p[7] = OH1b;   sg1.p[8] = BB(8); sg1.p[9] = BB(1);  sg1.p[10] = BB(9); sg1.p[11] = BB(2);
  gemm_wseg<0><<<512, 256, 0, stream>>>(sg1, WG1, 1536, gb1, h1, nullptr,
      BB(5), BB(7), BB(6), USIG, nullptr, nullptr, nullptr, nullptr);

  // L1 d-chain
  dj.j[0] = {BB(6), S0b, BB(8), BB(1)};
  dj.j[1] = {BB(6), S1b, BB(9), BB(2)};
  gemm_diffz<<<dim3(64, 4, 2), 256, 0, stream>>>(dj);
  dj.j[0] = {BB(1), S0b, BB(6), nullptr};
  gemm_diffz<<<dim3(64, 4, 1), 256, 0, stream>>>(dj);
  dj.j[0] = {BB(2), S1b, BB(1), nullptr};
  gemm_diffz<<<dim3(64, 4, 1), 256, 0, stream>>>(dj);

  // CAND1
  Segs sc1{};
  sc1.p[0] = BB(11); sc1.p[1] = BB(12); sc1.p[2] = BB(0); sc1.p[3] = BB(10); sc1.p[4] = BB(4); sc1.p[5] = BB(3);
  sc1.p[6] = BB(5);  sc1.p[7] = BB(7);  sc1.p[8] = BB(8); sc1.p[9] = BB(6);  sc1.p[10] = BB(9); sc1.p[11] = BB(1);
  gemm_wseg<1><<<512, 256, 0, stream>>>(sc1, WC1, 1536, cb1, h1, nullptr,
      nullptr, nullptr, nullptr, USIG, out_h1, nullptr, nullptr, nullptr);

  // projection
  proj_k<<<16384, 256, 0, stream>>>(out_h1, pw, pb, out);
}

// Round 12
// 1033.330 us; speedup vs baseline: 1.1570x; 1.0791x over previous
//
#include <hip/hip_runtime.h>
#include <hip/hip_bf16.h>

typedef unsigned short u16;
typedef unsigned int u32;
typedef __attribute__((ext_vector_type(2))) unsigned int u32x2;
typedef __attribute__((ext_vector_type(4))) float f32x4;
typedef __attribute__((ext_vector_type(8))) __bf16 bf16x8;

#define DEVI static __device__ __forceinline__

// ---------- scalar helpers ----------
DEVI u16 f2bf(float x) {
  union { float f; u32 u; } v; v.f = x;
  u32 r = v.u + 0x7fffu + ((v.u >> 16) & 1u);
  return (u16)(r >> 16);
}
DEVI float bf2f(u16 h) { union { u32 u; float f; } v; v.u = ((u32)h) << 16; return v.f; }
DEVI u32 pk2bf(float a, float b) { return (u32)f2bf(a) | ((u32)f2bf(b) << 16); }
DEVI float sigm(float x) { return 1.f / (1.f + __expf(-x)); }
DEVI float tanh_(float x) {
  float a = fabsf(x);
  float e = __expf(-2.f * a);
  float t = (1.f - e) / (1.f + e);
  return copysignf(t, x);
}

DEVI void gl_lds16(const u16* g, void* l) {
  __builtin_amdgcn_global_load_lds(
      (const __attribute__((address_space(1))) u32*)(const void*)g,
      (__attribute__((address_space(3))) u32*)l, 16, 0, 0);
}
DEVI f32x4 mfma16(bf16x8 a, bf16x8 b, f32x4 c) {
  return __builtin_amdgcn_mfma_f32_16x16x32_bf16(a, b, c, 0, 0, 0);
}

// 64B-row LDS swizzle key (R8-proven: zero conflicts).
#define SWZ(row) (((row) >> 1) & 3)

// ---------- prep kernels ----------
__global__ void sums_k(const float* __restrict__ adj, float* __restrict__ rs, float* __restrict__ cs) {
  __shared__ float red[256];
  int bid = blockIdx.x, tid = threadIdx.x;
  if (bid < 1024) {
    float a = 0.f;
    for (int j = tid; j < 1024; j += 256) a += adj[bid * 1024 + j];
    red[tid] = a; __syncthreads();
    for (int s = 128; s; s >>= 1) { if (tid < s) red[tid] += red[tid + s]; __syncthreads(); }
    if (!tid) rs[bid] = red[0];
  } else {
    int c0 = (bid - 1024) * 64;
    int c = tid & 63, r0 = tid >> 6;
    float a = 0.f;
    for (int r = r0; r < 1024; r += 4) a += adj[r * 1024 + c0 + c];
    red[tid] = a; __syncthreads();
    if (tid < 64) cs[c0 + c] = red[c] + red[64 + c] + red[128 + c] + red[192 + c];
  }
}

__global__ void s0_build(const float* __restrict__ adj, const float* __restrict__ rs, u16* __restrict__ S0) {
  __shared__ float tile[32][33];
  int i0 = blockIdx.x * 32, j0 = blockIdx.y * 32;
  int tx = threadIdx.x & 31, ty = threadIdx.x >> 5;
  for (int yy = ty; yy < 32; yy += 8)
    tile[yy][tx] = adj[(j0 + yy) * 1024 + i0 + tx];
  __syncthreads();
  for (int yy = ty; yy < 32; yy += 8)
    S0[(i0 + yy) * 1024 + j0 + tx] = f2bf(tile[tx][yy] / rs[j0 + tx]);
}

__global__ void s1_build(const float* __restrict__ adj, const float* __restrict__ cs, u16* __restrict__ S1) {
  int idx = blockIdx.x * 256 + threadIdx.x;
  int j = idx & 1023;
  S1[idx] = f2bf(adj[idx] / cs[j]);
}

// pack weights with cheb-fold; 5 segs per part: 0->W0-W2-W4, 1->W1, 2->2W2, 3->W3, 4->2W4
__global__ void pack_w(const float* __restrict__ src, u16* __restrict__ dst,
                       int NO, int Ktot, int off0, int off1) {
  int idx = blockIdx.x * 256 + threadIdx.x;
  if (idx >= NO * Ktot) return;
  int o = idx / Ktot, k = idx % Ktot;
  int seg = k >> 7, i = k & 127;
  int mo = seg % 5;
  int pos = ((seg / 5) ? off1 : off0) + i;
  const float* wr = src + (long)pos * 5 * NO + o;
  float v;
  switch (mo) {
    case 0: v = wr[0] - wr[(long)2 * NO] - wr[(long)4 * NO]; break;
    case 1: v = wr[(long)1 * NO]; break;
    case 2: v = 2.f * wr[(long)2 * NO]; break;
    case 3: v = wr[(long)3 * NO]; break;
    default: v = 2.f * wr[(long)4 * NO]; break;
  }
  dst[idx] = f2bf(v);
}

// h (B, N*128) fp32 -> hiN flat [r=b*1024+n][u] bf16 + hiT [b*128+u][n]
__global__ void build_hx(const float* __restrict__ src, u16* __restrict__ hiN,
                         u16* __restrict__ hiT) {
  __shared__ u16 t[32][33];
  int n0 = blockIdx.x * 32, u0 = blockIdx.y * 32, b = blockIdx.z;
  int tx = threadIdx.x & 31, ty = threadIdx.x >> 5;
  for (int yy = ty; yy < 32; yy += 8) {
    long d = (long)b * 131072 + (n0 + yy) * 128 + u0 + tx;
    u16 h = f2bf(src[d]);
    hiN[d] = h;
    t[yy][tx] = h;
  }
  __syncthreads();
  for (int yy = ty; yy < 32; yy += 8)
    hiT[(long)(b * 128 + u0 + yy) * 1024 + n0 + tx] = t[tx][yy];
}

// ---------- x-part (layer 0): exact fp32 path ----------
__global__ void xch0_build(const float* __restrict__ inp, float* __restrict__ x0) {
  int idx = blockIdx.x * 256 + threadIdx.x;
  int n = idx >> 7, c = idx & 127, b = c >> 1, d = c & 1;
  x0[idx] = inp[b * 2048 + n * 2 + d];
}

__global__ void xch_diffuse(const u16* __restrict__ S, const float* __restrict__ xin,
                            float* __restrict__ xout) {
  int n = blockIdx.x, c = threadIdx.x;
  float acc = 0.f;
  for (int k = 0; k < 1024; k++) acc += bf2f(S[n * 1024 + k]) * xin[k * 128 + c];
  xout[n * 128 + c] = acc;
}

__global__ void xch_cheb(const u16* __restrict__ S, const float* __restrict__ xin,
                         const float* __restrict__ x0, float* __restrict__ xout) {
  int n = blockIdx.x, c = threadIdx.x;
  float acc = 0.f;
  for (int k = 0; k < 1024; k++) acc += bf2f(S[n * 1024 + k]) * xin[k * 128 + c];
  xout[n * 128 + c] = 2.f * acc - x0[n * 128 + c];
}

// XG[r][o], r = b*1024+n; W staged in LDS once per block, 32 rows/block.
__global__ __launch_bounds__(256) void xg_build(
    const float* __restrict__ gw0, const float* __restrict__ cw0,
    const float* __restrict__ xch,
    u16* __restrict__ xgg, u16* __restrict__ xgc) {
  __shared__ float wg[10][256];
  __shared__ float wc[10][128];
  __shared__ float xv[10];
  int t = threadIdx.x;
#pragma unroll
  for (int q = 0; q < 10; q++) {
    int m = q % 5, p = q / 5;
    wg[q][t] = gw0[(long)(p * 5 + m) * 256 + t];
    if (t < 128) wc[q][t] = cw0[(long)(p * 5 + m) * 128 + t];
  }
  __syncthreads();
  int r0 = blockIdx.x * 32;
  for (int rl = 0; rl < 32; rl++) {
    int r = r0 + rl, n = r & 1023, b = r >> 10;
    if (t < 10) { int m = t % 5, p = t / 5; xv[t] = xch[(long)m * 131072 + n * 128 + b * 2 + p]; }
    __syncthreads();
    float a = 0.f;
#pragma unroll
    for (int q = 0; q < 10; q++) a += wg[q][t] * xv[q];
    xgg[(long)r * 256 + t] = f2bf(a);
    if (t < 128) {
      float a2 = 0.f;
#pragma unroll
      for (int q = 0; q < 10; q++) a2 += wc[q][t] * xv[q];
      xgc[(long)r * 128 + t] = f2bf(a2);
    }
    __syncthreads();
  }
}

// ---------- fused diffusion GEMM (256n x 128f tile, 4 waves, BK=32, triple-buffered) ----------
struct DiffJob { const u16* X; const u16* S; u16* YN; u16* YT; };
struct DiffJobs { DiffJob j[4]; };

__global__ __launch_bounds__(256, 2) void gemm_diffz(DiffJobs jobs) {
  DiffJob J = jobs.j[blockIdx.z];
  constexpr int BUF = 384 * 64;
  __shared__ char smem[3 * BUF];
  const int tid = threadIdx.x, wid = tid >> 6, lane = tid & 63;
  const int wrM = wid >> 1, wcN = wid & 1, l15 = lane & 15, l4 = lane >> 4;
  const int s_row = lane >> 2, s_kcp = lane & 3;
  const int ntile = blockIdx.y * 256;
  const int fbase = blockIdx.x * 128;

  f32x4 acc[8][4];
#pragma unroll
  for (int i = 0; i < 8; i++)
#pragma unroll
    for (int j = 0; j < 4; j++) acc[i][j] = (f32x4){0.f, 0.f, 0.f, 0.f};

  auto stage = [&](char* buf, int ks) {
    const int k0 = ks * 32;
#pragma unroll
    for (int c = 0; c < 6; c++) {
      const int row0 = c * 64 + wid * 16;
      const int row = row0 + s_row;
      const u16* src;
      if (row0 < 256) src = J.S + (long)(ntile + row) * 1024 + k0 + ((s_kcp ^ SWZ(row)) * 8);
      else { const int fr = row - 256; src = J.X + (long)(fbase + fr) * 1024 + k0 + ((s_kcp ^ SWZ(fr)) * 8); }
      gl_lds16(src, buf + row0 * 64);
    }
  };
  auto compute = [&](char* buf) {
    char* Ab = buf; char* Bb = buf + 256 * 64;
    bf16x8 af[8], bfr[4];
#pragma unroll
    for (int mb = 0; mb < 8; mb++) {
      const int row = wrM * 128 + mb * 16 + l15;
      af[mb] = *(const bf16x8*)(Ab + row * 64 + ((l4 ^ SWZ(row)) * 16));
    }
#pragma unroll
    for (int nb = 0; nb < 4; nb++) {
      const int row = wcN * 64 + nb * 16 + l15;
      bfr[nb] = *(const bf16x8*)(Bb + row * 64 + ((l4 ^ SWZ(row)) * 16));
    }
    __builtin_amdgcn_s_setprio(1);
#pragma unroll
    for (int mb = 0; mb < 8; mb++)
#pragma unroll
      for (int nb = 0; nb < 4; nb++)
        acc[mb][nb] = mfma16(af[mb], bfr[nb], acc[mb][nb]);
    __builtin_amdgcn_s_setprio(0);
  };

  const int NKS = 32;
  stage(smem, 0);
  stage(smem + BUF, 1);
  char* cur = smem; char* mid = smem + BUF; char* fut = smem + 2 * BUF;
  for (int ks = 0; ks + 2 < NKS; ks++) {
    stage(fut, ks + 2);
    asm volatile("s_waitcnt vmcnt(12)" ::: "memory");
    __builtin_amdgcn_s_barrier();
    __builtin_amdgcn_sched_barrier(0);
    compute(cur);
    asm volatile("" ::: "memory");
    __builtin_amdgcn_s_barrier();
    __builtin_amdgcn_sched_barrier(0);
    char* t = cur; cur = mid; mid = fut; fut = t;
  }
  asm volatile("s_waitcnt vmcnt(6)" ::: "memory");
  __builtin_amdgcn_s_barrier();
  __builtin_amdgcn_sched_barrier(0);
  compute(cur);
  asm volatile("s_waitcnt vmcnt(0)" ::: "memory");
  __builtin_amdgcn_s_barrier();
  __builtin_amdgcn_sched_barrier(0);
  compute(mid);

#pragma unroll
  for (int mb = 0; mb < 8; mb++) {
#pragma unroll
    for (int nb = 0; nb < 4; nb++) {
      const int n0 = ntile + wrM * 128 + mb * 16 + l4 * 4;
      const int f  = fbase + wcN * 64 + nb * 16 + l15;
      const int b = f >> 7, u = f & 127;
      f32x4 v = acc[mb][nb];
      u16 h0 = f2bf(v[0]), h1 = f2bf(v[1]), h2 = f2bf(v[2]), h3 = f2bf(v[3]);
      u16* yn = J.YN + (long)b * 131072 + (long)n0 * 128 + u;
      yn[0] = h0; yn[128] = h1; yn[256] = h2; yn[384] = h3;
      if (J.YT != nullptr) {
        u32x2 wv; wv[0] = (u32)h0 | ((u32)h1 << 16); wv[1] = (u32)h2 | ((u32)h3 << 16);
        *(u32x2*)(J.YT + (long)f * 1024 + n0) = wv;
      }
    }
  }
}

// ---------- W GEMM with fused epilogue (M x 128 tile, 4 waves, BK=32, triple-buffered) ----------
struct Segs { const u16* p[10]; };
DEVI const u16* seg_sel(const Segs& s, int i) {
  switch (i) {
    case 0: return s.p[0]; case 1: return s.p[1]; case 2: return s.p[2];
    case 3: return s.p[3]; case 4: return s.p[4]; case 5: return s.p[5];
    case 6: return s.p[6]; case 7: return s.p[7]; case 8: return s.p[8];
    default: return s.p[9];
  }
}

template<int EPI>   // 0 = GATE (M=256), 1 = CAND (M=128)
__global__ __launch_bounds__(256, 2) void gemm_wseg(
    Segs segs, const u16* __restrict__ WT, int Ktot,
    const float* __restrict__ bias, const float* __restrict__ Hprev,
    const u16* __restrict__ xadd,
    u16* __restrict__ rh_hi, u16* __restrict__ rh_t, u16* __restrict__ usig,
    float* __restrict__ hnew_out, u16* __restrict__ xa_hi, u16* __restrict__ xa_t)
{
  constexpr int TM = (EPI == 0) ? 256 : 128;
  constexpr int MB = (EPI == 0) ? 8 : 4;
  constexpr int MW = (EPI == 0) ? 128 : 64;
  constexpr int R1 = (TM + 128) / 64;
  constexpr int BUF = (TM + 128) * 64;
  __shared__ char smem[3 * BUF];
  const int tid = threadIdx.x, wid = tid >> 6, lane = tid & 63;
  const int wrM = wid >> 1, wcN = wid & 1, l15 = lane & 15, l4 = lane >> 4;
  const int s_row = lane >> 2, s_kcp = lane & 3;
  const int rtile = blockIdx.x * 128;

  f32x4 acc[MB][4];
#pragma unroll
  for (int i = 0; i < MB; i++)
#pragma unroll
    for (int j = 0; j < 4; j++) acc[i][j] = (f32x4){0.f, 0.f, 0.f, 0.f};

  const int NKS = Ktot >> 5;
  auto stage = [&](char* buf, int ks) {
    const int k0 = ks * 32;
    const int sidx = ks >> 2, si0 = (ks & 3) * 32;
    const u16* sp = seg_sel(segs, sidx);
#pragma unroll
    for (int c = 0; c < R1; c++) {
      const int row0 = c * 64 + wid * 16;
      const int row = row0 + s_row;
      const u16* src;
      if (row0 < TM) src = WT + (long)row * Ktot + k0 + ((s_kcp ^ SWZ(row)) * 8);
      else { const int br = row - TM; src = sp + (long)(rtile + br) * 128 + si0 + ((s_kcp ^ SWZ(br)) * 8); }
      gl_lds16(src, buf + row0 * 64);
    }
  };
  auto compute = [&](char* buf) {
    char* Ab = buf; char* Bb = buf + TM * 64;
    bf16x8 af[MB], bfr[4];
#pragma unroll
    for (int mb = 0; mb < MB; mb++) {
      const int row = wrM * MW + mb * 16 + l15;
      af[mb] = *(const bf16x8*)(Ab + row * 64 + ((l4 ^ SWZ(row)) * 16));
    }
#pragma unroll
    for (int nb = 0; nb < 4; nb++) {
      const int row = wcN * 64 + nb * 16 + l15;
      bfr[nb] = *(const bf16x8*)(Bb + row * 64 + ((l4 ^ SWZ(row)) * 16));
    }
    __builtin_amdgcn_s_setprio(1);
#pragma unroll
    for (int mb = 0; mb < MB; mb++)
#pragma unroll
      for (int nb = 0; nb < 4; nb++)
        acc[mb][nb] = mfma16(af[mb], bfr[nb], acc[mb][nb]);
    __builtin_amdgcn_s_setprio(0);
  };

  stage(smem, 0);
  stage(smem + BUF, 1);
  char* cur = smem; char* mid = smem + BUF; char* fut = smem + 2 * BUF;
  for (int ks = 0; ks + 2 < NKS; ks++) {
    stage(fut, ks + 2);
    if constexpr (R1 == 6) asm volatile("s_waitcnt vmcnt(12)" ::: "memory");
    else                   asm volatile("s_waitcnt vmcnt(8)" ::: "memory");
    __builtin_amdgcn_s_barrier();
    __builtin_amdgcn_sched_barrier(0);
    compute(cur);
    asm volatile("" ::: "memory");
    __builtin_amdgcn_s_barrier();
    __builtin_amdgcn_sched_barrier(0);
    char* t = cur; cur = mid; mid = fut; fut = t;
  }
  if constexpr (R1 == 6) asm volatile("s_waitcnt vmcnt(6)" ::: "memory");
  else                   asm volatile("s_waitcnt vmcnt(4)" ::: "memory");
  __builtin_amdgcn_s_barrier();
  __builtin_amdgcn_sched_barrier(0);
  compute(cur);
  asm volatile("s_waitcnt vmcnt(0)" ::: "memory");
  __builtin_amdgcn_s_barrier();
  __builtin_amdgcn_sched_barrier(0);
  compute(mid);

#pragma unroll
  for (int mb = 0; mb < MB; mb++) {
#pragma unroll
    for (int nb = 0; nb < 4; nb++) {
      const int o = wrM * MW + mb * 16 + l4 * 4;
      const int rr = rtile + wcN * 64 + nb * 16 + l15;
      const int n = rr & 1023, b = rr >> 10;
      f32x4 v = acc[mb][nb];
      float4 bv = *(const float4*)(bias + o);
      float a0 = 0.f, a1 = 0.f, a2 = 0.f, a3 = 0.f;
      if (xadd != nullptr) {
        const int xs = (EPI == 0) ? 256 : 128;
        u32x2 xv = *(const u32x2*)(xadd + (long)rr * xs + o);
        a0 = bf2f((u16)(xv[0] & 0xffffu)); a1 = bf2f((u16)(xv[0] >> 16));
        a2 = bf2f((u16)(xv[1] & 0xffffu)); a3 = bf2f((u16)(xv[1] >> 16));
      }
      if (EPI == 0) {
        float s0 = sigm(v[0] + bv.x + a0), s1 = sigm(v[1] + bv.y + a1);
        float s2 = sigm(v[2] + bv.z + a2), s3 = sigm(v[3] + bv.w + a3);
        if (o < 128) {
          float4 hv = *(const float4*)(Hprev + (long)rr * 128 + o);
          float r0 = s0 * hv.x, r1 = s1 * hv.y, r2 = s2 * hv.z, r3 = s3 * hv.w;
          u16 h0 = f2bf(r0), h1 = f2bf(r1), h2 = f2bf(r2), h3 = f2bf(r3);
          long d = (long)rr * 128 + o;
          u32x2 wh; wh[0] = (u32)h0 | ((u32)h1 << 16); wh[1] = (u32)h2 | ((u32)h3 << 16);
          *(u32x2*)(rh_hi + d) = wh;
          u16* rt = rh_t + (long)(b * 128 + o) * 1024 + n;
          rt[0] = h0; rt[1024] = h1; rt[2048] = h2; rt[3072] = h3;
        } else {
          u32x2 wu; wu[0] = pk2bf(s0, s1); wu[1] = pk2bf(s2, s3);
          *(u32x2*)(usig + (long)rr * 128 + (o - 128)) = wu;
        }
      } else {
        float c0 = tanh_(v[0] + bv.x + a0), c1 = tanh_(v[1] + bv.y + a1);
        float c2 = tanh_(v[2] + bv.z + a2), c3 = tanh_(v[3] + bv.w + a3);
        u32x2 uv = *(const u32x2*)(usig + (long)rr * 128 + o);
        float u0 = bf2f((u16)(uv[0] & 0xffffu)), u1 = bf2f((u16)(uv[0] >> 16));
        float u2 = bf2f((u16)(uv[1] & 0xffffu)), u3 = bf2f((u16)(uv[1] >> 16));
        float4 hv = *(const float4*)(Hprev + (long)rr * 128 + o);
        float h0n = u0 * hv.x + (1.f - u0) * c0;
        float h1n = u1 * hv.y + (1.f - u1) * c1;
        float h2n = u2 * hv.z + (1.f - u2) * c2;
        float h3n = u3 * hv.w + (1.f - u3) * c3;
        *(float4*)(hnew_out + (long)rr * 128 + o) = make_float4(h0n, h1n, h2n, h3n);
        if (xa_hi != nullptr) {
          u16 x0 = f2bf(h0n), x1 = f2bf(h1n), x2 = f2bf(h2n), x3 = f2bf(h3n);
          long d = (long)rr * 128 + o;
          u32x2 wh; wh[0] = (u32)x0 | ((u32)x1 << 16); wh[1] = (u32)x2 | ((u32)x3 << 16);
          *(u32x2*)(xa_hi + d) = wh;
          u16* xt = xa_t + (long)(b * 128 + o) * 1024 + n;
          xt[0] = x0; xt[1024] = x1; xt[2048] = x2; xt[3072] = x3;
        }
      }
    }
  }
}

// ---------- projection ----------
__global__ __launch_bounds__(256) void proj_k(const float* __restrict__ h1n, const float* __restrict__ pw,
                                              const float* __restrict__ pb, float* __restrict__ out) {
  int wid = threadIdx.x >> 6, lane = threadIdx.x & 63;
  int r = blockIdx.x * 4 + wid;
  int b = r >> 10, n = r & 1023;
  const float* hp = h1n + (long)b * 131072 + n * 128;
  float ha = hp[lane], hb = hp[lane + 64];
  float p0 = ha * pw[lane * 2]     + hb * pw[(lane + 64) * 2];
  float p1 = ha * pw[lane * 2 + 1] + hb * pw[(lane + 64) * 2 + 1];
  for (int off = 32; off; off >>= 1) { p0 += __shfl_down(p0, off); p1 += __shfl_down(p1, off); }
  if (!lane) {
    out[(long)b * 2048 + n * 2]     = p0 + pb[0];
    out[(long)b * 2048 + n * 2 + 1] = p1 + pb[1];
  }
}

// ---------- host ----------
extern "C" void kernel_launch(void* const* d_in, const int* in_sizes, int n_in,
                              void* d_out, int out_size, void* d_ws, size_t ws_size,
                              hipStream_t stream) {
  (void)in_sizes; (void)n_in; (void)out_size; (void)ws_size;
  const float* inputs = (const float*)d_in[0];
  const float* hidden = (const float*)d_in[1];
  const float* adj    = (const float*)d_in[2];
  const float* gw0 = (const float*)d_in[3];
  const float* gb0 = (const float*)d_in[4];
  const float* cw0 = (const float*)d_in[5];
  const float* cb0 = (const float*)d_in[6];
  const float* gw1 = (const float*)d_in[7];
  const float* gb1 = (const float*)d_in[8];
  const float* cw1 = (const float*)d_in[9];
  const float* cb1 = (const float*)d_in[10];
  const float* pw  = (const float*)d_in[11];
  const float* pb  = (const float*)d_in[12];

  float* out    = (float*)d_out;
  float* out_h0 = out + 131072;
  float* out_h1 = out_h0 + 8388608;
  const float* h0 = hidden;
  const float* h1 = hidden + 8388608;

  u16* OH1a = (u16*)out_h1;            // h1 hiN (dead after GATE1; CAND1 overwrites region)

  char* wp = (char*)d_ws;
  auto alloc = [&](size_t bytes) { char* r = wp; wp += (bytes + 255) & ~(size_t)255; return r; };
  u16*   S0b  = (u16*)  alloc(1048576 * 2);
  u16*   S1b  = (u16*)  alloc(1048576 * 2);
  float* rs   = (float*)alloc(1024 * 4);
  float* cs   = (float*)alloc(1024 * 4);
  u16*   WG0  = (u16*)  alloc((size_t)256 * 640 * 2);
  u16*   WC0  = (u16*)  alloc((size_t)128 * 640 * 2);
  u16*   WG1  = (u16*)  alloc((size_t)256 * 1280 * 2);
  u16*   WC1  = (u16*)  alloc((size_t)128 * 1280 * 2);
  u16*   Bb   = (u16*)  alloc((size_t)13 * 8388608 * 2);   // 13 chain slots
  u16*   USIG = (u16*)  alloc((size_t)8388608 * 2);
  float* XCH  = (float*)alloc((size_t)5 * 131072 * 4);
  auto BB = [&](int i) { return Bb + (size_t)i * 8388608; };
  auto XC = [&](int i) { return XCH + (size_t)i * 131072; };
  u16* XGg = BB(3);   // spans slots 3,4 (33.5 MB)
  u16* XGc = BB(5);

  // prep
  sums_k<<<1040, 256, 0, stream>>>(adj, rs, cs);
  s0_build<<<dim3(32, 32), 256, 0, stream>>>(adj, rs, S0b);
  s1_build<<<4096, 256, 0, stream>>>(adj, cs, S1b);
  pack_w<<<640,  256, 0, stream>>>(gw0, WG0, 256, 640, 2, 0);
  pack_w<<<320,  256, 0, stream>>>(cw0, WC0, 128, 640, 2, 0);
  pack_w<<<1280, 256, 0, stream>>>(gw1, WG1, 256, 1280, 0, 128);
  pack_w<<<640,  256, 0, stream>>>(cw1, WC1, 128, 1280, 0, 128);
  build_hx<<<dim3(32, 4, 64), 256, 0, stream>>>(h0, BB(0), BB(1));     // h0_hiN=A, h0T=B
  build_hx<<<dim3(32, 4, 64), 256, 0, stream>>>(h1, OH1a, BB(2));      // h1_hiN, h1T=C

  // x-part exact chains + additive preacts
  xch0_build<<<512, 256, 0, stream>>>(inputs, XC(0));
  xch_diffuse<<<1024, 128, 0, stream>>>(S0b, XC(0), XC(1));
  xch_cheb   <<<1024, 128, 0, stream>>>(S0b, XC(1), XC(0), XC(2));
  xch_diffuse<<<1024, 128, 0, stream>>>(S1b, XC(0), XC(3));
  xch_cheb   <<<1024, 128, 0, stream>>>(S1b, XC(3), XC(0), XC(4));
  xg_build<<<2048, 256, 0, stream>>>(gw0, cw0, XCH, XGg, XGc);

  DiffJobs dj{};
  // L0 s-chains: s1=S0*h0T -> N:BB6,T:BB7 ; s3=S1*h0T -> N:BB8,T:BB9
  dj.j[0] = {BB(1), S0b, BB(6), BB(7)};
  dj.j[1] = {BB(1), S1b, BB(8), BB(9)};
  gemm_diffz<<<dim3(64, 4, 2), 256, 0, stream>>>(dj);
  // s2=S0*s1T -> BB10 ; s4=S1*s3T -> BB11
  dj.j[0] = {BB(7), S0b, BB(10), nullptr};
  dj.j[1] = {BB(9), S1b, BB(11), nullptr};
  gemm_diffz<<<dim3(64, 4, 2), 256, 0, stream>>>(dj);

  // GATE0: segs {h0, s1, s2, s3, s4}; rh_hi->BB12, rhT->BB1 (h0T dead)
  Segs sg0{};
  sg0.p[0] = BB(0); sg0.p[1] = BB(6); sg0.p[2] = BB(10); sg0.p[3] = BB(8); sg0.p[4] = BB(11);
  gemm_wseg<0><<<512, 256, 0, stream>>>(sg0, WG0, 640, gb0, h0, XGg,
      BB(12), BB(1), USIG, nullptr, nullptr, nullptr);

  // L0 c-chains (rhT=BB1): c1 -> N:BB6,T:BB7 ; c3 -> N:BB8,T:BB9
  dj.j[0] = {BB(1), S0b, BB(6), BB(7)};
  dj.j[1] = {BB(1), S1b, BB(8), BB(9)};
  gemm_diffz<<<dim3(64, 4, 2), 256, 0, stream>>>(dj);
  // c2 -> BB10 ; c4 -> BB11
  dj.j[0] = {BB(7), S0b, BB(10), nullptr};
  dj.j[1] = {BB(9), S1b, BB(11), nullptr};
  gemm_diffz<<<dim3(64, 4, 2), 256, 0, stream>>>(dj);

  // CAND0: segs {rh, c1, c2, c3, c4}; out_h0; xa_hi->BB0 (h0 dead), xaT->BB1 (rhT dead)
  Segs sc0{};
  sc0.p[0] = BB(12); sc0.p[1] = BB(6); sc0.p[2] = BB(10); sc0.p[3] = BB(8); sc0.p[4] = BB(11);
  gemm_wseg<1><<<512, 256, 0, stream>>>(sc0, WC0, 640, cb0, h0, XGc,
      nullptr, nullptr, USIG, out_h0, BB(0), BB(1));

  // L1 wave-1 (z=4; XGg/XGc dead -> BB3,BB4,BB5 free):
  // s1'=S0*xaT -> N:BB3,T:BB4 ; s3'=S1*xaT -> N:BB5,T:BB6 ; t1=S0*h1T -> N:BB7,T:BB8 ; t3=S1*h1T -> N:BB9,T:BB10
  dj.j[0] = {BB(1), S0b, BB(3), BB(4)};
  dj.j[1] = {BB(1), S1b, BB(5), BB(6)};
  dj.j[2] = {BB(2), S0b, BB(7), BB(8)};
  dj.j[3] = {BB(2), S1b, BB(9), BB(10)};
  gemm_diffz<<<dim3(64, 4, 4), 256, 0, stream>>>(dj);
  // s2'=S0*s1'T -> BB11 ; s4'=S1*s3'T -> BB12 (rh0 dead)
  dj.j[0] = {BB(4), S0b, BB(11), nullptr};
  dj.j[1] = {BB(6), S1b, BB(12), nullptr};
  gemm_diffz<<<dim3(64, 4, 2), 256, 0, stream>>>(dj);
  // t2=S0*t1T -> BB4 (s1'T dead) ; t4=S1*t3T -> BB6 (s3'T dead)
  dj.j[0] = {BB(8), S0b, BB(4), nullptr};
  dj.j[1] = {BB(10), S1b, BB(6), nullptr};
  gemm_diffz<<<dim3(64, 4, 2), 256, 0, stream>>>(dj);

  // GATE1: segs x{xa, s1', s2', s3', s4'} h{h1, t1, t2, t3, t4}; rh1_hi->BB8 (t1T dead), rh1T->BB10 (t3T dead)
  Segs sg1{};
  sg1.p[0] = BB(0); sg1.p[1] = BB(3); sg1.p[2] = BB(11); sg1.p[3] = BB(5); sg1.p[4] = BB(12);
  sg1.p[5] = OH1a;  sg1.p[6] = BB(7); sg1.p[7] = BB(4);  sg1.p[8] = BB(9); sg1.p[9] = BB(6);
  gemm_wseg<0><<<512, 256, 0, stream>>>(sg1, WG1, 1280, gb1, h1, nullptr,
      BB(8), BB(10), USIG, nullptr, nullptr, nullptr);

  // L1 d-chains (rh1T=BB10): d1 -> N:BB1(xaT dead),T:BB2(h1T dead) ; d3 -> N:BB7(t1N dead),T:BB9(t3N dead)
  dj.j[0] = {BB(10), S0b, BB(1), BB(2)};
  dj.j[1] = {BB(10), S1b, BB(7), BB(9)};
  gemm_diffz<<<dim3(64, 4, 2), 256, 0, stream>>>(dj);
  // d2=S0*d1T -> BB4 (t2 dead) ; d4=S1*d3T -> BB6 (t4 dead)
  dj.j[0] = {BB(2), S0b, BB(4), nullptr};
  dj.j[1] = {BB(9), S1b, BB(6), nullptr};
  gemm_diffz<<<dim3(64, 4, 2), 256, 0, stream>>>(dj);

  // CAND1: segs x{xa, s1', s2', s3', s4'} rh{rh1, d1, d2, d3, d4}; -> out_h1 (OH1a dead)
  Segs sc1{};
  sc1.p[0] = BB(0); sc1.p[1] = BB(3); sc1.p[2] = BB(11); sc1.p[3] = BB(5); sc1.p[4] = BB(12);
  sc1.p[5] = BB(8); sc1.p[6] = BB(1); sc1.p[7] = BB(4);  sc1.p[8] = BB(7); sc1.p[9] = BB(6);
  gemm_wseg<1><<<512, 256, 0, stream>>>(sc1, WC1, 1280, cb1, h1, nullptr,
      nullptr, nullptr, USIG, out_h1, nullptr, nullptr);

  // projection
  proj_k<<<16384, 256, 0, stream>>>(out_h1, pw, pb, out);
}

// Round 13
// 1028.139 us; speedup vs baseline: 1.1628x; 1.0050x over previous
//
#include <hip/hip_runtime.h>
#include <hip/hip_bf16.h>

typedef unsigned short u16;
typedef unsigned int u32;
typedef __attribute__((ext_vector_type(2))) unsigned int u32x2;
typedef __attribute__((ext_vector_type(4))) float f32x4;
typedef __attribute__((ext_vector_type(8))) __bf16 bf16x8;

#define DEVI static __device__ __forceinline__

// ---------- scalar helpers ----------
DEVI u16 f2bf(float x) {
  union { float f; u32 u; } v; v.f = x;
  u32 r = v.u + 0x7fffu + ((v.u >> 16) & 1u);
  return (u16)(r >> 16);
}
DEVI float bf2f(u16 h) { union { u32 u; float f; } v; v.u = ((u32)h) << 16; return v.f; }
DEVI u32 pk2bf(float a, float b) { return (u32)f2bf(a) | ((u32)f2bf(b) << 16); }
DEVI float sigm(float x) { return 1.f / (1.f + __expf(-x)); }
DEVI float tanh_(float x) {
  float a = fabsf(x);
  float e = __expf(-2.f * a);
  float t = (1.f - e) / (1.f + e);
  return copysignf(t, x);
}

DEVI void gl_lds16(const u16* g, void* l) {
  __builtin_amdgcn_global_load_lds(
      (const __attribute__((address_space(1))) u32*)(const void*)g,
      (__attribute__((address_space(3))) u32*)l, 16, 0, 0);
}
DEVI f32x4 mfma16(bf16x8 a, bf16x8 b, f32x4 c) {
  return __builtin_amdgcn_mfma_f32_16x16x32_bf16(a, b, c, 0, 0, 0);
}

// 64B-row LDS swizzle key (R8-proven: zero conflicts).
#define SWZ(row) (((row) >> 1) & 3)

// ---------- prep kernels ----------
__global__ void sums_k(const float* __restrict__ adj, float* __restrict__ rs, float* __restrict__ cs) {
  __shared__ float red[256];
  int bid = blockIdx.x, tid = threadIdx.x;
  if (bid < 1024) {
    float a = 0.f;
    for (int j = tid; j < 1024; j += 256) a += adj[bid * 1024 + j];
    red[tid] = a; __syncthreads();
    for (int s = 128; s; s >>= 1) { if (tid < s) red[tid] += red[tid + s]; __syncthreads(); }
    if (!tid) rs[bid] = red[0];
  } else {
    int c0 = (bid - 1024) * 64;
    int c = tid & 63, r0 = tid >> 6;
    float a = 0.f;
    for (int r = r0; r < 1024; r += 4) a += adj[r * 1024 + c0 + c];
    red[tid] = a; __syncthreads();
    if (tid < 64) cs[c0 + c] = red[c] + red[64 + c] + red[128 + c] + red[192 + c];
  }
}

__global__ void s0_build(const float* __restrict__ adj, const float* __restrict__ rs, u16* __restrict__ S0) {
  __shared__ float tile[32][33];
  int i0 = blockIdx.x * 32, j0 = blockIdx.y * 32;
  int tx = threadIdx.x & 31, ty = threadIdx.x >> 5;
  for (int yy = ty; yy < 32; yy += 8)
    tile[yy][tx] = adj[(j0 + yy) * 1024 + i0 + tx];
  __syncthreads();
  for (int yy = ty; yy < 32; yy += 8)
    S0[(i0 + yy) * 1024 + j0 + tx] = f2bf(tile[tx][yy] / rs[j0 + tx]);
}

__global__ void s1_build(const float* __restrict__ adj, const float* __restrict__ cs, u16* __restrict__ S1) {
  int idx = blockIdx.x * 256 + threadIdx.x;
  int j = idx & 1023;
  S1[idx] = f2bf(adj[idx] / cs[j]);
}

// pack weights with cheb-fold; 5 segs per part: 0->W0-W2-W4, 1->W1, 2->2W2, 3->W3, 4->2W4
__global__ void pack_w(const float* __restrict__ src, u16* __restrict__ dst,
                       int NO, int Ktot, int off0, int off1) {
  int idx = blockIdx.x * 256 + threadIdx.x;
  if (idx >= NO * Ktot) return;
  int o = idx / Ktot, k = idx % Ktot;
  int seg = k >> 7, i = k & 127;
  int mo = seg % 5;
  int pos = ((seg / 5) ? off1 : off0) + i;
  const float* wr = src + (long)pos * 5 * NO + o;
  float v;
  switch (mo) {
    case 0: v = wr[0] - wr[(long)2 * NO] - wr[(long)4 * NO]; break;
    case 1: v = wr[(long)1 * NO]; break;
    case 2: v = 2.f * wr[(long)2 * NO]; break;
    case 3: v = wr[(long)3 * NO]; break;
    default: v = 2.f * wr[(long)4 * NO]; break;
  }
  dst[idx] = f2bf(v);
}

// h (B, N*128) fp32 -> hiN flat [r=b*1024+n][u] bf16 + hiT [b*128+u][n]
__global__ void build_hx(const float* __restrict__ src, u16* __restrict__ hiN,
                         u16* __restrict__ hiT) {
  __shared__ u16 t[32][33];
  int n0 = blockIdx.x * 32, u0 = blockIdx.y * 32, b = blockIdx.z;
  int tx = threadIdx.x & 31, ty = threadIdx.x >> 5;
  for (int yy = ty; yy < 32; yy += 8) {
    long d = (long)b * 131072 + (n0 + yy) * 128 + u0 + tx;
    u16 h = f2bf(src[d]);
    hiN[d] = h;
    t[yy][tx] = h;
  }
  __syncthreads();
  for (int yy = ty; yy < 32; yy += 8)
    hiT[(long)(b * 128 + u0 + yy) * 1024 + n0 + tx] = t[tx][yy];
}

// ---------- x-part (layer 0): exact fp32 path ----------
__global__ void xch0_build(const float* __restrict__ inp, float* __restrict__ x0) {
  int idx = blockIdx.x * 256 + threadIdx.x;
  int n = idx >> 7, c = idx & 127, b = c >> 1, d = c & 1;
  x0[idx] = inp[b * 2048 + n * 2 + d];
}

__global__ void xch_diffuse(const u16* __restrict__ S, const float* __restrict__ xin,
                            float* __restrict__ xout) {
  int n = blockIdx.x, c = threadIdx.x;
  float acc = 0.f;
  for (int k = 0; k < 1024; k++) acc += bf2f(S[n * 1024 + k]) * xin[k * 128 + c];
  xout[n * 128 + c] = acc;
}

__global__ void xch_cheb(const u16* __restrict__ S, const float* __restrict__ xin,
                         const float* __restrict__ x0, float* __restrict__ xout) {
  int n = blockIdx.x, c = threadIdx.x;
  float acc = 0.f;
  for (int k = 0; k < 1024; k++) acc += bf2f(S[n * 1024 + k]) * xin[k * 128 + c];
  xout[n * 128 + c] = 2.f * acc - x0[n * 128 + c];
}

// XG[r][o], r = b*1024+n; W staged in LDS once per block, 32 rows/block.
__global__ __launch_bounds__(256) void xg_build(
    const float* __restrict__ gw0, const float* __restrict__ cw0,
    const float* __restrict__ xch,
    u16* __restrict__ xgg, u16* __restrict__ xgc) {
  __shared__ float wg[10][256];
  __shared__ float wc[10][128];
  __shared__ float xv[10];
  int t = threadIdx.x;
#pragma unroll
  for (int q = 0; q < 10; q++) {
    int m = q % 5, p = q / 5;
    wg[q][t] = gw0[(long)(p * 5 + m) * 256 + t];
    if (t < 128) wc[q][t] = cw0[(long)(p * 5 + m) * 128 + t];
  }
  __syncthreads();
  int r0 = blockIdx.x * 32;
  for (int rl = 0; rl < 32; rl++) {
    int r = r0 + rl, n = r & 1023, b = r >> 10;
    if (t < 10) { int m = t % 5, p = t / 5; xv[t] = xch[(long)m * 131072 + n * 128 + b * 2 + p]; }
    __syncthreads();
    float a = 0.f;
#pragma unroll
    for (int q = 0; q < 10; q++) a += wg[q][t] * xv[q];
    xgg[(long)r * 256 + t] = f2bf(a);
    if (t < 128) {
      float a2 = 0.f;
#pragma unroll
      for (int q = 0; q < 10; q++) a2 += wc[q][t] * xv[q];
      xgc[(long)r * 128 + t] = f2bf(a2);
    }
    __syncthreads();
  }
}

// ---------- fused diffusion GEMM (256n x 128f tile, 4 waves, BK=32, triple-buffered) ----------
// XCD-cluster swizzle: the 4 ntile-blocks sharing an X f-slice land on ONE XCD -> L2 hits.
struct DiffJob { const u16* X; const u16* S; u16* YN; u16* YT; };
struct DiffJobs { DiffJob j[4]; };

__global__ __launch_bounds__(256, 2) void gemm_diffz(DiffJobs jobs) {
  DiffJob J = jobs.j[blockIdx.z];
  constexpr int BUF = 384 * 64;
  __shared__ char smem[3 * BUF];
  const int tid = threadIdx.x, wid = tid >> 6, lane = tid & 63;
  const int wrM = wid >> 1, wcN = wid & 1, l15 = lane & 15, l4 = lane >> 4;
  const int s_row = lane >> 2, s_kcp = lane & 3;
  // bijective XCD-cluster remap of the 256 (fbase,ntile) work items:
  // hw block l lands on XCD l%8; give XCD k the contiguous sl range [32k,32k+32)
  const int l = blockIdx.y * 64 + blockIdx.x;       // 0..255
  const int sl = (l & 7) * 32 + (l >> 3);
  const int fbase = (sl >> 2) * 128;
  const int ntile = (sl & 3) * 256;

  f32x4 acc[8][4];
#pragma unroll
  for (int i = 0; i < 8; i++)
#pragma unroll
    for (int j = 0; j < 4; j++) acc[i][j] = (f32x4){0.f, 0.f, 0.f, 0.f};

  auto stage = [&](char* buf, int ks) {
    const int k0 = ks * 32;
#pragma unroll
    for (int c = 0; c < 6; c++) {
      const int row0 = c * 64 + wid * 16;
      const int row = row0 + s_row;
      const u16* src;
      if (row0 < 256) src = J.S + (long)(ntile + row) * 1024 + k0 + ((s_kcp ^ SWZ(row)) * 8);
      else { const int fr = row - 256; src = J.X + (long)(fbase + fr) * 1024 + k0 + ((s_kcp ^ SWZ(fr)) * 8); }
      gl_lds16(src, buf + row0 * 64);
    }
  };
  auto compute = [&](char* buf) {
    char* Ab = buf; char* Bb = buf + 256 * 64;
    bf16x8 af[8], bfr[4];
#pragma unroll
    for (int mb = 0; mb < 8; mb++) {
      const int row = wrM * 128 + mb * 16 + l15;
      af[mb] = *(const bf16x8*)(Ab + row * 64 + ((l4 ^ SWZ(row)) * 16));
    }
#pragma unroll
    for (int nb = 0; nb < 4; nb++) {
      const int row = wcN * 64 + nb * 16 + l15;
      bfr[nb] = *(const bf16x8*)(Bb + row * 64 + ((l4 ^ SWZ(row)) * 16));
    }
    __builtin_amdgcn_s_setprio(1);
#pragma unroll
    for (int mb = 0; mb < 8; mb++)
#pragma unroll
      for (int nb = 0; nb < 4; nb++)
        acc[mb][nb] = mfma16(af[mb], bfr[nb], acc[mb][nb]);
    __builtin_amdgcn_s_setprio(0);
  };

  const int NKS = 32;
  stage(smem, 0);
  stage(smem + BUF, 1);
  char* cur = smem; char* mid = smem + BUF; char* fut = smem + 2 * BUF;
  for (int ks = 0; ks + 2 < NKS; ks++) {
    stage(fut, ks + 2);
    asm volatile("s_waitcnt vmcnt(12)" ::: "memory");
    __builtin_amdgcn_s_barrier();
    __builtin_amdgcn_sched_barrier(0);
    compute(cur);
    asm volatile("" ::: "memory");
    __builtin_amdgcn_s_barrier();
    __builtin_amdgcn_sched_barrier(0);
    char* t = cur; cur = mid; mid = fut; fut = t;
  }
  asm volatile("s_waitcnt vmcnt(6)" ::: "memory");
  __builtin_amdgcn_s_barrier();
  __builtin_amdgcn_sched_barrier(0);
  compute(cur);
  asm volatile("s_waitcnt vmcnt(0)" ::: "memory");
  __builtin_amdgcn_s_barrier();
  __builtin_amdgcn_sched_barrier(0);
  compute(mid);

#pragma unroll
  for (int mb = 0; mb < 8; mb++) {
#pragma unroll
    for (int nb = 0; nb < 4; nb++) {
      const int n0 = ntile + wrM * 128 + mb * 16 + l4 * 4;
      const int f  = fbase + wcN * 64 + nb * 16 + l15;
      const int b = f >> 7, u = f & 127;
      f32x4 v = acc[mb][nb];
      u16 h0 = f2bf(v[0]), h1 = f2bf(v[1]), h2 = f2bf(v[2]), h3 = f2bf(v[3]);
      u16* yn = J.YN + (long)b * 131072 + (long)n0 * 128 + u;
      yn[0] = h0; yn[128] = h1; yn[256] = h2; yn[384] = h3;
      if (J.YT != nullptr) {
        u32x2 wv; wv[0] = (u32)h0 | ((u32)h1 << 16); wv[1] = (u32)h2 | ((u32)h3 << 16);
        *(u32x2*)(J.YT + (long)f * 1024 + n0) = wv;
      }
    }
  }
}

// ---------- W GEMM with fused epilogue (M x 128 tile, 4 waves, BK=32, triple-buffered) ----------
struct Segs { const u16* p[10]; };
DEVI const u16* seg_sel(const Segs& s, int i) {
  switch (i) {
    case 0: return s.p[0]; case 1: return s.p[1]; case 2: return s.p[2];
    case 3: return s.p[3]; case 4: return s.p[4]; case 5: return s.p[5];
    case 6: return s.p[6]; case 7: return s.p[7]; case 8: return s.p[8];
    default: return s.p[9];
  }
}

template<int EPI>   // 0 = GATE (M=256), 1 = CAND (M=128)
__global__ __launch_bounds__(256, 2) void gemm_wseg(
    Segs segs, const u16* __restrict__ WT, int Ktot,
    const float* __restrict__ bias, const float* __restrict__ Hprev,
    const u16* __restrict__ xadd,
    u16* __restrict__ rh_hi, u16* __restrict__ rh_t, u16* __restrict__ usig,
    float* __restrict__ hnew_out, u16* __restrict__ xa_hi, u16* __restrict__ xa_t)
{
  constexpr int TM = (EPI == 0) ? 256 : 128;
  constexpr int MB = (EPI == 0) ? 8 : 4;
  constexpr int MW = (EPI == 0) ? 128 : 64;
  constexpr int R1 = (TM + 128) / 64;
  constexpr int BUF = (TM + 128) * 64;
  __shared__ char smem[3 * BUF];
  const int tid = threadIdx.x, wid = tid >> 6, lane = tid & 63;
  const int wrM = wid >> 1, wcN = wid & 1, l15 = lane & 15, l4 = lane >> 4;
  const int s_row = lane >> 2, s_kcp = lane & 3;
  const int rtile = blockIdx.x * 128;

  f32x4 acc[MB][4];
#pragma unroll
  for (int i = 0; i < MB; i++)
#pragma unroll
    for (int j = 0; j < 4; j++) acc[i][j] = (f32x4){0.f, 0.f, 0.f, 0.f};

  const int NKS = Ktot >> 5;
  auto stage = [&](char* buf, int ks) {
    const int k0 = ks * 32;
    const int sidx = ks >> 2, si0 = (ks & 3) * 32;
    const u16* sp = seg_sel(segs, sidx);
#pragma unroll
    for (int c = 0; c < R1; c++) {
      const int row0 = c * 64 + wid * 16;
      const int row = row0 + s_row;
      const u16* src;
      if (row0 < TM) src = WT + (long)row * Ktot + k0 + ((s_kcp ^ SWZ(row)) * 8);
      else { const int br = row - TM; src = sp + (long)(rtile + br) * 128 + si0 + ((s_kcp ^ SWZ(br)) * 8); }
      gl_lds16(src, buf + row0 * 64);
    }
  };
  auto compute = [&](char* buf) {
    char* Ab = buf; char* Bb = buf + TM * 64;
    bf16x8 af[MB], bfr[4];
#pragma unroll
    for (int mb = 0; mb < MB; mb++) {
      const int row = wrM * MW + mb * 16 + l15;
      af[mb] = *(const bf16x8*)(Ab + row * 64 + ((l4 ^ SWZ(row)) * 16));
    }
#pragma unroll
    for (int nb = 0; nb < 4; nb++) {
      const int row = wcN * 64 + nb * 16 + l15;
      bfr[nb] = *(const bf16x8*)(Bb + row * 64 + ((l4 ^ SWZ(row)) * 16));
    }
    __builtin_amdgcn_s_setprio(1);
#pragma unroll
    for (int mb = 0; mb < MB; mb++)
#pragma unroll
      for (int nb = 0; nb < 4; nb++)
        acc[mb][nb] = mfma16(af[mb], bfr[nb], acc[mb][nb]);
    __builtin_amdgcn_s_setprio(0);
  };

  stage(smem, 0);
  stage(smem + BUF, 1);
  char* cur = smem; char* mid = smem + BUF; char* fut = smem + 2 * BUF;
  for (int ks = 0; ks + 2 < NKS; ks++) {
    stage(fut, ks + 2);
    if constexpr (R1 == 6) asm volatile("s_waitcnt vmcnt(12)" ::: "memory");
    else                   asm volatile("s_waitcnt vmcnt(8)" ::: "memory");
    __builtin_amdgcn_s_barrier();
    __builtin_amdgcn_sched_barrier(0);
    compute(cur);
    asm volatile("" ::: "memory");
    __builtin_amdgcn_s_barrier();
    __builtin_amdgcn_sched_barrier(0);
    char* t = cur; cur = mid; mid = fut; fut = t;
  }
  if constexpr (R1 == 6) asm volatile("s_waitcnt vmcnt(6)" ::: "memory");
  else                   asm volatile("s_waitcnt vmcnt(4)" ::: "memory");
  __builtin_amdgcn_s_barrier();
  __builtin_amdgcn_sched_barrier(0);
  compute(cur);
  asm volatile("s_waitcnt vmcnt(0)" ::: "memory");
  __builtin_amdgcn_s_barrier();
  __builtin_amdgcn_sched_barrier(0);
  compute(mid);

#pragma unroll
  for (int mb = 0; mb < MB; mb++) {
#pragma unroll
    for (int nb = 0; nb < 4; nb++) {
      const int o = wrM * MW + mb * 16 + l4 * 4;
      const int rr = rtile + wcN * 64 + nb * 16 + l15;
      const int n = rr & 1023, b = rr >> 10;
      f32x4 v = acc[mb][nb];
      float4 bv = *(const float4*)(bias + o);
      float a0 = 0.f, a1 = 0.f, a2 = 0.f, a3 = 0.f;
      if (xadd != nullptr) {
        const int xs = (EPI == 0) ? 256 : 128;
        u32x2 xv = *(const u32x2*)(xadd + (long)rr * xs + o);
        a0 = bf2f((u16)(xv[0] & 0xffffu)); a1 = bf2f((u16)(xv[0] >> 16));
        a2 = bf2f((u16)(xv[1] & 0xffffu)); a3 = bf2f((u16)(xv[1] >> 16));
      }
      if (EPI == 0) {
        float s0 = sigm(v[0] + bv.x + a0), s1 = sigm(v[1] + bv.y + a1);
        float s2 = sigm(v[2] + bv.z + a2), s3 = sigm(v[3] + bv.w + a3);
        if (o < 128) {
          float4 hv = *(const float4*)(Hprev + (long)rr * 128 + o);
          float r0 = s0 * hv.x, r1 = s1 * hv.y, r2 = s2 * hv.z, r3 = s3 * hv.w;
          u16 h0 = f2bf(r0), h1 = f2bf(r1), h2 = f2bf(r2), h3 = f2bf(r3);
          long d = (long)rr * 128 + o;
          u32x2 wh; wh[0] = (u32)h0 | ((u32)h1 << 16); wh[1] = (u32)h2 | ((u32)h3 << 16);
          *(u32x2*)(rh_hi + d) = wh;
          u16* rt = rh_t + (long)(b * 128 + o) * 1024 + n;
          rt[0] = h0; rt[1024] = h1; rt[2048] = h2; rt[3072] = h3;
        } else {
          u32x2 wu; wu[0] = pk2bf(s0, s1); wu[1] = pk2bf(s2, s3);
          *(u32x2*)(usig + (long)rr * 128 + (o - 128)) = wu;
        }
      } else {
        float c0 = tanh_(v[0] + bv.x + a0), c1 = tanh_(v[1] + bv.y + a1);
        float c2 = tanh_(v[2] + bv.z + a2), c3 = tanh_(v[3] + bv.w + a3);
        u32x2 uv = *(const u32x2*)(usig + (long)rr * 128 + o);
        float u0 = bf2f((u16)(uv[0] & 0xffffu)), u1 = bf2f((u16)(uv[0] >> 16));
        float u2 = bf2f((u16)(uv[1] & 0xffffu)), u3 = bf2f((u16)(uv[1] >> 16));
        float4 hv = *(const float4*)(Hprev + (long)rr * 128 + o);
        float h0n = u0 * hv.x + (1.f - u0) * c0;
        float h1n = u1 * hv.y + (1.f - u1) * c1;
        float h2n = u2 * hv.z + (1.f - u2) * c2;
        float h3n = u3 * hv.w + (1.f - u3) * c3;
        *(float4*)(hnew_out + (long)rr * 128 + o) = make_float4(h0n, h1n, h2n, h3n);
        if (xa_hi != nullptr) {
          u16 x0 = f2bf(h0n), x1 = f2bf(h1n), x2 = f2bf(h2n), x3 = f2bf(h3n);
          long d = (long)rr * 128 + o;
          u32x2 wh; wh[0] = (u32)x0 | ((u32)x1 << 16); wh[1] = (u32)x2 | ((u32)x3 << 16);
          *(u32x2*)(xa_hi + d) = wh;
          u16* xt = xa_t + (long)(b * 128 + o) * 1024 + n;
          xt[0] = x0; xt[1024] = x1; xt[2048] = x2; xt[3072] = x3;
        }
      }
    }
  }
}

// ---------- projection ----------
__global__ __launch_bounds__(256) void proj_k(const float* __restrict__ h1n, const float* __restrict__ pw,
                                              const float* __restrict__ pb, float* __restrict__ out) {
  int wid = threadIdx.x >> 6, lane = threadIdx.x & 63;
  int r = blockIdx.x * 4 + wid;
  int b = r >> 10, n = r & 1023;
  const float* hp = h1n + (long)b * 131072 + n * 128;
  float ha = hp[lane], hb = hp[lane + 64];
  float p0 = ha * pw[lane * 2]     + hb * pw[(lane + 64) * 2];
  float p1 = ha * pw[lane * 2 + 1] + hb * pw[(lane + 64) * 2 + 1];
  for (int off = 32; off; off >>= 1) { p0 += __shfl_down(p0, off); p1 += __shfl_down(p1, off); }
  if (!lane) {
    out[(long)b * 2048 + n * 2]     = p0 + pb[0];
    out[(long)b * 2048 + n * 2 + 1] = p1 + pb[1];
  }
}

// ---------- host ----------
extern "C" void kernel_launch(void* const* d_in, const int* in_sizes, int n_in,
                              void* d_out, int out_size, void* d_ws, size_t ws_size,
                              hipStream_t stream) {
  (void)in_sizes; (void)n_in; (void)out_size; (void)ws_size;
  const float* inputs = (const float*)d_in[0];
  const float* hidden = (const float*)d_in[1];
  const float* adj    = (const float*)d_in[2];
  const float* gw0 = (const float*)d_in[3];
  const float* gb0 = (const float*)d_in[4];
  const float* cw0 = (const float*)d_in[5];
  const float* cb0 = (const float*)d_in[6];
  const float* gw1 = (const float*)d_in[7];
  const float* gb1 = (const float*)d_in[8];
  const float* cw1 = (const float*)d_in[9];
  const float* cb1 = (const float*)d_in[10];
  const float* pw  = (const float*)d_in[11];
  const float* pb  = (const float*)d_in[12];

  float* out    = (float*)d_out;
  float* out_h0 = out + 131072;
  float* out_h1 = out_h0 + 8388608;
  const float* h0 = hidden;
  const float* h1 = hidden + 8388608;

  u16* OH1a = (u16*)out_h1;            // h1 hiN (dead after GATE1; CAND1 overwrites region)

  char* wp = (char*)d_ws;
  auto alloc = [&](size_t bytes) { char* r = wp; wp += (bytes + 255) & ~(size_t)255; return r; };
  u16*   S0b  = (u16*)  alloc(1048576 * 2);
  u16*   S1b  = (u16*)  alloc(1048576 * 2);
  float* rs   = (float*)alloc(1024 * 4);
  float* cs   = (float*)alloc(1024 * 4);
  u16*   WG0  = (u16*)  alloc((size_t)256 * 640 * 2);
  u16*   WC0  = (u16*)  alloc((size_t)128 * 640 * 2);
  u16*   WG1  = (u16*)  alloc((size_t)256 * 1280 * 2);
  u16*   WC1  = (u16*)  alloc((size_t)128 * 1280 * 2);
  u16*   Bb   = (u16*)  alloc((size_t)13 * 8388608 * 2);   // 13 chain slots
  u16*   USIG = (u16*)  alloc((size_t)8388608 * 2);
  float* XCH  = (float*)alloc((size_t)5 * 131072 * 4);
  auto BB = [&](int i) { return Bb + (size_t)i * 8388608; };
  auto XC = [&](int i) { return XCH + (size_t)i * 131072; };
  u16* XGg = BB(3);   // spans slots 3,4 (33.5 MB)
  u16* XGc = BB(5);

  // prep
  sums_k<<<1040, 256, 0, stream>>>(adj, rs, cs);
  s0_build<<<dim3(32, 32), 256, 0, stream>>>(adj, rs, S0b);
  s1_build<<<4096, 256, 0, stream>>>(adj, cs, S1b);
  pack_w<<<640,  256, 0, stream>>>(gw0, WG0, 256, 640, 2, 0);
  pack_w<<<320,  256, 0, stream>>>(cw0, WC0, 128, 640, 2, 0);
  pack_w<<<1280, 256, 0, stream>>>(gw1, WG1, 256, 1280, 0, 128);
  pack_w<<<640,  256, 0, stream>>>(cw1, WC1, 128, 1280, 0, 128);
  build_hx<<<dim3(32, 4, 64), 256, 0, stream>>>(h0, BB(0), BB(1));     // h0_hiN=A, h0T=B
  build_hx<<<dim3(32, 4, 64), 256, 0, stream>>>(h1, OH1a, BB(2));      // h1_hiN, h1T=C

  // x-part exact chains + additive preacts
  xch0_build<<<512, 256, 0, stream>>>(inputs, XC(0));
  xch_diffuse<<<1024, 128, 0, stream>>>(S0b, XC(0), XC(1));
  xch_cheb   <<<1024, 128, 0, stream>>>(S0b, XC(1), XC(0), XC(2));
  xch_diffuse<<<1024, 128, 0, stream>>>(S1b, XC(0), XC(3));
  xch_cheb   <<<1024, 128, 0, stream>>>(S1b, XC(3), XC(0), XC(4));
  xg_build<<<2048, 256, 0, stream>>>(gw0, cw0, XCH, XGg, XGc);

  DiffJobs dj{};
  // L0 s-chains: s1=S0*h0T -> N:BB6,T:BB7 ; s3=S1*h0T -> N:BB8,T:BB9
  dj.j[0] = {BB(1), S0b, BB(6), BB(7)};
  dj.j[1] = {BB(1), S1b, BB(8), BB(9)};
  gemm_diffz<<<dim3(64, 4, 2), 256, 0, stream>>>(dj);
  // s2=S0*s1T -> BB10 ; s4=S1*s3T -> BB11
  dj.j[0] = {BB(7), S0b, BB(10), nullptr};
  dj.j[1] = {BB(9), S1b, BB(11), nullptr};
  gemm_diffz<<<dim3(64, 4, 2), 256, 0, stream>>>(dj);

  // GATE0: segs {h0, s1, s2, s3, s4}; rh_hi->BB12, rhT->BB1 (h0T dead)
  Segs sg0{};
  sg0.p[0] = BB(0); sg0.p[1] = BB(6); sg0.p[2] = BB(10); sg0.p[3] = BB(8); sg0.p[4] = BB(11);
  gemm_wseg<0><<<512, 256, 0, stream>>>(sg0, WG0, 640, gb0, h0, XGg,
      BB(12), BB(1), USIG, nullptr, nullptr, nullptr);

  // L0 c-chains (rhT=BB1): c1 -> N:BB6,T:BB7 ; c3 -> N:BB8,T:BB9
  dj.j[0] = {BB(1), S0b, BB(6), BB(7)};
  dj.j[1] = {BB(1), S1b, BB(8), BB(9)};
  gemm_diffz<<<dim3(64, 4, 2), 256, 0, stream>>>(dj);
  // c2 -> BB10 ; c4 -> BB11
  dj.j[0] = {BB(7), S0b, BB(10), nullptr};
  dj.j[1] = {BB(9), S1b, BB(11), nullptr};
  gemm_diffz<<<dim3(64, 4, 2), 256, 0, stream>>>(dj);

  // CAND0: segs {rh, c1, c2, c3, c4}; out_h0; xa_hi->BB0 (h0 dead), xaT->BB1 (rhT dead)
  Segs sc0{};
  sc0.p[0] = BB(12); sc0.p[1] = BB(6); sc0.p[2] = BB(10); sc0.p[3] = BB(8); sc0.p[4] = BB(11);
  gemm_wseg<1><<<512, 256, 0, stream>>>(sc0, WC0, 640, cb0, h0, XGc,
      nullptr, nullptr, USIG, out_h0, BB(0), BB(1));

  // L1 wave-1 (z=4; XGg/XGc dead -> BB3,BB4,BB5 free):
  dj.j[0] = {BB(1), S0b, BB(3), BB(4)};
  dj.j[1] = {BB(1), S1b, BB(5), BB(6)};
  dj.j[2] = {BB(2), S0b, BB(7), BB(8)};
  dj.j[3] = {BB(2), S1b, BB(9), BB(10)};
  gemm_diffz<<<dim3(64, 4, 4), 256, 0, stream>>>(dj);
  // s2'=S0*s1'T -> BB11 ; s4'=S1*s3'T -> BB12 (rh0 dead)
  dj.j[0] = {BB(4), S0b, BB(11), nullptr};
  dj.j[1] = {BB(6), S1b, BB(12), nullptr};
  gemm_diffz<<<dim3(64, 4, 2), 256, 0, stream>>>(dj);
  // t2=S0*t1T -> BB4 (s1'T dead) ; t4=S1*t3T -> BB6 (s3'T dead)
  dj.j[0] = {BB(8), S0b, BB(4), nullptr};
  dj.j[1] = {BB(10), S1b, BB(6), nullptr};
  gemm_diffz<<<dim3(64, 4, 2), 256, 0, stream>>>(dj);

  // GATE1: segs x{xa, s1', s2', s3', s4'} h{h1, t1, t2, t3, t4}; rh1_hi->BB8, rh1T->BB10
  Segs sg1{};
  sg1.p[0] = BB(0); sg1.p[1] = BB(3); sg1.p[2] = BB(11); sg1.p[3] = BB(5); sg1.p[4] = BB(12);
  sg1.p[5] = OH1a;  sg1.p[6] = BB(7); sg1.p[7] = BB(4);  sg1.p[8] = BB(9); sg1.p[9] = BB(6);
  gemm_wseg<0><<<512, 256, 0, stream>>>(sg1, WG1, 1280, gb1, h1, nullptr,
      BB(8), BB(10), USIG, nullptr, nullptr, nullptr);

  // L1 d-chains (rh1T=BB10): d1 -> N:BB1,T:BB2 ; d3 -> N:BB7,T:BB9
  dj.j[0] = {BB(10), S0b, BB(1), BB(2)};
  dj.j[1] = {BB(10), S1b, BB(7), BB(9)};
  gemm_diffz<<<dim3(64, 4, 2), 256, 0, stream>>>(dj);
  // d2=S0*d1T -> BB4 ; d4=S1*d3T -> BB6
  dj.j[0] = {BB(2), S0b, BB(4), nullptr};
  dj.j[1] = {BB(9), S1b, BB(6), nullptr};
  gemm_diffz<<<dim3(64, 4, 2), 256, 0, stream>>>(dj);

  // CAND1: segs x{xa, s1', s2', s3', s4'} rh{rh1, d1, d2, d3, d4}; -> out_h1
  Segs sc1{};
  sc1.p[0] = BB(0); sc1.p[1] = BB(3); sc1.p[2] = BB(11); sc1.p[3] = BB(5); sc1.p[4] = BB(12);
  sc1.p[5] = BB(8); sc1.p[6] = BB(1); sc1.p[7] = BB(4);  sc1.p[8] = BB(7); sc1.p[9] = BB(6);
  gemm_wseg<1><<<512, 256, 0, stream>>>(sc1, WC1, 1280, cb1, h1, nullptr,
      nullptr, nullptr, USIG, out_h1, nullptr, nullptr);

  // projection
  proj_k<<<16384, 256, 0, stream>>>(out_h1, pw, pb, out);
}

// Round 14
// 961.477 us; speedup vs baseline: 1.2435x; 1.0693x over previous
//
#include <hip/hip_runtime.h>
#include <hip/hip_bf16.h>

typedef unsigned short u16;
typedef unsigned int u32;
typedef __attribute__((ext_vector_type(2))) unsigned int u32x2;
typedef __attribute__((ext_vector_type(4))) float f32x4;
typedef __attribute__((ext_vector_type(8))) __bf16 bf16x8;

#define DEVI static __device__ __forceinline__

// ---------- scalar helpers ----------
DEVI u16 f2bf(float x) {
  union { float f; u32 u; } v; v.f = x;
  u32 r = v.u + 0x7fffu + ((v.u >> 16) & 1u);
  return (u16)(r >> 16);
}
DEVI float bf2f(u16 h) { union { u32 u; float f; } v; v.u = ((u32)h) << 16; return v.f; }
DEVI u32 pk2bf(float a, float b) { return (u32)f2bf(a) | ((u32)f2bf(b) << 16); }
DEVI float sigm(float x) { return 1.f / (1.f + __expf(-x)); }
DEVI float tanh_(float x) {
  float a = fabsf(x);
  float e = __expf(-2.f * a);
  float t = (1.f - e) / (1.f + e);
  return copysignf(t, x);
}

DEVI void gl_lds16(const u16* g, void* l) {
  __builtin_amdgcn_global_load_lds(
      (const __attribute__((address_space(1))) u32*)(const void*)g,
      (__attribute__((address_space(3))) u32*)l, 16, 0, 0);
}
DEVI f32x4 mfma16(bf16x8 a, bf16x8 b, f32x4 c) {
  return __builtin_amdgcn_mfma_f32_16x16x32_bf16(a, b, c, 0, 0, 0);
}

// 64B-row LDS swizzle key (R8-proven: zero conflicts).
#define SWZ(row) (((row) >> 1) & 3)

// ---------- prep kernels ----------
__global__ void sums_k(const float* __restrict__ adj, float* __restrict__ rs, float* __restrict__ cs) {
  __shared__ float red[256];
  int bid = blockIdx.x, tid = threadIdx.x;
  if (bid < 1024) {
    float a = 0.f;
    for (int j = tid; j < 1024; j += 256) a += adj[bid * 1024 + j];
    red[tid] = a; __syncthreads();
    for (int s = 128; s; s >>= 1) { if (tid < s) red[tid] += red[tid + s]; __syncthreads(); }
    if (!tid) rs[bid] = red[0];
  } else {
    int c0 = (bid - 1024) * 64;
    int c = tid & 63, r0 = tid >> 6;
    float a = 0.f;
    for (int r = r0; r < 1024; r += 4) a += adj[r * 1024 + c0 + c];
    red[tid] = a; __syncthreads();
    if (tid < 64) cs[c0 + c] = red[c] + red[64 + c] + red[128 + c] + red[192 + c];
  }
}

__global__ void s0_build(const float* __restrict__ adj, const float* __restrict__ rs, u16* __restrict__ S0) {
  __shared__ float tile[32][33];
  int i0 = blockIdx.x * 32, j0 = blockIdx.y * 32;
  int tx = threadIdx.x & 31, ty = threadIdx.x >> 5;
  for (int yy = ty; yy < 32; yy += 8)
    tile[yy][tx] = adj[(j0 + yy) * 1024 + i0 + tx];
  __syncthreads();
  for (int yy = ty; yy < 32; yy += 8)
    S0[(i0 + yy) * 1024 + j0 + tx] = f2bf(tile[tx][yy] / rs[j0 + tx]);
}

__global__ void s1_build(const float* __restrict__ adj, const float* __restrict__ cs, u16* __restrict__ S1) {
  int idx = blockIdx.x * 256 + threadIdx.x;
  int j = idx & 1023;
  S1[idx] = f2bf(adj[idx] / cs[j]);
}

// pack weights with cheb-fold; 5 segs per part: 0->W0-W2-W4, 1->W1, 2->2W2, 3->W3, 4->2W4
__global__ void pack_w(const float* __restrict__ src, u16* __restrict__ dst,
                       int NO, int Ktot, int off0, int off1) {
  int idx = blockIdx.x * 256 + threadIdx.x;
  if (idx >= NO * Ktot) return;
  int o = idx / Ktot, k = idx % Ktot;
  int seg = k >> 7, i = k & 127;
  int mo = seg % 5;
  int pos = ((seg / 5) ? off1 : off0) + i;
  const float* wr = src + (long)pos * 5 * NO + o;
  float v;
  switch (mo) {
    case 0: v = wr[0] - wr[(long)2 * NO] - wr[(long)4 * NO]; break;
    case 1: v = wr[(long)1 * NO]; break;
    case 2: v = 2.f * wr[(long)2 * NO]; break;
    case 3: v = wr[(long)3 * NO]; break;
    default: v = 2.f * wr[(long)4 * NO]; break;
  }
  dst[idx] = f2bf(v);
}

// h (B, N*128) fp32 -> hiN flat [r=b*1024+n][u] bf16 + hiT [b*128+u][n]
__global__ void build_hx(const float* __restrict__ src, u16* __restrict__ hiN,
                         u16* __restrict__ hiT) {
  __shared__ u16 t[32][33];
  int n0 = blockIdx.x * 32, u0 = blockIdx.y * 32, b = blockIdx.z;
  int tx = threadIdx.x & 31, ty = threadIdx.x >> 5;
  for (int yy = ty; yy < 32; yy += 8) {
    long d = (long)b * 131072 + (n0 + yy) * 128 + u0 + tx;
    u16 h = f2bf(src[d]);
    hiN[d] = h;
    t[yy][tx] = h;
  }
  __syncthreads();
  for (int yy = ty; yy < 32; yy += 8)
    hiT[(long)(b * 128 + u0 + yy) * 1024 + n0 + tx] = t[tx][yy];
}

// ---------- x-part (layer 0): exact fp32 path ----------
__global__ void xch0_build(const float* __restrict__ inp, float* __restrict__ x0) {
  int idx = blockIdx.x * 256 + threadIdx.x;
  int n = idx >> 7, c = idx & 127, b = c >> 1, d = c & 1;
  x0[idx] = inp[b * 2048 + n * 2 + d];
}

// z-fused x-chain step: xout = S@xin (x0==nullptr) or 2*(S@xin)-x0
struct XJob { const u16* S; const float* xin; const float* x0; float* xout; };
struct XJobs { XJob j[2]; };
__global__ void xch_step2(XJobs js) {
  XJob J = js.j[blockIdx.z];
  int n = blockIdx.x, c = threadIdx.x;
  float acc = 0.f;
  for (int k = 0; k < 1024; k++) acc += bf2f(J.S[n * 1024 + k]) * J.xin[k * 128 + c];
  J.xout[n * 128 + c] = (J.x0 != nullptr) ? (2.f * acc - J.x0[n * 128 + c]) : acc;
}

// XG[r][o], r = b*1024+n; W staged in LDS once per block, 32 rows/block.
__global__ __launch_bounds__(256) void xg_build(
    const float* __restrict__ gw0, const float* __restrict__ cw0,
    const float* __restrict__ xch,
    u16* __restrict__ xgg, u16* __restrict__ xgc) {
  __shared__ float wg[10][256];
  __shared__ float wc[10][128];
  __shared__ float xv[10];
  int t = threadIdx.x;
#pragma unroll
  for (int q = 0; q < 10; q++) {
    int m = q % 5, p = q / 5;
    wg[q][t] = gw0[(long)(p * 5 + m) * 256 + t];
    if (t < 128) wc[q][t] = cw0[(long)(p * 5 + m) * 128 + t];
  }
  __syncthreads();
  int r0 = blockIdx.x * 32;
  for (int rl = 0; rl < 32; rl++) {
    int r = r0 + rl, n = r & 1023, b = r >> 10;
    if (t < 10) { int m = t % 5, p = t / 5; xv[t] = xch[(long)m * 131072 + n * 128 + b * 2 + p]; }
    __syncthreads();
    float a = 0.f;
#pragma unroll
    for (int q = 0; q < 10; q++) a += wg[q][t] * xv[q];
    xgg[(long)r * 256 + t] = f2bf(a);
    if (t < 128) {
      float a2 = 0.f;
#pragma unroll
      for (int q = 0; q < 10; q++) a2 += wc[q][t] * xv[q];
      xgc[(long)r * 128 + t] = f2bf(a2);
    }
    __syncthreads();
  }
}

// ---------- fused diffusion GEMM (256n x 128f tile, 4 waves, BK=32, triple-buffered) ----------
struct DiffJob { const u16* X; const u16* S; u16* YN; u16* YT; };
struct DiffJobs { DiffJob j[4]; };

__global__ __launch_bounds__(256, 2) void gemm_diffz(DiffJobs jobs) {
  DiffJob J = jobs.j[blockIdx.z];
  constexpr int BUF = 384 * 64;
  __shared__ char smem[3 * BUF];
  const int tid = threadIdx.x, wid = tid >> 6, lane = tid & 63;
  const int wrM = wid >> 1, wcN = wid & 1, l15 = lane & 15, l4 = lane >> 4;
  const int s_row = lane >> 2, s_kcp = lane & 3;
  const int l = blockIdx.y * 64 + blockIdx.x;       // 0..255
  const int sl = (l & 7) * 32 + (l >> 3);
  const int fbase = (sl >> 2) * 128;
  const int ntile = (sl & 3) * 256;

  f32x4 acc[8][4];
#pragma unroll
  for (int i = 0; i < 8; i++)
#pragma unroll
    for (int j = 0; j < 4; j++) acc[i][j] = (f32x4){0.f, 0.f, 0.f, 0.f};

  auto stage = [&](char* buf, int ks) {
    const int k0 = ks * 32;
#pragma unroll
    for (int c = 0; c < 6; c++) {
      const int row0 = c * 64 + wid * 16;
      const int row = row0 + s_row;
      const u16* src;
      if (row0 < 256) src = J.S + (long)(ntile + row) * 1024 + k0 + ((s_kcp ^ SWZ(row)) * 8);
      else { const int fr = row - 256; src = J.X + (long)(fbase + fr) * 1024 + k0 + ((s_kcp ^ SWZ(fr)) * 8); }
      gl_lds16(src, buf + row0 * 64);
    }
  };
  auto compute = [&](char* buf) {
    char* Ab = buf; char* Bb = buf + 256 * 64;
    bf16x8 af[8], bfr[4];
#pragma unroll
    for (int mb = 0; mb < 8; mb++) {
      const int row = wrM * 128 + mb * 16 + l15;
      af[mb] = *(const bf16x8*)(Ab + row * 64 + ((l4 ^ SWZ(row)) * 16));
    }
#pragma unroll
    for (int nb = 0; nb < 4; nb++) {
      const int row = wcN * 64 + nb * 16 + l15;
      bfr[nb] = *(const bf16x8*)(Bb + row * 64 + ((l4 ^ SWZ(row)) * 16));
    }
    __builtin_amdgcn_s_setprio(1);
#pragma unroll
    for (int mb = 0; mb < 8; mb++)
#pragma unroll
      for (int nb = 0; nb < 4; nb++)
        acc[mb][nb] = mfma16(af[mb], bfr[nb], acc[mb][nb]);
    __builtin_amdgcn_s_setprio(0);
  };

  const int NKS = 32;
  stage(smem, 0);
  stage(smem + BUF, 1);
  char* cur = smem; char* mid = smem + BUF; char* fut = smem + 2 * BUF;
  for (int ks = 0; ks + 2 < NKS; ks++) {
    stage(fut, ks + 2);
    asm volatile("s_waitcnt vmcnt(12)" ::: "memory");
    __builtin_amdgcn_s_barrier();
    __builtin_amdgcn_sched_barrier(0);
    compute(cur);
    asm volatile("" ::: "memory");
    __builtin_amdgcn_s_barrier();
    __builtin_amdgcn_sched_barrier(0);
    char* t = cur; cur = mid; mid = fut; fut = t;
  }
  asm volatile("s_waitcnt vmcnt(6)" ::: "memory");
  __builtin_amdgcn_s_barrier();
  __builtin_amdgcn_sched_barrier(0);
  compute(cur);
  asm volatile("s_waitcnt vmcnt(0)" ::: "memory");
  __builtin_amdgcn_s_barrier();
  __builtin_amdgcn_sched_barrier(0);
  compute(mid);

#pragma unroll
  for (int mb = 0; mb < 8; mb++) {
#pragma unroll
    for (int nb = 0; nb < 4; nb++) {
      const int n0 = ntile + wrM * 128 + mb * 16 + l4 * 4;
      const int f  = fbase + wcN * 64 + nb * 16 + l15;
      const int b = f >> 7, u = f & 127;
      f32x4 v = acc[mb][nb];
      u16 h0 = f2bf(v[0]), h1 = f2bf(v[1]), h2 = f2bf(v[2]), h3 = f2bf(v[3]);
      u16* yn = J.YN + (long)b * 131072 + (long)n0 * 128 + u;
      yn[0] = h0; yn[128] = h1; yn[256] = h2; yn[384] = h3;
      if (J.YT != nullptr) {
        u32x2 wv; wv[0] = (u32)h0 | ((u32)h1 << 16); wv[1] = (u32)h2 | ((u32)h3 << 16);
        *(u32x2*)(J.YT + (long)f * 1024 + n0) = wv;
      }
    }
  }
}

// ---------- W GEMM with fused epilogue (M x 128 tile, 4 waves, BK=32, triple-buffered) ----------
struct Segs { const u16* p[10]; };
DEVI const u16* seg_sel(const Segs& s, int i) {
  switch (i) {
    case 0: return s.p[0]; case 1: return s.p[1]; case 2: return s.p[2];
    case 3: return s.p[3]; case 4: return s.p[4]; case 5: return s.p[5];
    case 6: return s.p[6]; case 7: return s.p[7]; case 8: return s.p[8];
    default: return s.p[9];
  }
}

template<int EPI>   // 0 = GATE (M=256), 1 = CAND (M=128)
__global__ __launch_bounds__(256, 2) void gemm_wseg(
    Segs segs, const u16* __restrict__ WT, int Ktot,
    const float* __restrict__ bias, const float* __restrict__ Hprev,
    const u16* __restrict__ Hb16,
    const u16* __restrict__ xadd,
    u16* __restrict__ rh_hi, u16* __restrict__ rh_t, u16* __restrict__ usig,
    float* __restrict__ hnew_out, u16* __restrict__ xa_hi, u16* __restrict__ xa_t)
{
  constexpr int TM = (EPI == 0) ? 256 : 128;
  constexpr int MB = (EPI == 0) ? 8 : 4;
  constexpr int MW = (EPI == 0) ? 128 : 64;
  constexpr int R1 = (TM + 128) / 64;
  constexpr int BUF = (TM + 128) * 64;
  __shared__ char smem[3 * BUF];
  const int tid = threadIdx.x, wid = tid >> 6, lane = tid & 63;
  const int wrM = wid >> 1, wcN = wid & 1, l15 = lane & 15, l4 = lane >> 4;
  const int s_row = lane >> 2, s_kcp = lane & 3;
  const int rtile = blockIdx.x * 128;

  f32x4 acc[MB][4];
#pragma unroll
  for (int i = 0; i < MB; i++)
#pragma unroll
    for (int j = 0; j < 4; j++) acc[i][j] = (f32x4){0.f, 0.f, 0.f, 0.f};

  const int NKS = Ktot >> 5;
  auto stage = [&](char* buf, int ks) {
    const int k0 = ks * 32;
    const int sidx = ks >> 2, si0 = (ks & 3) * 32;
    const u16* sp = seg_sel(segs, sidx);
#pragma unroll
    for (int c = 0; c < R1; c++) {
      const int row0 = c * 64 + wid * 16;
      const int row = row0 + s_row;
      const u16* src;
      if (row0 < TM) src = WT + (long)row * Ktot + k0 + ((s_kcp ^ SWZ(row)) * 8);
      else { const int br = row - TM; src = sp + (long)(rtile + br) * 128 + si0 + ((s_kcp ^ SWZ(br)) * 8); }
      gl_lds16(src, buf + row0 * 64);
    }
  };
  auto compute = [&](char* buf) {
    char* Ab = buf; char* Bb = buf + TM * 64;
    bf16x8 af[MB], bfr[4];
#pragma unroll
    for (int mb = 0; mb < MB; mb++) {
      const int row = wrM * MW + mb * 16 + l15;
      af[mb] = *(const bf16x8*)(Ab + row * 64 + ((l4 ^ SWZ(row)) * 16));
    }
#pragma unroll
    for (int nb = 0; nb < 4; nb++) {
      const int row = wcN * 64 + nb * 16 + l15;
      bfr[nb] = *(const bf16x8*)(Bb + row * 64 + ((l4 ^ SWZ(row)) * 16));
    }
    __builtin_amdgcn_s_setprio(1);
#pragma unroll
    for (int mb = 0; mb < MB; mb++)
#pragma unroll
      for (int nb = 0; nb < 4; nb++)
        acc[mb][nb] = mfma16(af[mb], bfr[nb], acc[mb][nb]);
    __builtin_amdgcn_s_setprio(0);
  };

  stage(smem, 0);
  stage(smem + BUF, 1);
  char* cur = smem; char* mid = smem + BUF; char* fut = smem + 2 * BUF;
  for (int ks = 0; ks + 2 < NKS; ks++) {
    stage(fut, ks + 2);
    if constexpr (R1 == 6) asm volatile("s_waitcnt vmcnt(12)" ::: "memory");
    else                   asm volatile("s_waitcnt vmcnt(8)" ::: "memory");
    __builtin_amdgcn_s_barrier();
    __builtin_amdgcn_sched_barrier(0);
    compute(cur);
    asm volatile("" ::: "memory");
    __builtin_amdgcn_s_barrier();
    __builtin_amdgcn_sched_barrier(0);
    char* t = cur; cur = mid; mid = fut; fut = t;
  }
  if constexpr (R1 == 6) asm volatile("s_waitcnt vmcnt(6)" ::: "memory");
  else                   asm volatile("s_waitcnt vmcnt(4)" ::: "memory");
  __builtin_amdgcn_s_barrier();
  __builtin_amdgcn_sched_barrier(0);
  compute(cur);
  asm volatile("s_waitcnt vmcnt(0)" ::: "memory");
  __builtin_amdgcn_s_barrier();
  __builtin_amdgcn_sched_barrier(0);
  compute(mid);

#pragma unroll
  for (int mb = 0; mb < MB; mb++) {
#pragma unroll
    for (int nb = 0; nb < 4; nb++) {
      const int o = wrM * MW + mb * 16 + l4 * 4;
      const int rr = rtile + wcN * 64 + nb * 16 + l15;
      const int n = rr & 1023, b = rr >> 10;
      f32x4 v = acc[mb][nb];
      float4 bv = *(const float4*)(bias + o);
      float a0 = 0.f, a1 = 0.f, a2 = 0.f, a3 = 0.f;
      if (xadd != nullptr) {
        const int xs = (EPI == 0) ? 256 : 128;
        u32x2 xv = *(const u32x2*)(xadd + (long)rr * xs + o);
        a0 = bf2f((u16)(xv[0] & 0xffffu)); a1 = bf2f((u16)(xv[0] >> 16));
        a2 = bf2f((u16)(xv[1] & 0xffffu)); a3 = bf2f((u16)(xv[1] >> 16));
      }
      // Hprev: bf16 path (cache-hot, halved bytes) or fp32 fallback
      float hx0, hx1, hx2, hx3;
      if (Hb16 != nullptr) {
        u32x2 hv2 = *(const u32x2*)(Hb16 + (long)rr * 128 + o);
        hx0 = bf2f((u16)(hv2[0] & 0xffffu)); hx1 = bf2f((u16)(hv2[0] >> 16));
        hx2 = bf2f((u16)(hv2[1] & 0xffffu)); hx3 = bf2f((u16)(hv2[1] >> 16));
      } else {
        float4 hv = *(const float4*)(Hprev + (long)rr * 128 + o);
        hx0 = hv.x; hx1 = hv.y; hx2 = hv.z; hx3 = hv.w;
      }
      if (EPI == 0) {
        float s0 = sigm(v[0] + bv.x + a0), s1 = sigm(v[1] + bv.y + a1);
        float s2 = sigm(v[2] + bv.z + a2), s3 = sigm(v[3] + bv.w + a3);
        if (o < 128) {
          float r0 = s0 * hx0, r1 = s1 * hx1, r2 = s2 * hx2, r3 = s3 * hx3;
          u16 h0 = f2bf(r0), h1 = f2bf(r1), h2 = f2bf(r2), h3 = f2bf(r3);
          long d = (long)rr * 128 + o;
          u32x2 wh; wh[0] = (u32)h0 | ((u32)h1 << 16); wh[1] = (u32)h2 | ((u32)h3 << 16);
          *(u32x2*)(rh_hi + d) = wh;
          u16* rt = rh_t + (long)(b * 128 + o) * 1024 + n;
          rt[0] = h0; rt[1024] = h1; rt[2048] = h2; rt[3072] = h3;
        } else {
          u32x2 wu; wu[0] = pk2bf(s0, s1); wu[1] = pk2bf(s2, s3);
          *(u32x2*)(usig + (long)rr * 128 + (o - 128)) = wu;
        }
      } else {
        float c0 = tanh_(v[0] + bv.x + a0), c1 = tanh_(v[1] + bv.y + a1);
        float c2 = tanh_(v[2] + bv.z + a2), c3 = tanh_(v[3] + bv.w + a3);
        u32x2 uv = *(const u32x2*)(usig + (long)rr * 128 + o);
        float u0 = bf2f((u16)(uv[0] & 0xffffu)), u1 = bf2f((u16)(uv[0] >> 16));
        float u2 = bf2f((u16)(uv[1] & 0xffffu)), u3 = bf2f((u16)(uv[1] >> 16));
        float h0n = u0 * hx0 + (1.f - u0) * c0;
        float h1n = u1 * hx1 + (1.f - u1) * c1;
        float h2n = u2 * hx2 + (1.f - u2) * c2;
        float h3n = u3 * hx3 + (1.f - u3) * c3;
        *(float4*)(hnew_out + (long)rr * 128 + o) = make_float4(h0n, h1n, h2n, h3n);
        if (xa_hi != nullptr) {
          u16 x0 = f2bf(h0n), x1 = f2bf(h1n), x2 = f2bf(h2n), x3 = f2bf(h3n);
          long d = (long)rr * 128 + o;
          u32x2 wh; wh[0] = (u32)x0 | ((u32)x1 << 16); wh[1] = (u32)x2 | ((u32)x3 << 16);
          *(u32x2*)(xa_hi + d) = wh;
          u16* xt = xa_t + (long)(b * 128 + o) * 1024 + n;
          xt[0] = x0; xt[1024] = x1; xt[2048] = x2; xt[3072] = x3;
        }
      }
    }
  }
}

// ---------- projection ----------
__global__ __launch_bounds__(256) void proj_k(const float* __restrict__ h1n, const float* __restrict__ pw,
                                              const float* __restrict__ pb, float* __restrict__ out) {
  int wid = threadIdx.x >> 6, lane = threadIdx.x & 63;
  int r = blockIdx.x * 4 + wid;
  int b = r >> 10, n = r & 1023;
  const float* hp = h1n + (long)b * 131072 + n * 128;
  float ha = hp[lane], hb = hp[lane + 64];
  float p0 = ha * pw[lane * 2]     + hb * pw[(lane + 64) * 2];
  float p1 = ha * pw[lane * 2 + 1] + hb * pw[(lane + 64) * 2 + 1];
  for (int off = 32; off; off >>= 1) { p0 += __shfl_down(p0, off); p1 += __shfl_down(p1, off); }
  if (!lane) {
    out[(long)b * 2048 + n * 2]     = p0 + pb[0];
    out[(long)b * 2048 + n * 2 + 1] = p1 + pb[1];
  }
}

// ---------- host ----------
extern "C" void kernel_launch(void* const* d_in, const int* in_sizes, int n_in,
                              void* d_out, int out_size, void* d_ws, size_t ws_size,
                              hipStream_t stream) {
  (void)in_sizes; (void)n_in; (void)out_size; (void)ws_size;
  const float* inputs = (const float*)d_in[0];
  const float* hidden = (const float*)d_in[1];
  const float* adj    = (const float*)d_in[2];
  const float* gw0 = (const float*)d_in[3];
  const float* gb0 = (const float*)d_in[4];
  const float* cw0 = (const float*)d_in[5];
  const float* cb0 = (const float*)d_in[6];
  const float* gw1 = (const float*)d_in[7];
  const float* gb1 = (const float*)d_in[8];
  const float* cw1 = (const float*)d_in[9];
  const float* cb1 = (const float*)d_in[10];
  const float* pw  = (const float*)d_in[11];
  const float* pb  = (const float*)d_in[12];

  float* out    = (float*)d_out;
  float* out_h0 = out + 131072;
  float* out_h1 = out_h0 + 8388608;
  const float* h0 = hidden;
  const float* h1 = hidden + 8388608;

  u16* OH1a = (u16*)out_h1;            // h1 hiN (dead after GATE1; CAND1 overwrites region)

  char* wp = (char*)d_ws;
  auto alloc = [&](size_t bytes) { char* r = wp; wp += (bytes + 255) & ~(size_t)255; return r; };
  u16*   S0b  = (u16*)  alloc(1048576 * 2);
  u16*   S1b  = (u16*)  alloc(1048576 * 2);
  float* rs   = (float*)alloc(1024 * 4);
  float* cs   = (float*)alloc(1024 * 4);
  u16*   WG0  = (u16*)  alloc((size_t)256 * 640 * 2);
  u16*   WC0  = (u16*)  alloc((size_t)128 * 640 * 2);
  u16*   WG1  = (u16*)  alloc((size_t)256 * 1280 * 2);
  u16*   WC1  = (u16*)  alloc((size_t)128 * 1280 * 2);
  u16*   Bb   = (u16*)  alloc((size_t)13 * 8388608 * 2);   // 13 chain slots
  u16*   USIG = (u16*)  alloc((size_t)8388608 * 2);
  float* XCH  = (float*)alloc((size_t)5 * 131072 * 4);
  auto BB = [&](int i) { return Bb + (size_t)i * 8388608; };
  auto XC = [&](int i) { return XCH + (size_t)i * 131072; };
  u16* XGg = BB(3);   // spans slots 3,4 (33.5 MB)
  u16* XGc = BB(5);

  // prep
  sums_k<<<1040, 256, 0, stream>>>(adj, rs, cs);
  s0_build<<<dim3(32, 32), 256, 0, stream>>>(adj, rs, S0b);
  s1_build<<<4096, 256, 0, stream>>>(adj, cs, S1b);
  pack_w<<<640,  256, 0, stream>>>(gw0, WG0, 256, 640, 2, 0);
  pack_w<<<320,  256, 0, stream>>>(cw0, WC0, 128, 640, 2, 0);
  pack_w<<<1280, 256, 0, stream>>>(gw1, WG1, 256, 1280, 0, 128);
  pack_w<<<640,  256, 0, stream>>>(cw1, WC1, 128, 1280, 0, 128);
  build_hx<<<dim3(32, 4, 64), 256, 0, stream>>>(h0, BB(0), BB(1));     // h0_hiN=A, h0T=B
  build_hx<<<dim3(32, 4, 64), 256, 0, stream>>>(h1, OH1a, BB(2));      // h1_hiN, h1T=C

  // x-part exact chains (z-fused pairs) + additive preacts
  xch0_build<<<512, 256, 0, stream>>>(inputs, XC(0));
  XJobs xj{};
  xj.j[0] = {S0b, XC(0), nullptr, XC(1)};
  xj.j[1] = {S1b, XC(0), nullptr, XC(3)};
  xch_step2<<<dim3(1024, 1, 2), 128, 0, stream>>>(xj);
  xj.j[0] = {S0b, XC(1), XC(0), XC(2)};
  xj.j[1] = {S1b, XC(3), XC(0), XC(4)};
  xch_step2<<<dim3(1024, 1, 2), 128, 0, stream>>>(xj);
  xg_build<<<2048, 256, 0, stream>>>(gw0, cw0, XCH, XGg, XGc);

  DiffJobs dj{};
  // L0 s-chains: s1=S0*h0T -> N:BB6,T:BB7 ; s3=S1*h0T -> N:BB8,T:BB9
  dj.j[0] = {BB(1), S0b, BB(6), BB(7)};
  dj.j[1] = {BB(1), S1b, BB(8), BB(9)};
  gemm_diffz<<<dim3(64, 4, 2), 256, 0, stream>>>(dj);
  // s2=S0*s1T -> BB10 ; s4=S1*s3T -> BB11
  dj.j[0] = {BB(7), S0b, BB(10), nullptr};
  dj.j[1] = {BB(9), S1b, BB(11), nullptr};
  gemm_diffz<<<dim3(64, 4, 2), 256, 0, stream>>>(dj);

  // GATE0: segs {h0, s1, s2, s3, s4}; Hb16=BB0; rh_hi->BB12, rhT->BB1 (h0T dead)
  Segs sg0{};
  sg0.p[0] = BB(0); sg0.p[1] = BB(6); sg0.p[2] = BB(10); sg0.p[3] = BB(8); sg0.p[4] = BB(11);
  gemm_wseg<0><<<512, 256, 0, stream>>>(sg0, WG0, 640, gb0, h0, BB(0), XGg,
      BB(12), BB(1), USIG, nullptr, nullptr, nullptr);

  // L0 c-chains (rhT=BB1): c1 -> N:BB6,T:BB7 ; c3 -> N:BB8,T:BB9
  dj.j[0] = {BB(1), S0b, BB(6), BB(7)};
  dj.j[1] = {BB(1), S1b, BB(8), BB(9)};
  gemm_diffz<<<dim3(64, 4, 2), 256, 0, stream>>>(dj);
  // c2 -> BB10 ; c4 -> BB11
  dj.j[0] = {BB(7), S0b, BB(10), nullptr};
  dj.j[1] = {BB(9), S1b, BB(11), nullptr};
  gemm_diffz<<<dim3(64, 4, 2), 256, 0, stream>>>(dj);

  // CAND0: segs {rh, c1, c2, c3, c4}; Hb16=BB0 (read-then-write same element: safe);
  // out_h0; xa_hi->BB0, xaT->BB1
  Segs sc0{};
  sc0.p[0] = BB(12); sc0.p[1] = BB(6); sc0.p[2] = BB(10); sc0.p[3] = BB(8); sc0.p[4] = BB(11);
  gemm_wseg<1><<<512, 256, 0, stream>>>(sc0, WC0, 640, cb0, h0, BB(0), XGc,
      nullptr, nullptr, USIG, out_h0, BB(0), BB(1));

  // L1 wave-1 (z=4; XGg/XGc dead -> BB3,BB4,BB5 free):
  dj.j[0] = {BB(1), S0b, BB(3), BB(4)};
  dj.j[1] = {BB(1), S1b, BB(5), BB(6)};
  dj.j[2] = {BB(2), S0b, BB(7), BB(8)};
  dj.j[3] = {BB(2), S1b, BB(9), BB(10)};
  gemm_diffz<<<dim3(64, 4, 4), 256, 0, stream>>>(dj);
  // s2'=S0*s1'T -> BB11 ; s4'=S1*s3'T -> BB12 (rh0 dead)
  dj.j[0] = {BB(4), S0b, BB(11), nullptr};
  dj.j[1] = {BB(6), S1b, BB(12), nullptr};
  gemm_diffz<<<dim3(64, 4, 2), 256, 0, stream>>>(dj);
  // t2=S0*t1T -> BB4 (s1'T dead) ; t4=S1*t3T -> BB6 (s3'T dead)
  dj.j[0] = {BB(8), S0b, BB(4), nullptr};
  dj.j[1] = {BB(10), S1b, BB(6), nullptr};
  gemm_diffz<<<dim3(64, 4, 2), 256, 0, stream>>>(dj);

  // GATE1: segs x{xa, s1', s2', s3', s4'} h{h1, t1, t2, t3, t4}; Hb16=OH1a;
  // rh1_hi->BB8 (t1T dead), rh1T->BB10 (t3T dead)
  Segs sg1{};
  sg1.p[0] = BB(0); sg1.p[1] = BB(3); sg1.p[2] = BB(11); sg1.p[3] = BB(5); sg1.p[4] = BB(12);
  sg1.p[5] = OH1a;  sg1.p[6] = BB(7); sg1.p[7] = BB(4);  sg1.p[8] = BB(9); sg1.p[9] = BB(6);
  gemm_wseg<0><<<512, 256, 0, stream>>>(sg1, WG1, 1280, gb1, h1, OH1a, nullptr,
      BB(8), BB(10), USIG, nullptr, nullptr, nullptr);

  // L1 d-chains (rh1T=BB10): d1 -> N:BB1,T:BB2 ; d3 -> N:BB7,T:BB9
  dj.j[0] = {BB(10), S0b, BB(1), BB(2)};
  dj.j[1] = {BB(10), S1b, BB(7), BB(9)};
  gemm_diffz<<<dim3(64, 4, 2), 256, 0, stream>>>(dj);
  // d2=S0*d1T -> BB4 ; d4=S1*d3T -> BB6
  dj.j[0] = {BB(2), S0b, BB(4), nullptr};
  dj.j[1] = {BB(9), S1b, BB(6), nullptr};
  gemm_diffz<<<dim3(64, 4, 2), 256, 0, stream>>>(dj);

  // CAND1: segs x{xa, s1', s2', s3', s4'} rh{rh1, d1, d2, d3, d4}; Hb16=nullptr
  // (bf16 h1 aliases out_h1 region at different byte offsets -> fp32 read required)
  Segs sc1{};
  sc1.p[0] = BB(0); sc1.p[1] = BB(3); sc1.p[2] = BB(11); sc1.p[3] = BB(5); sc1.p[4] = BB(12);
  sc1.p[5] = BB(8); sc1.p[6] = BB(1); sc1.p[7] = BB(4);  sc1.p[8] = BB(7); sc1.p[9] = BB(6);
  gemm_wseg<1><<<512, 256, 0, stream>>>(sc1, WC1, 1280, cb1, h1, nullptr, nullptr,
      nullptr, nullptr, USIG, out_h1, nullptr, nullptr);

  // projection
  proj_k<<<16384, 256, 0, stream>>>(out_h1, pw, pb, out);
}

// Round 15
// 922.054 us; speedup vs baseline: 1.2966x; 1.0428x over previous
//
#include <hip/hip_runtime.h>
#include <hip/hip_bf16.h>

typedef unsigned short u16;
typedef unsigned int u32;
typedef __attribute__((ext_vector_type(2))) unsigned int u32x2;
typedef __attribute__((ext_vector_type(4))) float f32x4;
typedef __attribute__((ext_vector_type(8))) __bf16 bf16x8;

#define DEVI static __device__ __forceinline__

// ---------- scalar helpers ----------
DEVI u16 f2bf(float x) {
  union { float f; u32 u; } v; v.f = x;
  u32 r = v.u + 0x7fffu + ((v.u >> 16) & 1u);
  return (u16)(r >> 16);
}
DEVI float bf2f(u16 h) { union { u32 u; float f; } v; v.u = ((u32)h) << 16; return v.f; }
DEVI u32 pk2bf(float a, float b) { return (u32)f2bf(a) | ((u32)f2bf(b) << 16); }
DEVI float sigm(float x) { return 1.f / (1.f + __expf(-x)); }
DEVI float tanh_(float x) {
  float a = fabsf(x);
  float e = __expf(-2.f * a);
  float t = (1.f - e) / (1.f + e);
  return copysignf(t, x);
}

DEVI void gl_lds16(const u16* g, void* l) {
  __builtin_amdgcn_global_load_lds(
      (const __attribute__((address_space(1))) u32*)(const void*)g,
      (__attribute__((address_space(3))) u32*)l, 16, 0, 0);
}
DEVI f32x4 mfma16(bf16x8 a, bf16x8 b, f32x4 c) {
  return __builtin_amdgcn_mfma_f32_16x16x32_bf16(a, b, c, 0, 0, 0);
}

// 64B-row LDS swizzle key (R8-proven: zero conflicts).
#define SWZ(row) (((row) >> 1) & 3)

// ---------- prep kernels ----------
__global__ void sums_k(const float* __restrict__ adj, float* __restrict__ rs, float* __restrict__ cs) {
  __shared__ float red[256];
  int bid = blockIdx.x, tid = threadIdx.x;
  if (bid < 1024) {
    float a = 0.f;
    for (int j = tid; j < 1024; j += 256) a += adj[bid * 1024 + j];
    red[tid] = a; __syncthreads();
    for (int s = 128; s; s >>= 1) { if (tid < s) red[tid] += red[tid + s]; __syncthreads(); }
    if (!tid) rs[bid] = red[0];
  } else {
    int c0 = (bid - 1024) * 64;
    int c = tid & 63, r0 = tid >> 6;
    float a = 0.f;
    for (int r = r0; r < 1024; r += 4) a += adj[r * 1024 + c0 + c];
    red[tid] = a; __syncthreads();
    if (tid < 64) cs[c0 + c] = red[c] + red[64 + c] + red[128 + c] + red[192 + c];
  }
}

// S0[i][j] = adj[j][i]/rs[j]; also S0T[j][i] = S0[i][j].
__global__ void s0t_build(const float* __restrict__ adj, const float* __restrict__ rs,
                          u16* __restrict__ S0, u16* __restrict__ S0T) {
  __shared__ float tile[32][33];
  int i0 = blockIdx.x * 32, j0 = blockIdx.y * 32;
  int tx = threadIdx.x & 31, ty = threadIdx.x >> 5;
  for (int yy = ty; yy < 32; yy += 8)
    tile[yy][tx] = adj[(j0 + yy) * 1024 + i0 + tx];
  __syncthreads();
  for (int yy = ty; yy < 32; yy += 8) {
    S0 [(i0 + yy) * 1024 + j0 + tx] = f2bf(tile[tx][yy] / rs[j0 + tx]);
    S0T[(j0 + yy) * 1024 + i0 + tx] = f2bf(tile[yy][tx] / rs[j0 + yy]);
  }
}

// S1[i][j] = adj[i][j]/cs[j]; also S1T[j][i].
__global__ void s1t_build(const float* __restrict__ adj, const float* __restrict__ cs,
                          u16* __restrict__ S1, u16* __restrict__ S1T) {
  __shared__ float tile[32][33];
  int i0 = blockIdx.x * 32, j0 = blockIdx.y * 32;
  int tx = threadIdx.x & 31, ty = threadIdx.x >> 5;
  for (int yy = ty; yy < 32; yy += 8)
    tile[yy][tx] = adj[(i0 + yy) * 1024 + j0 + tx];
  __syncthreads();
  for (int yy = ty; yy < 32; yy += 8) {
    S1 [(i0 + yy) * 1024 + j0 + tx] = f2bf(tile[yy][tx] / cs[j0 + tx]);
    S1T[(j0 + yy) * 1024 + i0 + tx] = f2bf(tile[tx][yy] / cs[j0 + yy]);
  }
}

// pack weights with cheb-fold; 5 segs per part: 0->W0-W2-W4, 1->W1, 2->2W2, 3->W3, 4->2W4
__global__ void pack_w(const float* __restrict__ src, u16* __restrict__ dst,
                       int NO, int Ktot, int off0, int off1) {
  int idx = blockIdx.x * 256 + threadIdx.x;
  if (idx >= NO * Ktot) return;
  int o = idx / Ktot, k = idx % Ktot;
  int seg = k >> 7, i = k & 127;
  int mo = seg % 5;
  int pos = ((seg / 5) ? off1 : off0) + i;
  const float* wr = src + (long)pos * 5 * NO + o;
  float v;
  switch (mo) {
    case 0: v = wr[0] - wr[(long)2 * NO] - wr[(long)4 * NO]; break;
    case 1: v = wr[(long)1 * NO]; break;
    case 2: v = 2.f * wr[(long)2 * NO]; break;
    case 3: v = wr[(long)3 * NO]; break;
    default: v = 2.f * wr[(long)4 * NO]; break;
  }
  dst[idx] = f2bf(v);
}

// h (B, N*128) fp32 -> hiN flat [r=b*1024+n][u] bf16 + hiT [b*128+u][n]
__global__ void build_hx(const float* __restrict__ src, u16* __restrict__ hiN,
                         u16* __restrict__ hiT) {
  __shared__ u16 t[32][33];
  int n0 = blockIdx.x * 32, u0 = blockIdx.y * 32, b = blockIdx.z;
  int tx = threadIdx.x & 31, ty = threadIdx.x >> 5;
  for (int yy = ty; yy < 32; yy += 8) {
    long d = (long)b * 131072 + (n0 + yy) * 128 + u0 + tx;
    u16 h = f2bf(src[d]);
    hiN[d] = h;
    t[yy][tx] = h;
  }
  __syncthreads();
  for (int yy = ty; yy < 32; yy += 8)
    hiT[(long)(b * 128 + u0 + yy) * 1024 + n0 + tx] = t[tx][yy];
}

// ---------- x-part (layer 0): exact fp32 path ----------
__global__ void xch0_build(const float* __restrict__ inp, float* __restrict__ x0) {
  int idx = blockIdx.x * 256 + threadIdx.x;
  int n = idx >> 7, c = idx & 127, b = c >> 1, d = c & 1;
  x0[idx] = inp[b * 2048 + n * 2 + d];
}

struct XJob { const u16* S; const float* xin; const float* x0; float* xout; };
struct XJobs { XJob j[2]; };
__global__ void xch_step2(XJobs js) {
  XJob J = js.j[blockIdx.z];
  int n = blockIdx.x, c = threadIdx.x;
  float acc = 0.f;
  for (int k = 0; k < 1024; k++) acc += bf2f(J.S[n * 1024 + k]) * J.xin[k * 128 + c];
  J.xout[n * 128 + c] = (J.x0 != nullptr) ? (2.f * acc - J.x0[n * 128 + c]) : acc;
}

__global__ __launch_bounds__(256) void xg_build(
    const float* __restrict__ gw0, const float* __restrict__ cw0,
    const float* __restrict__ xch,
    u16* __restrict__ xgg, u16* __restrict__ xgc) {
  __shared__ float wg[10][256];
  __shared__ float wc[10][128];
  __shared__ float xv[10];
  int t = threadIdx.x;
#pragma unroll
  for (int q = 0; q < 10; q++) {
    int m = q % 5, p = q / 5;
    wg[q][t] = gw0[(long)(p * 5 + m) * 256 + t];
    if (t < 128) wc[q][t] = cw0[(long)(p * 5 + m) * 128 + t];
  }
  __syncthreads();
  int r0 = blockIdx.x * 32;
  for (int rl = 0; rl < 32; rl++) {
    int r = r0 + rl, n = r & 1023, b = r >> 10;
    if (t < 10) { int m = t % 5, p = t / 5; xv[t] = xch[(long)m * 131072 + n * 128 + b * 2 + p]; }
    __syncthreads();
    float a = 0.f;
#pragma unroll
    for (int q = 0; q < 10; q++) a += wg[q][t] * xv[q];
    xgg[(long)r * 256 + t] = f2bf(a);
    if (t < 128) {
      float a2 = 0.f;
#pragma unroll
      for (int q = 0; q < 10; q++) a2 += wc[q][t] * xv[q];
      xgc[(long)r * 128 + t] = f2bf(a2);
    }
    __syncthreads();
  }
}

// ---------- diffusion GEMM:  Y[n][f] = sum_k S[n][k] * XT[f][k] ----------
// Chain mode (YN): F=8192, grid (64,4,z), XCD-cluster swizzle, chain-layout output.
// Matrix mode (YS): F=1024, grid (8,4,z), plain row-major [n][f] output (for S^2).
struct DiffJob { const u16* X; const u16* S; u16* YN; u16* YS; };
struct DiffJobs { DiffJob j[4]; };

__global__ __launch_bounds__(256, 2) void gemm_diffz(DiffJobs jobs) {
  DiffJob J = jobs.j[blockIdx.z];
  constexpr int BUF = 384 * 64;
  __shared__ char smem[3 * BUF];
  const int tid = threadIdx.x, wid = tid >> 6, lane = tid & 63;
  const int wrM = wid >> 1, wcN = wid & 1, l15 = lane & 15, l4 = lane >> 4;
  const int s_row = lane >> 2, s_kcp = lane & 3;
  int fbase, ntile;
  if (gridDim.x == 64) {
    const int l = blockIdx.y * 64 + blockIdx.x;
    const int sl = (l & 7) * 32 + (l >> 3);
    fbase = (sl >> 2) * 128;
    ntile = (sl & 3) * 256;
  } else {
    fbase = blockIdx.x * 128;
    ntile = blockIdx.y * 256;
  }

  f32x4 acc[8][4];
#pragma unroll
  for (int i = 0; i < 8; i++)
#pragma unroll
    for (int j = 0; j < 4; j++) acc[i][j] = (f32x4){0.f, 0.f, 0.f, 0.f};

  auto stage = [&](char* buf, int ks) {
    const int k0 = ks * 32;
#pragma unroll
    for (int c = 0; c < 6; c++) {
      const int row0 = c * 64 + wid * 16;
      const int row = row0 + s_row;
      const u16* src;
      if (row0 < 256) src = J.S + (long)(ntile + row) * 1024 + k0 + ((s_kcp ^ SWZ(row)) * 8);
      else { const int fr = row - 256; src = J.X + (long)(fbase + fr) * 1024 + k0 + ((s_kcp ^ SWZ(fr)) * 8); }
      gl_lds16(src, buf + row0 * 64);
    }
  };
  auto compute = [&](char* buf) {
    char* Ab = buf; char* Bb = buf + 256 * 64;
    bf16x8 af[8], bfr[4];
#pragma unroll
    for (int mb = 0; mb < 8; mb++) {
      const int row = wrM * 128 + mb * 16 + l15;
      af[mb] = *(const bf16x8*)(Ab + row * 64 + ((l4 ^ SWZ(row)) * 16));
    }
#pragma unroll
    for (int nb = 0; nb < 4; nb++) {
      const int row = wcN * 64 + nb * 16 + l15;
      bfr[nb] = *(const bf16x8*)(Bb + row * 64 + ((l4 ^ SWZ(row)) * 16));
    }
    __builtin_amdgcn_s_setprio(1);
#pragma unroll
    for (int mb = 0; mb < 8; mb++)
#pragma unroll
      for (int nb = 0; nb < 4; nb++)
        acc[mb][nb] = mfma16(af[mb], bfr[nb], acc[mb][nb]);
    __builtin_amdgcn_s_setprio(0);
  };

  const int NKS = 32;
  stage(smem, 0);
  stage(smem + BUF, 1);
  char* cur = smem; char* mid = smem + BUF; char* fut = smem + 2 * BUF;
  for (int ks = 0; ks + 2 < NKS; ks++) {
    stage(fut, ks + 2);
    asm volatile("s_waitcnt vmcnt(12)" ::: "memory");
    __builtin_amdgcn_s_barrier();
    __builtin_amdgcn_sched_barrier(0);
    compute(cur);
    asm volatile("" ::: "memory");
    __builtin_amdgcn_s_barrier();
    __builtin_amdgcn_sched_barrier(0);
    char* t = cur; cur = mid; mid = fut; fut = t;
  }
  asm volatile("s_waitcnt vmcnt(6)" ::: "memory");
  __builtin_amdgcn_s_barrier();
  __builtin_amdgcn_sched_barrier(0);
  compute(cur);
  asm volatile("s_waitcnt vmcnt(0)" ::: "memory");
  __builtin_amdgcn_s_barrier();
  __builtin_amdgcn_sched_barrier(0);
  compute(mid);

#pragma unroll
  for (int mb = 0; mb < 8; mb++) {
#pragma unroll
    for (int nb = 0; nb < 4; nb++) {
      const int n0 = ntile + wrM * 128 + mb * 16 + l4 * 4;
      const int f  = fbase + wcN * 64 + nb * 16 + l15;
      f32x4 v = acc[mb][nb];
      u16 h0 = f2bf(v[0]), h1 = f2bf(v[1]), h2 = f2bf(v[2]), h3 = f2bf(v[3]);
      if (J.YN != nullptr) {
        const int b = f >> 7, u = f & 127;
        u16* yn = J.YN + (long)b * 131072 + (long)n0 * 128 + u;
        yn[0] = h0; yn[128] = h1; yn[256] = h2; yn[384] = h3;
      } else {
        u16* ys = J.YS + (long)n0 * 1024 + f;
        ys[0] = h0; ys[1024] = h1; ys[2048] = h2; ys[3072] = h3;
      }
    }
  }
}

// ---------- W GEMM with fused epilogue (M x 128 tile, 4 waves, BK=32, triple-buffered) ----------
struct Segs { const u16* p[10]; };
DEVI const u16* seg_sel(const Segs& s, int i) {
  switch (i) {
    case 0: return s.p[0]; case 1: return s.p[1]; case 2: return s.p[2];
    case 3: return s.p[3]; case 4: return s.p[4]; case 5: return s.p[5];
    case 6: return s.p[6]; case 7: return s.p[7]; case 8: return s.p[8];
    default: return s.p[9];
  }
}

template<int EPI>   // 0 = GATE (M=256), 1 = CAND (M=128)
__global__ __launch_bounds__(256, 2) void gemm_wseg(
    Segs segs, const u16* __restrict__ WT, int Ktot,
    const float* __restrict__ bias, const float* __restrict__ Hprev,
    const u16* __restrict__ Hb16,
    const u16* __restrict__ xadd,
    u16* __restrict__ rh_hi, u16* __restrict__ rh_t, u16* __restrict__ usig,
    float* __restrict__ hnew_out, u16* __restrict__ xa_hi, u16* __restrict__ xa_t)
{
  constexpr int TM = (EPI == 0) ? 256 : 128;
  constexpr int MB = (EPI == 0) ? 8 : 4;
  constexpr int MW = (EPI == 0) ? 128 : 64;
  constexpr int R1 = (TM + 128) / 64;
  constexpr int BUF = (TM + 128) * 64;
  __shared__ char smem[3 * BUF];
  const int tid = threadIdx.x, wid = tid >> 6, lane = tid & 63;
  const int wrM = wid >> 1, wcN = wid & 1, l15 = lane & 15, l4 = lane >> 4;
  const int s_row = lane >> 2, s_kcp = lane & 3;
  const int rtile = blockIdx.x * 128;

  f32x4 acc[MB][4];
#pragma unroll
  for (int i = 0; i < MB; i++)
#pragma unroll
    for (int j = 0; j < 4; j++) acc[i][j] = (f32x4){0.f, 0.f, 0.f, 0.f};

  const int NKS = Ktot >> 5;
  auto stage = [&](char* buf, int ks) {
    const int k0 = ks * 32;
    const int sidx = ks >> 2, si0 = (ks & 3) * 32;
    const u16* sp = seg_sel(segs, sidx);
#pragma unroll
    for (int c = 0; c < R1; c++) {
      const int row0 = c * 64 + wid * 16;
      const int row = row0 + s_row;
      const u16* src;
      if (row0 < TM) src = WT + (long)row * Ktot + k0 + ((s_kcp ^ SWZ(row)) * 8);
      else { const int br = row - TM; src = sp + (long)(rtile + br) * 128 + si0 + ((s_kcp ^ SWZ(br)) * 8); }
      gl_lds16(src, buf + row0 * 64);
    }
  };
  auto compute = [&](char* buf) {
    char* Ab = buf; char* Bb = buf + TM * 64;
    bf16x8 af[MB], bfr[4];
#pragma unroll
    for (int mb = 0; mb < MB; mb++) {
      const int row = wrM * MW + mb * 16 + l15;
      af[mb] = *(const bf16x8*)(Ab + row * 64 + ((l4 ^ SWZ(row)) * 16));
    }
#pragma unroll
    for (int nb = 0; nb < 4; nb++) {
      const int row = wcN * 64 + nb * 16 + l15;
      bfr[nb] = *(const bf16x8*)(Bb + row * 64 + ((l4 ^ SWZ(row)) * 16));
    }
    __builtin_amdgcn_s_setprio(1);
#pragma unroll
    for (int mb = 0; mb < MB; mb++)
#pragma unroll
      for (int nb = 0; nb < 4; nb++)
        acc[mb][nb] = mfma16(af[mb], bfr[nb], acc[mb][nb]);
    __builtin_amdgcn_s_setprio(0);
  };

  stage(smem, 0);
  stage(smem + BUF, 1);
  char* cur = smem; char* mid = smem + BUF; char* fut = smem + 2 * BUF;
  for (int ks = 0; ks + 2 < NKS; ks++) {
    stage(fut, ks + 2);
    if constexpr (R1 == 6) asm volatile("s_waitcnt vmcnt(12)" ::: "memory");
    else                   asm volatile("s_waitcnt vmcnt(8)" ::: "memory");
    __builtin_amdgcn_s_barrier();
    __builtin_amdgcn_sched_barrier(0);
    compute(cur);
    asm volatile("" ::: "memory");
    __builtin_amdgcn_s_barrier();
    __builtin_amdgcn_sched_barrier(0);
    char* t = cur; cur = mid; mid = fut; fut = t;
  }
  if constexpr (R1 == 6) asm volatile("s_waitcnt vmcnt(6)" ::: "memory");
  else                   asm volatile("s_waitcnt vmcnt(4)" ::: "memory");
  __builtin_amdgcn_s_barrier();
  __builtin_amdgcn_sched_barrier(0);
  compute(cur);
  asm volatile("s_waitcnt vmcnt(0)" ::: "memory");
  __builtin_amdgcn_s_barrier();
  __builtin_amdgcn_sched_barrier(0);
  compute(mid);

#pragma unroll
  for (int mb = 0; mb < MB; mb++) {
#pragma unroll
    for (int nb = 0; nb < 4; nb++) {
      const int o = wrM * MW + mb * 16 + l4 * 4;
      const int rr = rtile + wcN * 64 + nb * 16 + l15;
      const int n = rr & 1023, b = rr >> 10;
      f32x4 v = acc[mb][nb];
      float4 bv = *(const float4*)(bias + o);
      float a0 = 0.f, a1 = 0.f, a2 = 0.f, a3 = 0.f;
      if (xadd != nullptr) {
        const int xs = (EPI == 0) ? 256 : 128;
        u32x2 xv = *(const u32x2*)(xadd + (long)rr * xs + o);
        a0 = bf2f((u16)(xv[0] & 0xffffu)); a1 = bf2f((u16)(xv[0] >> 16));
        a2 = bf2f((u16)(xv[1] & 0xffffu)); a3 = bf2f((u16)(xv[1] >> 16));
      }
      float hx0, hx1, hx2, hx3;
      if (Hb16 != nullptr) {
        u32x2 hv2 = *(const u32x2*)(Hb16 + (long)rr * 128 + o);
        hx0 = bf2f((u16)(hv2[0] & 0xffffu)); hx1 = bf2f((u16)(hv2[0] >> 16));
        hx2 = bf2f((u16)(hv2[1] & 0xffffu)); hx3 = bf2f((u16)(hv2[1] >> 16));
      } else {
        float4 hv = *(const float4*)(Hprev + (long)rr * 128 + o);
        hx0 = hv.x; hx1 = hv.y; hx2 = hv.z; hx3 = hv.w;
      }
      if (EPI == 0) {
        float s0 = sigm(v[0] + bv.x + a0), s1 = sigm(v[1] + bv.y + a1);
        float s2 = sigm(v[2] + bv.z + a2), s3 = sigm(v[3] + bv.w + a3);
        if (o < 128) {
          float r0 = s0 * hx0, r1 = s1 * hx1, r2 = s2 * hx2, r3 = s3 * hx3;
          u16 h0 = f2bf(r0), h1 = f2bf(r1), h2 = f2bf(r2), h3 = f2bf(r3);
          long d = (long)rr * 128 + o;
          u32x2 wh; wh[0] = (u32)h0 | ((u32)h1 << 16); wh[1] = (u32)h2 | ((u32)h3 << 16);
          *(u32x2*)(rh_hi + d) = wh;
          u16* rt = rh_t + (long)(b * 128 + o) * 1024 + n;
          rt[0] = h0; rt[1024] = h1; rt[2048] = h2; rt[3072] = h3;
        } else {
          u32x2 wu; wu[0] = pk2bf(s0, s1); wu[1] = pk2bf(s2, s3);
          *(u32x2*)(usig + (long)rr * 128 + (o - 128)) = wu;
        }
      } else {
        float c0 = tanh_(v[0] + bv.x + a0), c1 = tanh_(v[1] + bv.y + a1);
        float c2 = tanh_(v[2] + bv.z + a2), c3 = tanh_(v[3] + bv.w + a3);
        u32x2 uv = *(const u32x2*)(usig + (long)rr * 128 + o);
        float u0 = bf2f((u16)(uv[0] & 0xffffu)), u1 = bf2f((u16)(uv[0] >> 16));
        float u2 = bf2f((u16)(uv[1] & 0xffffu)), u3 = bf2f((u16)(uv[1] >> 16));
        float h0n = u0 * hx0 + (1.f - u0) * c0;
        float h1n = u1 * hx1 + (1.f - u1) * c1;
        float h2n = u2 * hx2 + (1.f - u2) * c2;
        float h3n = u3 * hx3 + (1.f - u3) * c3;
        *(float4*)(hnew_out + (long)rr * 128 + o) = make_float4(h0n, h1n, h2n, h3n);
        if (xa_hi != nullptr) {
          u16 x0 = f2bf(h0n), x1 = f2bf(h1n), x2 = f2bf(h2n), x3 = f2bf(h3n);
          long d = (long)rr * 128 + o;
          u32x2 wh; wh[0] = (u32)x0 | ((u32)x1 << 16); wh[1] = (u32)x2 | ((u32)x3 << 16);
          *(u32x2*)(xa_hi + d) = wh;
          u16* xt = xa_t + (long)(b * 128 + o) * 1024 + n;
          xt[0] = x0; xt[1024] = x1; xt[2048] = x2; xt[3072] = x3;
        }
      }
    }
  }
}

// ---------- projection ----------
__global__ __launch_bounds__(256) void proj_k(const float* __restrict__ h1n, const float* __restrict__ pw,
                                              const float* __restrict__ pb, float* __restrict__ out) {
  int wid = threadIdx.x >> 6, lane = threadIdx.x & 63;
  int r = blockIdx.x * 4 + wid;
  int b = r >> 10, n = r & 1023;
  const float* hp = h1n + (long)b * 131072 + n * 128;
  float ha = hp[lane], hb = hp[lane + 64];
  float p0 = ha * pw[lane * 2]     + hb * pw[(lane + 64) * 2];
  float p1 = ha * pw[lane * 2 + 1] + hb * pw[(lane + 64) * 2 + 1];
  for (int off = 32; off; off >>= 1) { p0 += __shfl_down(p0, off); p1 += __shfl_down(p1, off); }
  if (!lane) {
    out[(long)b * 2048 + n * 2]     = p0 + pb[0];
    out[(long)b * 2048 + n * 2 + 1] = p1 + pb[1];
  }
}

// ---------- host ----------
extern "C" void kernel_launch(void* const* d_in, const int* in_sizes, int n_in,
                              void* d_out, int out_size, void* d_ws, size_t ws_size,
                              hipStream_t stream) {
  (void)in_sizes; (void)n_in; (void)out_size; (void)ws_size;
  const float* inputs = (const float*)d_in[0];
  const float* hidden = (const float*)d_in[1];
  const float* adj    = (const float*)d_in[2];
  const float* gw0 = (const float*)d_in[3];
  const float* gb0 = (const float*)d_in[4];
  const float* cw0 = (const float*)d_in[5];
  const float* cb0 = (const float*)d_in[6];
  const float* gw1 = (const float*)d_in[7];
  const float* gb1 = (const float*)d_in[8];
  const float* cw1 = (const float*)d_in[9];
  const float* cb1 = (const float*)d_in[10];
  const float* pw  = (const float*)d_in[11];
  const float* pb  = (const float*)d_in[12];

  float* out    = (float*)d_out;
  float* out_h0 = out + 131072;
  float* out_h1 = out_h0 + 8388608;
  const float* h0 = hidden;
  const float* h1 = hidden + 8388608;

  u16* OH1a = (u16*)out_h1;            // h1 hiN (intact until CAND1 writes out_h1)

  char* wp = (char*)d_ws;
  auto alloc = [&](size_t bytes) { char* r = wp; wp += (bytes + 255) & ~(size_t)255; return r; };
  u16*   S0b  = (u16*)  alloc(1048576 * 2);
  u16*   S1b  = (u16*)  alloc(1048576 * 2);
  u16*   S0Tb = (u16*)  alloc(1048576 * 2);
  u16*   S1Tb = (u16*)  alloc(1048576 * 2);
  u16*   SQ0  = (u16*)  alloc(1048576 * 2);
  u16*   SQ1  = (u16*)  alloc(1048576 * 2);
  float* rs   = (float*)alloc(1024 * 4);
  float* cs   = (float*)alloc(1024 * 4);
  u16*   WG0  = (u16*)  alloc((size_t)256 * 640 * 2);
  u16*   WC0  = (u16*)  alloc((size_t)128 * 640 * 2);
  u16*   WG1  = (u16*)  alloc((size_t)256 * 1280 * 2);
  u16*   WC1  = (u16*)  alloc((size_t)128 * 1280 * 2);
  u16*   Bb   = (u16*)  alloc((size_t)13 * 8388608 * 2);   // 13 chain slots
  u16*   USIG = (u16*)  alloc((size_t)8388608 * 2);
  float* XCH  = (float*)alloc((size_t)5 * 131072 * 4);
  auto BB = [&](int i) { return Bb + (size_t)i * 8388608; };
  auto XC = [&](int i) { return XCH + (size_t)i * 131072; };
  u16* XGg = BB(3);   // spans slots 3,4
  u16* XGc = BB(5);

  // prep
  sums_k<<<1040, 256, 0, stream>>>(adj, rs, cs);
  s0t_build<<<dim3(32, 32), 256, 0, stream>>>(adj, rs, S0b, S0Tb);
  s1t_build<<<dim3(32, 32), 256, 0, stream>>>(adj, cs, S1b, S1Tb);
  pack_w<<<640,  256, 0, stream>>>(gw0, WG0, 256, 640, 2, 0);
  pack_w<<<320,  256, 0, stream>>>(cw0, WC0, 128, 640, 2, 0);
  pack_w<<<1280, 256, 0, stream>>>(gw1, WG1, 256, 1280, 0, 128);
  pack_w<<<640,  256, 0, stream>>>(cw1, WC1, 128, 1280, 0, 128);
  build_hx<<<dim3(32, 4, 64), 256, 0, stream>>>(h0, BB(0), BB(1));     // h0N=BB0, h0T=BB1
  build_hx<<<dim3(32, 4, 64), 256, 0, stream>>>(h1, OH1a, BB(2));      // h1N=OH1a, h1T=BB2

  // SQ0 = S0^2, SQ1 = S1^2  (Y[n][f] = sum_k S[n][k]*ST[f][k]; plain [n][f] output)
  DiffJobs dj{};
  dj.j[0] = {S0Tb, S0b, nullptr, SQ0};
  dj.j[1] = {S1Tb, S1b, nullptr, SQ1};
  gemm_diffz<<<dim3(8, 4, 2), 256, 0, stream>>>(dj);

  // x-part exact chains + additive preacts
  xch0_build<<<512, 256, 0, stream>>>(inputs, XC(0));
  XJobs xj{};
  xj.j[0] = {S0b, XC(0), nullptr, XC(1)};
  xj.j[1] = {S1b, XC(0), nullptr, XC(3)};
  xch_step2<<<dim3(1024, 1, 2), 128, 0, stream>>>(xj);
  xj.j[0] = {S0b, XC(1), XC(0), XC(2)};
  xj.j[1] = {S1b, XC(3), XC(0), XC(4)};
  xch_step2<<<dim3(1024, 1, 2), 128, 0, stream>>>(xj);
  xg_build<<<2048, 256, 0, stream>>>(gw0, cw0, XCH, XGg, XGc);

  // L0 s-group (X=h0T): {S0->s1:BB6, SQ0->s2:BB7, S1->s3:BB8, SQ1->s4:BB9}
  dj.j[0] = {BB(1), S0b, BB(6), nullptr};
  dj.j[1] = {BB(1), SQ0, BB(7), nullptr};
  dj.j[2] = {BB(1), S1b, BB(8), nullptr};
  dj.j[3] = {BB(1), SQ1, BB(9), nullptr};
  gemm_diffz<<<dim3(64, 4, 4), 256, 0, stream>>>(dj);

  // GATE0: segs {h0, s1, s2, s3, s4}; Hb16=BB0; rh_hi->BB10, rhT->BB11
  Segs sg0{};
  sg0.p[0] = BB(0); sg0.p[1] = BB(6); sg0.p[2] = BB(7); sg0.p[3] = BB(8); sg0.p[4] = BB(9);
  gemm_wseg<0><<<512, 256, 0, stream>>>(sg0, WG0, 640, gb0, h0, BB(0), XGg,
      BB(10), BB(11), USIG, nullptr, nullptr, nullptr);

  // L0 c-group (X=rhT=BB11): c1..c4 -> BB6,7,8,9 (s-group dead)
  dj.j[0] = {BB(11), S0b, BB(6), nullptr};
  dj.j[1] = {BB(11), SQ0, BB(7), nullptr};
  dj.j[2] = {BB(11), S1b, BB(8), nullptr};
  dj.j[3] = {BB(11), SQ1, BB(9), nullptr};
  gemm_diffz<<<dim3(64, 4, 4), 256, 0, stream>>>(dj);

  // CAND0: segs {rh, c1..c4}; Hb16=BB0; out_h0; xa_hi->BB0 (elemwise RW safe), xaT->BB1
  Segs sc0{};
  sc0.p[0] = BB(10); sc0.p[1] = BB(6); sc0.p[2] = BB(7); sc0.p[3] = BB(8); sc0.p[4] = BB(9);
  gemm_wseg<1><<<512, 256, 0, stream>>>(sc0, WC0, 640, cb0, h0, BB(0), XGc,
      nullptr, nullptr, USIG, out_h0, BB(0), BB(1));

  // L1 s'-group (X=xaT=BB1): s1'..s4' -> BB3,4,5,6 (XG dead, c1 dead)
  dj.j[0] = {BB(1), S0b, BB(3), nullptr};
  dj.j[1] = {BB(1), SQ0, BB(4), nullptr};
  dj.j[2] = {BB(1), S1b, BB(5), nullptr};
  dj.j[3] = {BB(1), SQ1, BB(6), nullptr};
  gemm_diffz<<<dim3(64, 4, 4), 256, 0, stream>>>(dj);
  // L1 t-group (X=h1T=BB2): t1..t4 -> BB7,8,9,10 (c2..c4, rh0 dead)
  dj.j[0] = {BB(2), S0b, BB(7), nullptr};
  dj.j[1] = {BB(2), SQ0, BB(8), nullptr};
  dj.j[2] = {BB(2), S1b, BB(9), nullptr};
  dj.j[3] = {BB(2), SQ1, BB(10), nullptr};
  gemm_diffz<<<dim3(64, 4, 4), 256, 0, stream>>>(dj);

  // GATE1: segs x{xa, s1'..s4'} h{h1, t1..t4}; Hb16=OH1a; rh1_hi->BB11, rh1T->BB12
  Segs sg1{};
  sg1.p[0] = BB(0); sg1.p[1] = BB(3); sg1.p[2] = BB(4); sg1.p[3] = BB(5); sg1.p[4] = BB(6);
  sg1.p[5] = OH1a;  sg1.p[6] = BB(7); sg1.p[7] = BB(8); sg1.p[8] = BB(9); sg1.p[9] = BB(10);
  gemm_wseg<0><<<512, 256, 0, stream>>>(sg1, WG1, 1280, gb1, h1, OH1a, nullptr,
      BB(11), BB(12), USIG, nullptr, nullptr, nullptr);

  // L1 d-group (X=rh1T=BB12): d1..d4 -> BB1,2,7,8 (xaT, h1T, t1, t2 dead)
  dj.j[0] = {BB(12), S0b, BB(1), nullptr};
  dj.j[1] = {BB(12), SQ0, BB(2), nullptr};
  dj.j[2] = {BB(12), S1b, BB(7), nullptr};
  dj.j[3] = {BB(12), SQ1, BB(8), nullptr};
  gemm_diffz<<<dim3(64, 4, 4), 256, 0, stream>>>(dj);

  // CAND1: segs x{xa, s1'..s4'} rh{rh1, d1..d4}; fp32 Hprev (OH1a aliases out_h1) -> out_h1
  Segs sc1{};
  sc1.p[0] = BB(0);  sc1.p[1] = BB(3); sc1.p[2] = BB(4); sc1.p[3] = BB(5); sc1.p[4] = BB(6);
  sc1.p[5] = BB(11); sc1.p[6] = BB(1); sc1.p[7] = BB(2); sc1.p[8] = BB(7); sc1.p[9] = BB(8);
  gemm_wseg<1><<<512, 256, 0, stream>>>(sc1, WC1, 1280, cb1, h1, nullptr, nullptr,
      nullptr, nullptr, USIG, out_h1, nullptr, nullptr);

  // projection
  proj_k<<<16384, 256, 0, stream>>>(out_h1, pw, pb, out);
}

// Round 16
// 920.468 us; speedup vs baseline: 1.2989x; 1.0017x over previous
//
#include <hip/hip_runtime.h>
#include <hip/hip_bf16.h>

typedef unsigned short u16;
typedef unsigned int u32;
typedef __attribute__((ext_vector_type(2))) unsigned int u32x2;
typedef __attribute__((ext_vector_type(4))) float f32x4;
typedef __attribute__((ext_vector_type(8))) __bf16 bf16x8;

#define DEVI static __device__ __forceinline__

// ---------- scalar helpers ----------
DEVI u16 f2bf(float x) {
  union { float f; u32 u; } v; v.f = x;
  u32 r = v.u + 0x7fffu + ((v.u >> 16) & 1u);
  return (u16)(r >> 16);
}
DEVI float bf2f(u16 h) { union { u32 u; float f; } v; v.u = ((u32)h) << 16; return v.f; }
DEVI u32 pk2bf(float a, float b) { return (u32)f2bf(a) | ((u32)f2bf(b) << 16); }
DEVI float sigm(float x) { return 1.f / (1.f + __expf(-x)); }
DEVI float tanh_(float x) {
  float a = fabsf(x);
  float e = __expf(-2.f * a);
  float t = (1.f - e) / (1.f + e);
  return copysignf(t, x);
}

DEVI void gl_lds16(const u16* g, void* l) {
  __builtin_amdgcn_global_load_lds(
      (const __attribute__((address_space(1))) u32*)(const void*)g,
      (__attribute__((address_space(3))) u32*)l, 16, 0, 0);
}
DEVI f32x4 mfma16(bf16x8 a, bf16x8 b, f32x4 c) {
  return __builtin_amdgcn_mfma_f32_16x16x32_bf16(a, b, c, 0, 0, 0);
}

// 64B-row LDS swizzle key (R8-proven: zero conflicts).
#define SWZ(row) (((row) >> 1) & 3)

// ---------- prep kernels ----------
__global__ void sums_k(const float* __restrict__ adj, float* __restrict__ rs, float* __restrict__ cs) {
  __shared__ float red[256];
  int bid = blockIdx.x, tid = threadIdx.x;
  if (bid < 1024) {
    float a = 0.f;
    for (int j = tid; j < 1024; j += 256) a += adj[bid * 1024 + j];
    red[tid] = a; __syncthreads();
    for (int s = 128; s; s >>= 1) { if (tid < s) red[tid] += red[tid + s]; __syncthreads(); }
    if (!tid) rs[bid] = red[0];
  } else {
    int c0 = (bid - 1024) * 64;
    int c = tid & 63, r0 = tid >> 6;
    float a = 0.f;
    for (int r = r0; r < 1024; r += 4) a += adj[r * 1024 + c0 + c];
    red[tid] = a; __syncthreads();
    if (tid < 64) cs[c0 + c] = red[c] + red[64 + c] + red[128 + c] + red[192 + c];
  }
}

__global__ void s0t_build(const float* __restrict__ adj, const float* __restrict__ rs,
                          u16* __restrict__ S0, u16* __restrict__ S0T) {
  __shared__ float tile[32][33];
  int i0 = blockIdx.x * 32, j0 = blockIdx.y * 32;
  int tx = threadIdx.x & 31, ty = threadIdx.x >> 5;
  for (int yy = ty; yy < 32; yy += 8)
    tile[yy][tx] = adj[(j0 + yy) * 1024 + i0 + tx];
  __syncthreads();
  for (int yy = ty; yy < 32; yy += 8) {
    S0 [(i0 + yy) * 1024 + j0 + tx] = f2bf(tile[tx][yy] / rs[j0 + tx]);
    S0T[(j0 + yy) * 1024 + i0 + tx] = f2bf(tile[yy][tx] / rs[j0 + yy]);
  }
}

__global__ void s1t_build(const float* __restrict__ adj, const float* __restrict__ cs,
                          u16* __restrict__ S1, u16* __restrict__ S1T) {
  __shared__ float tile[32][33];
  int i0 = blockIdx.x * 32, j0 = blockIdx.y * 32;
  int tx = threadIdx.x & 31, ty = threadIdx.x >> 5;
  for (int yy = ty; yy < 32; yy += 8)
    tile[yy][tx] = adj[(i0 + yy) * 1024 + j0 + tx];
  __syncthreads();
  for (int yy = ty; yy < 32; yy += 8) {
    S1 [(i0 + yy) * 1024 + j0 + tx] = f2bf(tile[yy][tx] / cs[j0 + tx]);
    S1T[(j0 + yy) * 1024 + i0 + tx] = f2bf(tile[tx][yy] / cs[j0 + yy]);
  }
}

__global__ void pack_w(const float* __restrict__ src, u16* __restrict__ dst,
                       int NO, int Ktot, int off0, int off1) {
  int idx = blockIdx.x * 256 + threadIdx.x;
  if (idx >= NO * Ktot) return;
  int o = idx / Ktot, k = idx % Ktot;
  int seg = k >> 7, i = k & 127;
  int mo = seg % 5;
  int pos = ((seg / 5) ? off1 : off0) + i;
  const float* wr = src + (long)pos * 5 * NO + o;
  float v;
  switch (mo) {
    case 0: v = wr[0] - wr[(long)2 * NO] - wr[(long)4 * NO]; break;
    case 1: v = wr[(long)1 * NO]; break;
    case 2: v = 2.f * wr[(long)2 * NO]; break;
    case 3: v = wr[(long)3 * NO]; break;
    default: v = 2.f * wr[(long)4 * NO]; break;
  }
  dst[idx] = f2bf(v);
}

__global__ void build_hx(const float* __restrict__ src, u16* __restrict__ hiN,
                         u16* __restrict__ hiT) {
  __shared__ u16 t[32][33];
  int n0 = blockIdx.x * 32, u0 = blockIdx.y * 32, b = blockIdx.z;
  int tx = threadIdx.x & 31, ty = threadIdx.x >> 5;
  for (int yy = ty; yy < 32; yy += 8) {
    long d = (long)b * 131072 + (n0 + yy) * 128 + u0 + tx;
    u16 h = f2bf(src[d]);
    hiN[d] = h;
    t[yy][tx] = h;
  }
  __syncthreads();
  for (int yy = ty; yy < 32; yy += 8)
    hiT[(long)(b * 128 + u0 + yy) * 1024 + n0 + tx] = t[tx][yy];
}

// ---------- x-part (layer 0): exact fp32 path ----------
__global__ void xch0_build(const float* __restrict__ inp, float* __restrict__ x0) {
  int idx = blockIdx.x * 256 + threadIdx.x;
  int n = idx >> 7, c = idx & 127, b = c >> 1, d = c & 1;
  x0[idx] = inp[b * 2048 + n * 2 + d];
}

struct XJob { const u16* S; const float* xin; const float* x0; float* xout; };
struct XJobs { XJob j[2]; };
__global__ void xch_step2(XJobs js) {
  XJob J = js.j[blockIdx.z];
  int n = blockIdx.x, c = threadIdx.x;
  float acc = 0.f;
#pragma unroll 8
  for (int k = 0; k < 1024; k++) acc += bf2f(J.S[n * 1024 + k]) * J.xin[k * 128 + c];
  J.xout[n * 128 + c] = (J.x0 != nullptr) ? (2.f * acc - J.x0[n * 128 + c]) : acc;
}

__global__ __launch_bounds__(256) void xg_build(
    const float* __restrict__ gw0, const float* __restrict__ cw0,
    const float* __restrict__ xch,
    u16* __restrict__ xgg, u16* __restrict__ xgc) {
  __shared__ float wg[10][256];
  __shared__ float wc[10][128];
  __shared__ float xv[10];
  int t = threadIdx.x;
#pragma unroll
  for (int q = 0; q < 10; q++) {
    int m = q % 5, p = q / 5;
    wg[q][t] = gw0[(long)(p * 5 + m) * 256 + t];
    if (t < 128) wc[q][t] = cw0[(long)(p * 5 + m) * 128 + t];
  }
  __syncthreads();
  int r0 = blockIdx.x * 32;
  for (int rl = 0; rl < 32; rl++) {
    int r = r0 + rl, n = r & 1023, b = r >> 10;
    if (t < 10) { int m = t % 5, p = t / 5; xv[t] = xch[(long)m * 131072 + n * 128 + b * 2 + p]; }
    __syncthreads();
    float a = 0.f;
#pragma unroll
    for (int q = 0; q < 10; q++) a += wg[q][t] * xv[q];
    xgg[(long)r * 256 + t] = f2bf(a);
    if (t < 128) {
      float a2 = 0.f;
#pragma unroll
      for (int q = 0; q < 10; q++) a2 += wc[q][t] * xv[q];
      xgc[(long)r * 128 + t] = f2bf(a2);
    }
    __syncthreads();
  }
}

// ---------- diffusion GEMM:  Y[n][f] = sum_k S[n][k] * XT[f][k] ----------
struct DiffJob { const u16* X; const u16* S; u16* YN; u16* YS; };
struct DiffJobs { DiffJob j[8]; };

__global__ __launch_bounds__(256, 2) void gemm_diffz(DiffJobs jobs) {
  DiffJob J = jobs.j[blockIdx.z];
  constexpr int BUF = 384 * 64;
  __shared__ char smem[3 * BUF];
  const int tid = threadIdx.x, wid = tid >> 6, lane = tid & 63;
  const int wrM = wid >> 1, wcN = wid & 1, l15 = lane & 15, l4 = lane >> 4;
  const int s_row = lane >> 2, s_kcp = lane & 3;
  int fbase, ntile;
  if (gridDim.x == 64) {
    const int l = blockIdx.y * 64 + blockIdx.x;
    const int sl = (l & 7) * 32 + (l >> 3);
    fbase = (sl >> 2) * 128;
    ntile = (sl & 3) * 256;
  } else {
    fbase = blockIdx.x * 128;
    ntile = blockIdx.y * 256;
  }

  f32x4 acc[8][4];
#pragma unroll
  for (int i = 0; i < 8; i++)
#pragma unroll
    for (int j = 0; j < 4; j++) acc[i][j] = (f32x4){0.f, 0.f, 0.f, 0.f};

  auto stage = [&](char* buf, int ks) {
    const int k0 = ks * 32;
#pragma unroll
    for (int c = 0; c < 6; c++) {
      const int row0 = c * 64 + wid * 16;
      const int row = row0 + s_row;
      const u16* src;
      if (row0 < 256) src = J.S + (long)(ntile + row) * 1024 + k0 + ((s_kcp ^ SWZ(row)) * 8);
      else { const int fr = row - 256; src = J.X + (long)(fbase + fr) * 1024 + k0 + ((s_kcp ^ SWZ(fr)) * 8); }
      gl_lds16(src, buf + row0 * 64);
    }
  };
  auto compute = [&](char* buf) {
    char* Ab = buf; char* Bb = buf + 256 * 64;
    bf16x8 af[8], bfr[4];
#pragma unroll
    for (int mb = 0; mb < 8; mb++) {
      const int row = wrM * 128 + mb * 16 + l15;
      af[mb] = *(const bf16x8*)(Ab + row * 64 + ((l4 ^ SWZ(row)) * 16));
    }
#pragma unroll
    for (int nb = 0; nb < 4; nb++) {
      const int row = wcN * 64 + nb * 16 + l15;
      bfr[nb] = *(const bf16x8*)(Bb + row * 64 + ((l4 ^ SWZ(row)) * 16));
    }
    __builtin_amdgcn_s_setprio(1);
#pragma unroll
    for (int mb = 0; mb < 8; mb++)
#pragma unroll
      for (int nb = 0; nb < 4; nb++)
        acc[mb][nb] = mfma16(af[mb], bfr[nb], acc[mb][nb]);
    __builtin_amdgcn_s_setprio(0);
  };

  const int NKS = 32;
  stage(smem, 0);
  stage(smem + BUF, 1);
  char* cur = smem; char* mid = smem + BUF; char* fut = smem + 2 * BUF;
  for (int ks = 0; ks + 2 < NKS; ks++) {
    stage(fut, ks + 2);
    asm volatile("s_waitcnt vmcnt(12)" ::: "memory");
    __builtin_amdgcn_s_barrier();
    __builtin_amdgcn_sched_barrier(0);
    compute(cur);
    asm volatile("" ::: "memory");
    __builtin_amdgcn_s_barrier();
    __builtin_amdgcn_sched_barrier(0);
    char* t = cur; cur = mid; mid = fut; fut = t;
  }
  asm volatile("s_waitcnt vmcnt(6)" ::: "memory");
  __builtin_amdgcn_s_barrier();
  __builtin_amdgcn_sched_barrier(0);
  compute(cur);
  asm volatile("s_waitcnt vmcnt(0)" ::: "memory");
  __builtin_amdgcn_s_barrier();
  __builtin_amdgcn_sched_barrier(0);
  compute(mid);

#pragma unroll
  for (int mb = 0; mb < 8; mb++) {
#pragma unroll
    for (int nb = 0; nb < 4; nb++) {
      const int n0 = ntile + wrM * 128 + mb * 16 + l4 * 4;
      const int f  = fbase + wcN * 64 + nb * 16 + l15;
      f32x4 v = acc[mb][nb];
      u16 h0 = f2bf(v[0]), h1 = f2bf(v[1]), h2 = f2bf(v[2]), h3 = f2bf(v[3]);
      if (J.YN != nullptr) {
        const int b = f >> 7, u = f & 127;
        u16* yn = J.YN + (long)b * 131072 + (long)n0 * 128 + u;
        yn[0] = h0; yn[128] = h1; yn[256] = h2; yn[384] = h3;
      } else {
        u16* ys = J.YS + (long)n0 * 1024 + f;
        ys[0] = h0; ys[1024] = h1; ys[2048] = h2; ys[3072] = h3;
      }
    }
  }
}

// ---------- W GEMM with fused epilogue (M x 128 tile, 4 waves, BK=32, triple-buffered) ----------
struct Segs { const u16* p[10]; };
DEVI const u16* seg_sel(const Segs& s, int i) {
  switch (i) {
    case 0: return s.p[0]; case 1: return s.p[1]; case 2: return s.p[2];
    case 3: return s.p[3]; case 4: return s.p[4]; case 5: return s.p[5];
    case 6: return s.p[6]; case 7: return s.p[7]; case 8: return s.p[8];
    default: return s.p[9];
  }
}

template<int EPI>   // 0 = GATE (M=256), 1 = CAND (M=128)
__global__ __launch_bounds__(256, 2) void gemm_wseg(
    Segs segs, const u16* __restrict__ WT, int Ktot,
    const float* __restrict__ bias, const float* __restrict__ Hprev,
    const u16* __restrict__ Hb16,
    const u16* __restrict__ xadd,
    u16* __restrict__ rh_hi, u16* __restrict__ rh_t, u16* __restrict__ usig,
    float* __restrict__ hnew_out, u16* __restrict__ xa_hi, u16* __restrict__ xa_t)
{
  constexpr int TM = (EPI == 0) ? 256 : 128;
  constexpr int MB = (EPI == 0) ? 8 : 4;
  constexpr int MW = (EPI == 0) ? 128 : 64;
  constexpr int R1 = (TM + 128) / 64;
  constexpr int BUF = (TM + 128) * 64;
  __shared__ char smem[3 * BUF];
  const int tid = threadIdx.x, wid = tid >> 6, lane = tid & 63;
  const int wrM = wid >> 1, wcN = wid & 1, l15 = lane & 15, l4 = lane >> 4;
  const int s_row = lane >> 2, s_kcp = lane & 3;
  const int rtile = blockIdx.x * 128;

  f32x4 acc[MB][4];
#pragma unroll
  for (int i = 0; i < MB; i++)
#pragma unroll
    for (int j = 0; j < 4; j++) acc[i][j] = (f32x4){0.f, 0.f, 0.f, 0.f};

  const int NKS = Ktot >> 5;
  auto stage = [&](char* buf, int ks) {
    const int k0 = ks * 32;
    const int sidx = ks >> 2, si0 = (ks & 3) * 32;
    const u16* sp = seg_sel(segs, sidx);
#pragma unroll
    for (int c = 0; c < R1; c++) {
      const int row0 = c * 64 + wid * 16;
      const int row = row0 + s_row;
      const u16* src;
      if (row0 < TM) src = WT + (long)row * Ktot + k0 + ((s_kcp ^ SWZ(row)) * 8);
      else { const int br = row - TM; src = sp + (long)(rtile + br) * 128 + si0 + ((s_kcp ^ SWZ(br)) * 8); }
      gl_lds16(src, buf + row0 * 64);
    }
  };
  auto compute = [&](char* buf) {
    char* Ab = buf; char* Bb = buf + TM * 64;
    bf16x8 af[MB], bfr[4];
#pragma unroll
    for (int mb = 0; mb < MB; mb++) {
      const int row = wrM * MW + mb * 16 + l15;
      af[mb] = *(const bf16x8*)(Ab + row * 64 + ((l4 ^ SWZ(row)) * 16));
    }
#pragma unroll
    for (int nb = 0; nb < 4; nb++) {
      const int row = wcN * 64 + nb * 16 + l15;
      bfr[nb] = *(const bf16x8*)(Bb + row * 64 + ((l4 ^ SWZ(row)) * 16));
    }
    __builtin_amdgcn_s_setprio(1);
#pragma unroll
    for (int mb = 0; mb < MB; mb++)
#pragma unroll
      for (int nb = 0; nb < 4; nb++)
        acc[mb][nb] = mfma16(af[mb], bfr[nb], acc[mb][nb]);
    __builtin_amdgcn_s_setprio(0);
  };

  stage(smem, 0);
  stage(smem + BUF, 1);
  char* cur = smem; char* mid = smem + BUF; char* fut = smem + 2 * BUF;
  for (int ks = 0; ks + 2 < NKS; ks++) {
    stage(fut, ks + 2);
    if constexpr (R1 == 6) asm volatile("s_waitcnt vmcnt(12)" ::: "memory");
    else                   asm volatile("s_waitcnt vmcnt(8)" ::: "memory");
    __builtin_amdgcn_s_barrier();
    __builtin_amdgcn_sched_barrier(0);
    compute(cur);
    asm volatile("" ::: "memory");
    __builtin_amdgcn_s_barrier();
    __builtin_amdgcn_sched_barrier(0);
    char* t = cur; cur = mid; mid = fut; fut = t;
  }
  if constexpr (R1 == 6) asm volatile("s_waitcnt vmcnt(6)" ::: "memory");
  else                   asm volatile("s_waitcnt vmcnt(4)" ::: "memory");
  __builtin_amdgcn_s_barrier();
  __builtin_amdgcn_sched_barrier(0);
  compute(cur);
  asm volatile("s_waitcnt vmcnt(0)" ::: "memory");
  __builtin_amdgcn_s_barrier();
  __builtin_amdgcn_sched_barrier(0);
  compute(mid);

#pragma unroll
  for (int mb = 0; mb < MB; mb++) {
#pragma unroll
    for (int nb = 0; nb < 4; nb++) {
      const int o = wrM * MW + mb * 16 + l4 * 4;
      const int rr = rtile + wcN * 64 + nb * 16 + l15;
      const int n = rr & 1023, b = rr >> 10;
      f32x4 v = acc[mb][nb];
      float4 bv = *(const float4*)(bias + o);
      float a0 = 0.f, a1 = 0.f, a2 = 0.f, a3 = 0.f;
      if (xadd != nullptr) {
        const int xs = (EPI == 0) ? 256 : 128;
        u32x2 xv = *(const u32x2*)(xadd + (long)rr * xs + o);
        a0 = bf2f((u16)(xv[0] & 0xffffu)); a1 = bf2f((u16)(xv[0] >> 16));
        a2 = bf2f((u16)(xv[1] & 0xffffu)); a3 = bf2f((u16)(xv[1] >> 16));
      }
      float hx0, hx1, hx2, hx3;
      if (Hb16 != nullptr) {
        u32x2 hv2 = *(const u32x2*)(Hb16 + (long)rr * 128 + o);
        hx0 = bf2f((u16)(hv2[0] & 0xffffu)); hx1 = bf2f((u16)(hv2[0] >> 16));
        hx2 = bf2f((u16)(hv2[1] & 0xffffu)); hx3 = bf2f((u16)(hv2[1] >> 16));
      } else {
        float4 hv = *(const float4*)(Hprev + (long)rr * 128 + o);
        hx0 = hv.x; hx1 = hv.y; hx2 = hv.z; hx3 = hv.w;
      }
      if (EPI == 0) {
        float s0 = sigm(v[0] + bv.x + a0), s1 = sigm(v[1] + bv.y + a1);
        float s2 = sigm(v[2] + bv.z + a2), s3 = sigm(v[3] + bv.w + a3);
        if (o < 128) {
          float r0 = s0 * hx0, r1 = s1 * hx1, r2 = s2 * hx2, r3 = s3 * hx3;
          u16 h0 = f2bf(r0), h1 = f2bf(r1), h2 = f2bf(r2), h3 = f2bf(r3);
          long d = (long)rr * 128 + o;
          u32x2 wh; wh[0] = (u32)h0 | ((u32)h1 << 16); wh[1] = (u32)h2 | ((u32)h3 << 16);
          *(u32x2*)(rh_hi + d) = wh;
          u16* rt = rh_t + (long)(b * 128 + o) * 1024 + n;
          rt[0] = h0; rt[1024] = h1; rt[2048] = h2; rt[3072] = h3;
        } else {
          u32x2 wu; wu[0] = pk2bf(s0, s1); wu[1] = pk2bf(s2, s3);
          *(u32x2*)(usig + (long)rr * 128 + (o - 128)) = wu;
        }
      } else {
        float c0 = tanh_(v[0] + bv.x + a0), c1 = tanh_(v[1] + bv.y + a1);
        float c2 = tanh_(v[2] + bv.z + a2), c3 = tanh_(v[3] + bv.w + a3);
        u32x2 uv = *(const u32x2*)(usig + (long)rr * 128 + o);
        float u0 = bf2f((u16)(uv[0] & 0xffffu)), u1 = bf2f((u16)(uv[0] >> 16));
        float u2 = bf2f((u16)(uv[1] & 0xffffu)), u3 = bf2f((u16)(uv[1] >> 16));
        float h0n = u0 * hx0 + (1.f - u0) * c0;
        float h1n = u1 * hx1 + (1.f - u1) * c1;
        float h2n = u2 * hx2 + (1.f - u2) * c2;
        float h3n = u3 * hx3 + (1.f - u3) * c3;
        *(float4*)(hnew_out + (long)rr * 128 + o) = make_float4(h0n, h1n, h2n, h3n);
        if (xa_hi != nullptr) {
          u16 x0 = f2bf(h0n), x1 = f2bf(h1n), x2 = f2bf(h2n), x3 = f2bf(h3n);
          long d = (long)rr * 128 + o;
          u32x2 wh; wh[0] = (u32)x0 | ((u32)x1 << 16); wh[1] = (u32)x2 | ((u32)x3 << 16);
          *(u32x2*)(xa_hi + d) = wh;
          u16* xt = xa_t + (long)(b * 128 + o) * 1024 + n;
          xt[0] = x0; xt[1024] = x1; xt[2048] = x2; xt[3072] = x3;
        }
      }
    }
  }
}

// ---------- projection ----------
__global__ __launch_bounds__(256) void proj_k(const float* __restrict__ h1n, const float* __restrict__ pw,
                                              const float* __restrict__ pb, float* __restrict__ out) {
  int wid = threadIdx.x >> 6, lane = threadIdx.x & 63;
  int r = blockIdx.x * 4 + wid;
  int b = r >> 10, n = r & 1023;
  const float* hp = h1n + (long)b * 131072 + n * 128;
  float ha = hp[lane], hb = hp[lane + 64];
  float p0 = ha * pw[lane * 2]     + hb * pw[(lane + 64) * 2];
  float p1 = ha * pw[lane * 2 + 1] + hb * pw[(lane + 64) * 2 + 1];
  for (int off = 32; off; off >>= 1) { p0 += __shfl_down(p0, off); p1 += __shfl_down(p1, off); }
  if (!lane) {
    out[(long)b * 2048 + n * 2]     = p0 + pb[0];
    out[(long)b * 2048 + n * 2 + 1] = p1 + pb[1];
  }
}

// ---------- host ----------
extern "C" void kernel_launch(void* const* d_in, const int* in_sizes, int n_in,
                              void* d_out, int out_size, void* d_ws, size_t ws_size,
                              hipStream_t stream) {
  (void)in_sizes; (void)n_in; (void)out_size; (void)ws_size;
  const float* inputs = (const float*)d_in[0];
  const float* hidden = (const float*)d_in[1];
  const float* adj    = (const float*)d_in[2];
  const float* gw0 = (const float*)d_in[3];
  const float* gb0 = (const float*)d_in[4];
  const float* cw0 = (const float*)d_in[5];
  const float* cb0 = (const float*)d_in[6];
  const float* gw1 = (const float*)d_in[7];
  const float* gb1 = (const float*)d_in[8];
  const float* cw1 = (const float*)d_in[9];
  const float* cb1 = (const float*)d_in[10];
  const float* pw  = (const float*)d_in[11];
  const float* pb  = (const float*)d_in[12];

  float* out    = (float*)d_out;
  float* out_h0 = out + 131072;
  float* out_h1 = out_h0 + 8388608;
  const float* h0 = hidden;
  const float* h1 = hidden + 8388608;

  u16* OH1a = (u16*)out_h1;            // h1 hiN (intact until CAND1 writes out_h1)

  char* wp = (char*)d_ws;
  auto alloc = [&](size_t bytes) { char* r = wp; wp += (bytes + 255) & ~(size_t)255; return r; };
  u16*   S0b  = (u16*)  alloc(1048576 * 2);
  u16*   S1b  = (u16*)  alloc(1048576 * 2);
  u16*   S0Tb = (u16*)  alloc(1048576 * 2);
  u16*   S1Tb = (u16*)  alloc(1048576 * 2);
  u16*   SQ0  = (u16*)  alloc(1048576 * 2);
  u16*   SQ1  = (u16*)  alloc(1048576 * 2);
  float* rs   = (float*)alloc(1024 * 4);
  float* cs   = (float*)alloc(1024 * 4);
  u16*   WG0  = (u16*)  alloc((size_t)256 * 640 * 2);
  u16*   WC0  = (u16*)  alloc((size_t)128 * 640 * 2);
  u16*   WG1  = (u16*)  alloc((size_t)256 * 1280 * 2);
  u16*   WC1  = (u16*)  alloc((size_t)128 * 1280 * 2);
  u16*   Bb   = (u16*)  alloc((size_t)13 * 8388608 * 2);   // 13 chain slots
  u16*   USIG = (u16*)  alloc((size_t)8388608 * 2);
  float* XCH  = (float*)alloc((size_t)5 * 131072 * 4);
  auto BB = [&](int i) { return Bb + (size_t)i * 8388608; };
  auto XC = [&](int i) { return XCH + (size_t)i * 131072; };
  u16* XGg = BB(3);   // spans slots 3,4
  u16* XGc = BB(5);

  // prep
  sums_k<<<1040, 256, 0, stream>>>(adj, rs, cs);
  s0t_build<<<dim3(32, 32), 256, 0, stream>>>(adj, rs, S0b, S0Tb);
  s1t_build<<<dim3(32, 32), 256, 0, stream>>>(adj, cs, S1b, S1Tb);
  pack_w<<<640,  256, 0, stream>>>(gw0, WG0, 256, 640, 2, 0);
  pack_w<<<320,  256, 0, stream>>>(cw0, WC0, 128, 640, 2, 0);
  pack_w<<<1280, 256, 0, stream>>>(gw1, WG1, 256, 1280, 0, 128);
  pack_w<<<640,  256, 0, stream>>>(cw1, WC1, 128, 1280, 0, 128);
  build_hx<<<dim3(32, 4, 64), 256, 0, stream>>>(h0, BB(0), BB(1));     // h0N=BB0, h0T=BB1
  build_hx<<<dim3(32, 4, 64), 256, 0, stream>>>(h1, OH1a, BB(2));      // h1N=OH1a, h1T=BB2

  // SQ0 = S0^2, SQ1 = S1^2
  DiffJobs dj{};
  dj.j[0] = {S0Tb, S0b, nullptr, SQ0};
  dj.j[1] = {S1Tb, S1b, nullptr, SQ1};
  gemm_diffz<<<dim3(8, 4, 2), 256, 0, stream>>>(dj);

  // x-part exact chains + additive preacts
  xch0_build<<<512, 256, 0, stream>>>(inputs, XC(0));
  XJobs xj{};
  xj.j[0] = {S0b, XC(0), nullptr, XC(1)};
  xj.j[1] = {S1b, XC(0), nullptr, XC(3)};
  xch_step2<<<dim3(1024, 1, 2), 128, 0, stream>>>(xj);
  xj.j[0] = {S0b, XC(1), XC(0), XC(2)};
  xj.j[1] = {S1b, XC(3), XC(0), XC(4)};
  xch_step2<<<dim3(1024, 1, 2), 128, 0, stream>>>(xj);
  xg_build<<<2048, 256, 0, stream>>>(gw0, cw0, XCH, XGg, XGc);

  // L0 s-group (X=h0T=BB1): {S0->s1:BB6, SQ0->s2:BB7, S1->s3:BB8, SQ1->s4:BB9}
  dj.j[0] = {BB(1), S0b, BB(6), nullptr};
  dj.j[1] = {BB(1), SQ0, BB(7), nullptr};
  dj.j[2] = {BB(1), S1b, BB(8), nullptr};
  dj.j[3] = {BB(1), SQ1, BB(9), nullptr};
  gemm_diffz<<<dim3(64, 4, 4), 256, 0, stream>>>(dj);

  // GATE0: segs {h0, s1..s4}; Hb16=BB0; xadd=XGg; rh_hi->BB10, rhT->BB11
  Segs sg0{};
  sg0.p[0] = BB(0); sg0.p[1] = BB(6); sg0.p[2] = BB(7); sg0.p[3] = BB(8); sg0.p[4] = BB(9);
  gemm_wseg<0><<<512, 256, 0, stream>>>(sg0, WG0, 640, gb0, h0, BB(0), XGg,
      BB(10), BB(11), USIG, nullptr, nullptr, nullptr);

  // MERGED c-group + t-group (z=8):
  //  c (X=rhT=BB11): c1->BB6, c2->BB7, c3->BB8, c4->BB9  (s-group dead after GATE0)
  //  t (X=h1T=BB2):  t1->BB1, t2->BB3, t3->BB4, t4->BB12 (h0T dead, XGg dead after GATE0)
  dj.j[0] = {BB(11), S0b, BB(6), nullptr};
  dj.j[1] = {BB(11), SQ0, BB(7), nullptr};
  dj.j[2] = {BB(11), S1b, BB(8), nullptr};
  dj.j[3] = {BB(11), SQ1, BB(9), nullptr};
  dj.j[4] = {BB(2),  S0b, BB(1), nullptr};
  dj.j[5] = {BB(2),  SQ0, BB(3), nullptr};
  dj.j[6] = {BB(2),  S1b, BB(4), nullptr};
  dj.j[7] = {BB(2),  SQ1, BB(12), nullptr};
  gemm_diffz<<<dim3(64, 4, 8), 256, 0, stream>>>(dj);

  // CAND0: segs {rh=BB10, c1..c4}; Hb16=BB0; xadd=XGc(BB5); out_h0;
  // xa_hi->BB0 (elemwise RW safe), xaT->BB11 (rhT dead)
  Segs sc0{};
  sc0.p[0] = BB(10); sc0.p[1] = BB(6); sc0.p[2] = BB(7); sc0.p[3] = BB(8); sc0.p[4] = BB(9);
  gemm_wseg<1><<<512, 256, 0, stream>>>(sc0, WC0, 640, cb0, h0, BB(0), XGc,
      nullptr, nullptr, USIG, out_h0, BB(0), BB(11));

  // L1 s'-group (X=xaT=BB11): s1'->BB2, s2'->BB5, s3'->BB6, s4'->BB7
  // (h1T dead after merged launch; XGc dead after CAND0; c1,c2 dead)
  dj.j[0] = {BB(11), S0b, BB(2), nullptr};
  dj.j[1] = {BB(11), SQ0, BB(5), nullptr};
  dj.j[2] = {BB(11), S1b, BB(6), nullptr};
  dj.j[3] = {BB(11), SQ1, BB(7), nullptr};
  gemm_diffz<<<dim3(64, 4, 4), 256, 0, stream>>>(dj);

  // GATE1: segs x{xa=BB0, s1'..s4'} h{h1=OH1a, t1=BB1, t2=BB3, t3=BB4, t4=BB12};
  // Hb16=OH1a; rh1_hi->BB8, rh1T->BB9 (c3,c4 dead)
  Segs sg1{};
  sg1.p[0] = BB(0); sg1.p[1] = BB(2); sg1.p[2] = BB(5); sg1.p[3] = BB(6); sg1.p[4] = BB(7);
  sg1.p[5] = OH1a;  sg1.p[6] = BB(1); sg1.p[7] = BB(3); sg1.p[8] = BB(4); sg1.p[9] = BB(12);
  gemm_wseg<0><<<512, 256, 0, stream>>>(sg1, WG1, 1280, gb1, h1, OH1a, nullptr,
      BB(8), BB(9), USIG, nullptr, nullptr, nullptr);

  // L1 d-group (X=rh1T=BB9): d1->BB10, d2->BB1, d3->BB3, d4->BB4 (t1..t3 dead)
  dj.j[0] = {BB(9), S0b, BB(10), nullptr};
  dj.j[1] = {BB(9), SQ0, BB(1), nullptr};
  dj.j[2] = {BB(9), S1b, BB(3), nullptr};
  dj.j[3] = {BB(9), SQ1, BB(4), nullptr};
  gemm_diffz<<<dim3(64, 4, 4), 256, 0, stream>>>(dj);

  // CAND1: segs x{xa, s1'..s4'} rh{rh1=BB8, d1=BB10, d2=BB1, d3=BB3, d4=BB4};
  // fp32 Hprev (OH1a aliases out_h1) -> out_h1
  Segs sc1{};
  sc1.p[0] = BB(0); sc1.p[1] = BB(2);  sc1.p[2] = BB(5); sc1.p[3] = BB(6); sc1.p[4] = BB(7);
  sc1.p[5] = BB(8); sc1.p[6] = BB(10); sc1.p[7] = BB(1); sc1.p[8] = BB(3); sc1.p[9] = BB(4);
  gemm_wseg<1><<<512, 256, 0, stream>>>(sc1, WC1, 1280, cb1, h1, nullptr, nullptr,
      nullptr, nullptr, USIG, out_h1, nullptr, nullptr);

  // projection
  proj_k<<<16384, 256, 0, stream>>>(out_h1, pw, pb, out);
}